// Round 7
// baseline (1437.133 us; speedup 1.0000x reference)
//
#include <hip/hip_runtime.h>

#define N_PTS 262144
#define NG 128
#define GS 1024
#define FPS_B 16

typedef __attribute__((ext_vector_type(8))) short short8;
typedef __attribute__((ext_vector_type(8))) __bf16 bf16x8;
typedef __attribute__((ext_vector_type(4))) float f32x4;
typedef unsigned long long ull;

__device__ __forceinline__ unsigned short f2bf(float f) {
  unsigned u = __float_as_uint(f);
  unsigned r = u + 0x7FFFu + ((u >> 16) & 1u);
  return (unsigned short)(r >> 16);
}

__device__ __forceinline__ f32x4 mfma16(short8 a, short8 b, f32x4 c) {
  return __builtin_amdgcn_mfma_f32_16x16x32_bf16(
      __builtin_bit_cast(bf16x8, a), __builtin_bit_cast(bf16x8, b), c, 0, 0, 0);
}

__device__ __forceinline__ ull shfl_xor_u64(ull v, int m) {
  unsigned lo = __shfl_xor((unsigned)v, m);
  unsigned hi = __shfl_xor((unsigned)(v >> 32), m);
  return ((ull)hi << 32) | lo;
}
__device__ __forceinline__ ull shfl_u64(ull v, int src) {
  unsigned lo = __shfl((unsigned)v, src);
  unsigned hi = __shfl((unsigned)(v >> 32), src);
  return ((ull)hi << 32) | lo;
}

__device__ __forceinline__ void st64(ull* p, ull v) {
  __hip_atomic_store(p, v, __ATOMIC_RELAXED, __HIP_MEMORY_SCOPE_AGENT);
}
__device__ __forceinline__ ull ld64(const ull* p) {
  return __hip_atomic_load(p, __ATOMIC_RELAXED, __HIP_MEMORY_SCOPE_AGENT);
}

// ordered-uint encode for float (monotone for all finite floats)
__device__ __forceinline__ unsigned ordenc(float f) {
  unsigned u = __float_as_uint(f);
  return (u >> 31) ? ~u : (u | 0x80000000u);
}

__device__ __forceinline__ unsigned knn_key(float x, float y, float z, float pp,
                                            float sx, float sy, float sz, float s2) {
  float dot = __fmaf_rn(sx, x, __fmaf_rn(sy, y, __fmul_rn(sz, z)));
  float d2 = __fadd_rn(__fsub_rn(s2, __fadd_rn(dot, dot)), pp);
  return ordenc(d2);
}

// ---------------- prep: bf16 transposed weights ------------------------------
__global__ void __launch_bounds__(256) prep_kernel(const float* __restrict__ w2,
    const float* __restrict__ w3, unsigned short* __restrict__ w2t,
    unsigned short* __restrict__ w3t) {
  int i = blockIdx.x * 256 + threadIdx.x;
  if (i < 131072) { int n = i >> 7, k = i & 127; w3t[i] = f2bf(w3[k * 1024 + n]); }
  if (i < 8192)  { int n = i >> 6, k = i & 63;  w2t[i] = f2bf(w2[k * 128 + n]); }
}

__device__ __forceinline__ void select_bucket(const unsigned* hist, int nbins,
                                              unsigned krem, unsigned* sres, int lane) {
  const int per = nbins >> 6;
  unsigned local = 0;
  for (int j = 0; j < per; ++j) local += hist[lane * per + j];
  unsigned inc = local;
  for (int off = 1; off < 64; off <<= 1) {
    unsigned v = __shfl_up(inc, off);
    if (lane >= off) inc += v;
  }
  unsigned exc = inc - local;
  if (exc < krem && krem <= inc) {
    unsigned c = exc;
    for (int j = 0; j < per; ++j) {
      unsigned h = hist[lane * per + j];
      if (c + h >= krem) { sres[0] = (unsigned)(lane * per + j); sres[1] = c; break; }
      c += h;
    }
  }
}

// ---------------- fused: fps (blocks 0..15) + per-group workers (16..143) ----
// kslots[2][3][16]: depth-2 parity; A={seq:14|dist:32|~idx:18},
// B={seq:14|x:32|yhi:18}, C={seq:14|ylo:14|z:32|pad:4}.
// mb[sel*4+c] = {coord_bits:32|seq:32} written once per step by fps block 0.
__global__ void __launch_bounds__(1024) fused_kernel(const float* __restrict__ pc,
    const float* __restrict__ w1, const unsigned short* __restrict__ w2t,
    const unsigned short* __restrict__ w3t, float* __restrict__ out,
    unsigned* __restrict__ cnts, ull* __restrict__ kslots, ull* __restrict__ mb,
    ull* __restrict__ cslots) {
  __shared__ __align__(16) char buf[73728];
  __shared__ int idxL[1024];
  __shared__ unsigned sres[2];
  __shared__ unsigned scnt[4];
  __shared__ float mbx[3];
  __shared__ float rs[3][16];
  __shared__ float bc[3];
  __shared__ ull wkeyL[16];
  __shared__ float wcx[16], wcy[16], wcz[16];

  const int tid = threadIdx.x, lane = tid & 63, wv = tid >> 6;
  const float* xs = pc;
  const float* ys = pc + N_PTS;
  const float* zs = pc + 2 * N_PTS;

  if (blockIdx.x < FPS_B) {
    // ===================== FPS role =====================
    const int p = blockIdx.x;
    const int gt = p * 1024 + tid;
    float* sampled_out = out + 131072;
    float x[16], y[16], z[16], md[16];
    float sx = 0.f, sy = 0.f, sz = 0.f;
#pragma unroll
    for (int j = 0; j < 16; ++j) {
      int i = gt + j * 16384;
      x[j] = xs[i]; y[j] = ys[i]; z[j] = zs[i];
      sx += x[j]; sy += y[j]; sz += z[j];
    }
#pragma unroll
    for (int m = 32; m; m >>= 1) {
      sx += __shfl_xor(sx, m); sy += __shfl_xor(sy, m); sz += __shfl_xor(sz, m);
    }
    if (lane == 0) { rs[0][wv] = sx; rs[1][wv] = sy; rs[2][wv] = sz; }
    __syncthreads();
    if (tid == 0) {
      float ax = 0.f, ay = 0.f, az = 0.f;
      for (int w = 0; w < 16; ++w) { ax += rs[0][w]; ay += rs[1][w]; az += rs[2][w]; }
      st64(&cslots[0 + p], (ull)__float_as_uint(ax));
      st64(&cslots[16 + p], (ull)__float_as_uint(ay));
      st64(&cslots[32 + p], (ull)__float_as_uint(az));
      __hip_atomic_fetch_add(&cnts[4], 1u, __ATOMIC_RELEASE, __HIP_MEMORY_SCOPE_AGENT);
    }
    if (wv == 0) {
      while (__hip_atomic_load(&cnts[4], __ATOMIC_RELAXED, __HIP_MEMORY_SCOPE_AGENT) < 16u)
        __builtin_amdgcn_s_sleep(1);
      (void)__hip_atomic_load(&cnts[4], __ATOMIC_ACQUIRE, __HIP_MEMORY_SCOPE_AGENT);
      float f = 0.f;
      if (lane < 48) f = __uint_as_float((unsigned)ld64(&cslots[lane]));
      float s = 0.f;
      for (int q = 0; q < 16; ++q) s += __shfl(f, (lane & 48) + q);  // ascending
      if (lane == 0)  bc[0] = s * (1.f / N_PTS);
      if (lane == 16) bc[1] = s * (1.f / N_PTS);
      if (lane == 32) bc[2] = s * (1.f / N_PTS);
    }
    __syncthreads();
    {
      float cx = bc[0], cy = bc[1], cz = bc[2];
#pragma unroll
      for (int j = 0; j < 16; ++j) {
        float dx = x[j] - cx, dy = y[j] - cy, dz = z[j] - cz;
        md[j] = sqrtf(dx * dx + dy * dy + dz * dz);
      }
    }
    for (int sel = 0; sel < NG; ++sel) {
      const ull seq = (ull)(sel + 1);
      ull lkey = 0ull; int jb = 0;
#pragma unroll
      for (int j = 0; j < 16; ++j) {
        unsigned fb = __float_as_uint(md[j]);
        ull k = ((ull)fb << 18) | (ull)(0x3FFFFu ^ (unsigned)(gt + j * 16384));
        if (k > lkey) { lkey = k; jb = j; }
      }
      float bx = x[jb], by = y[jb], bz = z[jb];
#pragma unroll
      for (int m = 32; m; m >>= 1) {
        ull o = shfl_xor_u64(lkey, m);
        float ox = __shfl_xor(bx, m), oy = __shfl_xor(by, m), oz = __shfl_xor(bz, m);
        if (o > lkey) { lkey = o; bx = ox; by = oy; bz = oz; }
      }
      if (lane == 0) { wkeyL[wv] = lkey; wcx[wv] = bx; wcy[wv] = by; wcz[wv] = bz; }
      __syncthreads();
      if (wv == 0) {
        ull kv = 0ull; float cx = 0.f, cy = 0.f, cz = 0.f;
        if (lane < 16) { kv = wkeyL[lane]; cx = wcx[lane]; cy = wcy[lane]; cz = wcz[lane]; }
#pragma unroll
        for (int m = 8; m; m >>= 1) {
          ull o = shfl_xor_u64(kv, m);
          float ox = __shfl_xor(cx, m), oy = __shfl_xor(cy, m), oz = __shfl_xor(cz, m);
          if (o > kv) { kv = o; cx = ox; cy = oy; cz = oz; }
        }
        const int pb = (sel & 1) * 48;
        if (lane == 0) st64(&kslots[pb + p], (seq << 50) | kv);
        if (lane == 1)
          st64(&kslots[pb + 16 + p], (seq << 50) |
               ((ull)__float_as_uint(cx) << 18) | (ull)(__float_as_uint(cy) >> 14));
        if (lane == 2)
          st64(&kslots[pb + 32 + p], (seq << 50) |
               ((ull)(__float_as_uint(cy) & 0x3FFFu) << 36) |
               ((ull)__float_as_uint(cz) << 4));
        ull v = 0ull;
        for (;;) {
          if (lane < 48) v = ld64(&kslots[pb + (lane >> 4) * 16 + (lane & 15)]);
          bool ok = (lane >= 48) || ((v >> 50) == seq);
          if (__all((int)ok)) break;
          __builtin_amdgcn_s_sleep(1);
        }
        ull kk = (lane < 16) ? v : 0ull;
        int ws_ = lane & 15;
#pragma unroll
        for (int m = 8; m; m >>= 1) {
          ull o = shfl_xor_u64(kk, m);
          int ow = __shfl_xor(ws_, m);
          if (o > kk) { kk = o; ws_ = ow; }
        }
        int wwin = __shfl(ws_, 0);
        ull Bv = shfl_u64(v, 16 + wwin);
        ull Cv = shfl_u64(v, 32 + wwin);
        unsigned xb = (unsigned)((Bv >> 18) & 0xFFFFFFFFull);
        unsigned yb = ((unsigned)(Bv & 0x3FFFFull) << 14) | (unsigned)((Cv >> 36) & 0x3FFFull);
        unsigned zb = (unsigned)((Cv >> 4) & 0xFFFFFFFFull);
        if (lane == 0) {
          bc[0] = __uint_as_float(xb);
          bc[1] = __uint_as_float(yb);
          bc[2] = __uint_as_float(zb);
        }
        if (p == 0 && lane < 3) {
          unsigned cb = lane == 0 ? xb : (lane == 1 ? yb : zb);
          sampled_out[sel * 3 + lane] = __uint_as_float(cb);
          st64(&mb[sel * 4 + lane], ((ull)cb << 32) | seq);
        }
      }
      __syncthreads();
      {
        float wx = bc[0], wy = bc[1], wz = bc[2];
#pragma unroll
        for (int j = 0; j < 16; ++j) {
          float dx = x[j] - wx, dy = y[j] - wy, dz = z[j] - wz;
          float d = sqrtf(dx * dx + dy * dy + dz * dz);
          md[j] = (sel == 0) ? d : fminf(md[j], d);
        }
      }
    }
    return;
  }

  // ===================== worker role: knn + mlp for one group =====================
  const int g = blockIdx.x - FPS_B;
  unsigned* hist = (unsigned*)buf;            // [2048]
  unsigned* candk = (unsigned*)(buf + 8192);  // [8192]
  unsigned* candi = (unsigned*)(buf + 40960); // [8192]
  const int ch = tid & 63;
  const float w10 = w1[ch], w11 = w1[64 + ch], w12 = w1[128 + ch];

  for (int i = tid; i < 2048; i += 1024) hist[i] = 0u;
  if (tid == 0) { scnt[0] = 0u; scnt[1] = 0u; scnt[2] = 0u; scnt[3] = 0u; }
  if (tid < 3) {  // wait for this group's sampled point
    ull v;
    do {
      v = ld64(&mb[g * 4 + tid]);
      if ((unsigned)v != (unsigned)(g + 1)) __builtin_amdgcn_s_sleep(8);
    } while ((unsigned)v != (unsigned)(g + 1));
    mbx[tid] = __uint_as_float((unsigned)(v >> 32));
  }
  __syncthreads();
  const float sx = mbx[0], sy = mbx[1], sz = mbx[2];
  const float s2 = __fadd_rn(__fadd_rn(__fmul_rn(sx, sx), __fmul_rn(sy, sy)),
                             __fmul_rn(sz, sz));
  for (int i = tid; i < N_PTS; i += 1024) {
    float xv = xs[i], yv = ys[i], zv = zs[i];
    float pp = __fadd_rn(__fadd_rn(__fmul_rn(xv, xv), __fmul_rn(yv, yv)), __fmul_rn(zv, zv));
    unsigned k = knn_key(xv, yv, zv, pp, sx, sy, sz, s2);
    atomicAdd(&hist[k >> 21], 1u);
  }
  __syncthreads();
  if (tid < 64) select_bucket(hist, 2048, GS, sres, lane);
  __syncthreads();
  const unsigned b0 = sres[0];
  unsigned krem = GS - sres[1];
  __syncthreads();
  for (int i = tid; i < N_PTS; i += 1024) {
    float xv = xs[i], yv = ys[i], zv = zs[i];
    float pp = __fadd_rn(__fadd_rn(__fmul_rn(xv, xv), __fmul_rn(yv, yv)), __fmul_rn(zv, zv));
    unsigned k = knn_key(xv, yv, zv, pp, sx, sy, sz, s2);
    unsigned b = k >> 21;
    if (b < b0) {
      unsigned pos = atomicAdd(&scnt[0], 1u);
      idxL[pos] = i;
    } else if (b == b0) {
      unsigned e = atomicAdd(&scnt[1], 1u);
      if (e < 8192u) { candk[e] = k; candi[e] = i; }
    }
  }
  __syncthreads();
  const int m = (int)min(scnt[1], 8192u);
  const int base1 = (int)scnt[0];
  for (int i = tid; i < 2048; i += 1024) hist[i] = 0u;
  __syncthreads();
  for (int j = tid; j < m; j += 1024) atomicAdd(&hist[(candk[j] >> 10) & 2047u], 1u);
  __syncthreads();
  if (tid < 64) select_bucket(hist, 2048, krem, sres, lane);
  __syncthreads();
  const unsigned b2 = sres[0];
  krem -= sres[1];
  __syncthreads();
  if (tid < 1024) hist[tid] = 0u;
  __syncthreads();
  for (int j = tid; j < m; j += 1024)
    if (((candk[j] >> 10) & 2047u) == b2) atomicAdd(&hist[candk[j] & 1023u], 1u);
  __syncthreads();
  if (tid < 64) select_bucket(hist, 1024, krem, sres, lane);
  __syncthreads();
  const unsigned b3 = sres[0];
  krem -= sres[1];
  const unsigned T = (b0 << 21) | (b2 << 10) | b3;
  __syncthreads();
  for (int j = tid; j < m; j += 1024) {
    unsigned k = candk[j];
    if (k < T) {
      unsigned pos = atomicAdd(&scnt[2], 1u);
      idxL[base1 + (int)pos] = candi[j];
    } else if (k == T) {
      unsigned e = atomicAdd(&scnt[3], 1u);
      if (e < 2048u) hist[e] = candi[j];
    }
  }
  __syncthreads();
  if (tid < 64) {
    const int tc = (int)min(scnt[3], 2048u);
    const int base2 = base1 + (int)scnt[2];
    for (int j = 0; j < (int)krem; ++j) {
      int best = 0x7FFFFFFF;
      for (int q = lane; q < tc; q += 64) best = min(best, (int)hist[q]);
      for (int mm = 32; mm; mm >>= 1) best = min(best, __shfl_xor(best, mm));
      for (int q = lane; q < tc; q += 64)
        if ((int)hist[q] == best) hist[q] = 0x7FFFFFFFu;
      if (lane == 0) idxL[base2 + j] = best;
    }
  }
  __syncthreads();
  // ---- mlp phase (reuses buf) ----
  short* h1 = (short*)buf;                    // [128*72]
  short* h2 = (short*)(buf + 18432);          // [128*136]
  float* cxs = (float*)(buf + 53248);
  float* cys = (float*)(buf + 53760);
  float* czs = (float*)(buf + 54272);
  unsigned* gmaxL = (unsigned*)(buf + 54784); // [1024]
  gmaxL[tid] = 0u;
  const int cB = lane & 15, kB = (lane >> 4) * 8, r0 = (lane >> 4) * 4;
  const int rowblk = wv & 7, nh = wv >> 3;
  for (int t = 0; t < 8; ++t) {
    __syncthreads();
    if (tid < 128) {
      int pt = idxL[t * 128 + tid];
      cxs[tid] = xs[pt]; cys[tid] = ys[pt]; czs[tid] = zs[pt];
    }
    __syncthreads();
    {
      const int pg = tid >> 6;
      for (int q = 0; q < 8; ++q) {
        int pr = pg * 8 + q;
        float v = fmaxf(__fmaf_rn(cxs[pr], w10, __fmaf_rn(cys[pr], w11, czs[pr] * w12)), 0.f);
        h1[pr * 72 + ch] = (short)f2bf(v);
      }
    }
    __syncthreads();
    {
      short8 a[2];
#pragma unroll
      for (int ks = 0; ks < 2; ++ks)
        a[ks] = *(const short8*)&h1[(rowblk * 16 + cB) * 72 + kB + ks * 32];
#pragma unroll
      for (int n0 = nh * 4; n0 < nh * 4 + 4; ++n0) {
        short8 bb[2];
#pragma unroll
        for (int ks = 0; ks < 2; ++ks)
          bb[ks] = *(const short8*)&w2t[(n0 * 16 + cB) * 64 + kB + ks * 32];
        f32x4 acc = {0.f, 0.f, 0.f, 0.f};
        acc = mfma16(a[0], bb[0], acc);
        acc = mfma16(a[1], bb[1], acc);
#pragma unroll
        for (int r = 0; r < 4; ++r)
          h2[(rowblk * 16 + r0 + r) * 136 + n0 * 16 + cB] = (short)f2bf(fmaxf(acc[r], 0.f));
      }
    }
    __syncthreads();
    {
      short8 a2[4];
#pragma unroll
      for (int ks = 0; ks < 4; ++ks)
        a2[ks] = *(const short8*)&h2[(rowblk * 16 + cB) * 136 + kB + ks * 32];
      for (int n0 = nh * 32; n0 < nh * 32 + 32; ++n0) {
        short8 b3[4];
#pragma unroll
        for (int ks = 0; ks < 4; ++ks)
          b3[ks] = *(const short8*)&w3t[(n0 * 16 + cB) * 128 + kB + ks * 32];
        f32x4 acc = {0.f, 0.f, 0.f, 0.f};
#pragma unroll
        for (int ks = 0; ks < 4; ++ks) acc = mfma16(a2[ks], b3[ks], acc);
        float mv = fmaxf(fmaxf(acc[0], acc[1]), fmaxf(acc[2], acc[3]));
        mv = fmaxf(mv, __shfl_xor(mv, 16));
        mv = fmaxf(mv, __shfl_xor(mv, 32));
        if (lane < 16) atomicMax(&gmaxL[n0 * 16 + lane], ordenc(mv));
      }
    }
  }
  __syncthreads();
  {
    unsigned mm = gmaxL[tid];
    out[g * 1024 + tid] = (mm >> 31) ? __uint_as_float(mm ^ 0x80000000u)
                                     : __uint_as_float(~mm);
  }
}

extern "C" void kernel_launch(void* const* d_in, const int* in_sizes, int n_in,
                              void* d_out, int out_size, void* d_ws, size_t ws_size,
                              hipStream_t stream) {
  (void)in_sizes; (void)n_in; (void)out_size; (void)ws_size;
  const float* pc = (const float*)d_in[0];
  const float* w1 = (const float*)d_in[1];
  const float* w2 = (const float*)d_in[2];
  const float* w3 = (const float*)d_in[3];
  float* out = (float*)d_out;
  char* ws = (char*)d_ws;

  unsigned* cnts = (unsigned*)(ws + 0);     // centroid counter
  ull* kslots = (ull*)(ws + 128);           // 96 ull (depth-2 × 3 lines)
  ull* mb = (ull*)(ws + 1024);              // 512 ull group mailboxes
  ull* cslots = (ull*)(ws + 5632);          // 48 ull centroid partials
  unsigned short* w2t = (unsigned short*)(ws + 8192);    // 16 KiB
  unsigned short* w3t = (unsigned short*)(ws + 24576);   // 256 KiB

  hipMemsetAsync(ws, 0, 8192, stream);
  prep_kernel<<<512, 256, 0, stream>>>(w2, w3, w2t, w3t);
  fused_kernel<<<FPS_B + NG, 1024, 0, stream>>>(pc, w1, w2t, w3t, out,
                                                cnts, kslots, mb, cslots);
}

// Round 8
// 1427.385 us; speedup vs baseline: 1.0068x; 1.0068x over previous
//
#include <hip/hip_runtime.h>

#define N_PTS 262144
#define NG 128
#define GS 1024
#define FPS_B 16

typedef __attribute__((ext_vector_type(8))) short short8;
typedef __attribute__((ext_vector_type(8))) __bf16 bf16x8;
typedef __attribute__((ext_vector_type(4))) float f32x4;
typedef unsigned long long ull;

__device__ __forceinline__ unsigned short f2bf(float f) {
  unsigned u = __float_as_uint(f);
  unsigned r = u + 0x7FFFu + ((u >> 16) & 1u);
  return (unsigned short)(r >> 16);
}

__device__ __forceinline__ f32x4 mfma16(short8 a, short8 b, f32x4 c) {
  return __builtin_amdgcn_mfma_f32_16x16x32_bf16(
      __builtin_bit_cast(bf16x8, a), __builtin_bit_cast(bf16x8, b), c, 0, 0, 0);
}

__device__ __forceinline__ ull shfl_xor_u64(ull v, int m) {
  unsigned lo = __shfl_xor((unsigned)v, m);
  unsigned hi = __shfl_xor((unsigned)(v >> 32), m);
  return ((ull)hi << 32) | lo;
}
__device__ __forceinline__ ull shfl_u64(ull v, int src) {
  unsigned lo = __shfl((unsigned)v, src);
  unsigned hi = __shfl((unsigned)(v >> 32), src);
  return ((ull)hi << 32) | lo;
}

__device__ __forceinline__ void st64(ull* p, ull v) {
  __hip_atomic_store(p, v, __ATOMIC_RELAXED, __HIP_MEMORY_SCOPE_AGENT);
}
__device__ __forceinline__ ull ld64(const ull* p) {
  return __hip_atomic_load(p, __ATOMIC_RELAXED, __HIP_MEMORY_SCOPE_AGENT);
}

__device__ __forceinline__ unsigned ordenc(float f) {
  unsigned u = __float_as_uint(f);
  return (u >> 31) ? ~u : (u | 0x80000000u);
}

__device__ __forceinline__ unsigned knn_key(float x, float y, float z, float pp,
                                            float sx, float sy, float sz, float s2) {
  float dot = __fmaf_rn(sx, x, __fmaf_rn(sy, y, __fmul_rn(sz, z)));
  float d2 = __fadd_rn(__fsub_rn(s2, __fadd_rn(dot, dot)), pp);
  return ordenc(d2);
}

__device__ __forceinline__ void select_bucket(const unsigned* hist, int nbins,
                                              unsigned krem, unsigned* sres, int lane) {
  const int per = nbins >> 6;
  unsigned local = 0;
  for (int j = 0; j < per; ++j) local += hist[lane * per + j];
  unsigned inc = local;
  for (int off = 1; off < 64; off <<= 1) {
    unsigned v = __shfl_up(inc, off);
    if (lane >= off) inc += v;
  }
  unsigned exc = inc - local;
  if (exc < krem && krem <= inc) {
    unsigned c = exc;
    for (int j = 0; j < per; ++j) {
      unsigned h = hist[lane * per + j];
      if (c + h >= krem) { sres[0] = (unsigned)(lane * per + j); sres[1] = c; break; }
      c += h;
    }
  }
}

// fused: fps (blocks 0..15) + per-group workers (16..143), workers serialized
// behind fps. kslots[2][3][16] depth-2 parity: A={seq:14|dist:32|~idx:18},
// B={seq:14|x:32|yhi:18}, C={seq:14|ylo:14|z:32|pad:4}.
// mb[sel*4+c]={coord:32|seq:32}; mb[508] low32==128 signals fps done.
__global__ void __launch_bounds__(1024) fused_kernel(const float* __restrict__ pc,
    const float* __restrict__ w1, const float* __restrict__ w2,
    const float* __restrict__ w3, unsigned short* __restrict__ w2t,
    unsigned short* __restrict__ w3t, float* __restrict__ out,
    unsigned* __restrict__ cnts, unsigned* __restrict__ prepcnt,
    ull* __restrict__ kslots, ull* __restrict__ mb, ull* __restrict__ cslots) {
  __shared__ __align__(16) char buf[73728];
  __shared__ int idxL[1024];
  __shared__ unsigned sres[2];
  __shared__ unsigned scnt[4];
  __shared__ float mbx[3];
  __shared__ float rs[3][16];
  __shared__ float bc[3];
  __shared__ ull wkeyL[16];
  __shared__ float wcx[16], wcy[16], wcz[16];

  const int tid = threadIdx.x, lane = tid & 63, wv = tid >> 6;
  const float* xs = pc;
  const float* ys = pc + N_PTS;
  const float* zs = pc + 2 * N_PTS;

  if (blockIdx.x < FPS_B) {
    // ===================== FPS role =====================
    const int p = blockIdx.x;
    const int gt = p * 1024 + tid;
    float* sampled_out = out + 131072;
    float x[16], y[16], z[16], md[16];
    float sx = 0.f, sy = 0.f, sz = 0.f;
#pragma unroll
    for (int j = 0; j < 16; ++j) {
      int i = gt + j * 16384;
      x[j] = xs[i]; y[j] = ys[i]; z[j] = zs[i];
      sx += x[j]; sy += y[j]; sz += z[j];
    }
#pragma unroll
    for (int m = 32; m; m >>= 1) {
      sx += __shfl_xor(sx, m); sy += __shfl_xor(sy, m); sz += __shfl_xor(sz, m);
    }
    if (lane == 0) { rs[0][wv] = sx; rs[1][wv] = sy; rs[2][wv] = sz; }
    __syncthreads();
    if (tid == 0) {
      float ax = 0.f, ay = 0.f, az = 0.f;
      for (int w = 0; w < 16; ++w) { ax += rs[0][w]; ay += rs[1][w]; az += rs[2][w]; }
      st64(&cslots[0 + p], (ull)__float_as_uint(ax));
      st64(&cslots[16 + p], (ull)__float_as_uint(ay));
      st64(&cslots[32 + p], (ull)__float_as_uint(az));
      __hip_atomic_fetch_add(&cnts[4], 1u, __ATOMIC_RELEASE, __HIP_MEMORY_SCOPE_AGENT);
    }
    if (wv == 0) {
      while (__hip_atomic_load(&cnts[4], __ATOMIC_RELAXED, __HIP_MEMORY_SCOPE_AGENT) < 16u)
        __builtin_amdgcn_s_sleep(1);
      (void)__hip_atomic_load(&cnts[4], __ATOMIC_ACQUIRE, __HIP_MEMORY_SCOPE_AGENT);
      float f = 0.f;
      if (lane < 48) f = __uint_as_float((unsigned)ld64(&cslots[lane]));
      float s = 0.f;
      for (int q = 0; q < 16; ++q) s += __shfl(f, (lane & 48) + q);  // ascending
      if (lane == 0)  bc[0] = s * (1.f / N_PTS);
      if (lane == 16) bc[1] = s * (1.f / N_PTS);
      if (lane == 32) bc[2] = s * (1.f / N_PTS);
    }
    __syncthreads();
    ull lkey = 0ull; int jb = 0;
    {
      float cx = bc[0], cy = bc[1], cz = bc[2];
#pragma unroll
      for (int j = 0; j < 16; ++j) {
        float dx = x[j] - cx, dy = y[j] - cy, dz = z[j] - cz;
        float d = sqrtf(dx * dx + dy * dy + dz * dz);
        md[j] = d;
        unsigned fb = __float_as_uint(d);
        ull k = ((ull)fb << 18) | (ull)(0x3FFFFu ^ (unsigned)(gt + j * 16384));
        if (k > lkey) { lkey = k; jb = j; }
      }
    }
    for (int sel = 0; sel < NG; ++sel) {
      const ull seq = (ull)(sel + 1);
      float bx = x[jb], by = y[jb], bz = z[jb];
      ull rk = lkey;
#pragma unroll
      for (int m = 32; m; m >>= 1) {
        ull o = shfl_xor_u64(rk, m);
        float ox = __shfl_xor(bx, m), oy = __shfl_xor(by, m), oz = __shfl_xor(bz, m);
        if (o > rk) { rk = o; bx = ox; by = oy; bz = oz; }
      }
      if (lane == 0) { wkeyL[wv] = rk; wcx[wv] = bx; wcy[wv] = by; wcz[wv] = bz; }
      __syncthreads();
      if (wv == 0) {
        ull kv = 0ull; float cx = 0.f, cy = 0.f, cz = 0.f;
        if (lane < 16) { kv = wkeyL[lane]; cx = wcx[lane]; cy = wcy[lane]; cz = wcz[lane]; }
#pragma unroll
        for (int m = 8; m; m >>= 1) {
          ull o = shfl_xor_u64(kv, m);
          float ox = __shfl_xor(cx, m), oy = __shfl_xor(cy, m), oz = __shfl_xor(cz, m);
          if (o > kv) { kv = o; cx = ox; cy = oy; cz = oz; }
        }
        const int pb = (sel & 1) * 48;
        if (lane == 0) st64(&kslots[pb + p], (seq << 50) | kv);
        if (lane == 1)
          st64(&kslots[pb + 16 + p], (seq << 50) |
               ((ull)__float_as_uint(cx) << 18) | (ull)(__float_as_uint(cy) >> 14));
        if (lane == 2)
          st64(&kslots[pb + 32 + p], (seq << 50) |
               ((ull)(__float_as_uint(cy) & 0x3FFFu) << 36) |
               ((ull)__float_as_uint(cz) << 4));
        ull v = 0ull;
        for (;;) {  // hot spin, no sleep
          if (lane < 48) v = ld64(&kslots[pb + (lane >> 4) * 16 + (lane & 15)]);
          bool ok = (lane >= 48) || ((v >> 50) == seq);
          if (__all((int)ok)) break;
        }
        ull kk = (lane < 16) ? v : 0ull;
        int ws_ = lane & 15;
#pragma unroll
        for (int m = 8; m; m >>= 1) {
          ull o = shfl_xor_u64(kk, m);
          int ow = __shfl_xor(ws_, m);
          if (o > kk) { kk = o; ws_ = ow; }
        }
        int wwin = __shfl(ws_, 0);
        ull Bv = shfl_u64(v, 16 + wwin);
        ull Cv = shfl_u64(v, 32 + wwin);
        unsigned xb = (unsigned)((Bv >> 18) & 0xFFFFFFFFull);
        unsigned yb = ((unsigned)(Bv & 0x3FFFFull) << 14) | (unsigned)((Cv >> 36) & 0x3FFFull);
        unsigned zb = (unsigned)((Cv >> 4) & 0xFFFFFFFFull);
        if (lane == 0) {
          bc[0] = __uint_as_float(xb);
          bc[1] = __uint_as_float(yb);
          bc[2] = __uint_as_float(zb);
        }
        if (p == 0 && lane < 3) {
          unsigned cb = lane == 0 ? xb : (lane == 1 ? yb : zb);
          sampled_out[sel * 3 + lane] = __uint_as_float(cb);
          st64(&mb[sel * 4 + lane], ((ull)cb << 32) | seq);
        }
      }
      __syncthreads();
      {  // fused md-update + next-step candidate
        float wx = bc[0], wy = bc[1], wz = bc[2];
        ull nk = 0ull; int nj = 0;
#pragma unroll
        for (int j = 0; j < 16; ++j) {
          float dx = x[j] - wx, dy = y[j] - wy, dz = z[j] - wz;
          float d = sqrtf(dx * dx + dy * dy + dz * dz);
          float m = (sel == 0) ? d : fminf(md[j], d);
          md[j] = m;
          unsigned fb = __float_as_uint(m);
          ull k = ((ull)fb << 18) | (ull)(0x3FFFFu ^ (unsigned)(gt + j * 16384));
          if (k > nk) { nk = k; nj = j; }
        }
        lkey = nk; jb = nj;
      }
    }
    return;
  }

  // ===================== worker role =====================
  const int g = blockIdx.x - FPS_B;
  // --- prep slices (hidden behind fps): w3t rows, w2t rows ---
  {
    int i3 = g * 1024 + tid;
    { int n = i3 >> 7, k = i3 & 127; w3t[i3] = f2bf(w3[k * 1024 + n]); }
    if (tid < 64) { int i2 = g * 64 + tid; int n = i2 >> 6, k = i2 & 63; w2t[i2] = f2bf(w2[k * 128 + n]); }
  }
  __syncthreads();
  if (tid == 0) {
    __hip_atomic_fetch_add(prepcnt, 1u, __ATOMIC_RELEASE, __HIP_MEMORY_SCOPE_AGENT);
    while (__hip_atomic_load(prepcnt, __ATOMIC_RELAXED, __HIP_MEMORY_SCOPE_AGENT) < 128u)
      __builtin_amdgcn_s_sleep(8);
    (void)__hip_atomic_load(prepcnt, __ATOMIC_ACQUIRE, __HIP_MEMORY_SCOPE_AGENT);
    while ((unsigned)ld64(&mb[508]) != 128u)  // fps completion (serialize)
      __builtin_amdgcn_s_sleep(16);
  }
  __syncthreads();
  if (tid < 3) {
    ull v;
    do { v = ld64(&mb[g * 4 + tid]); } while ((unsigned)v != (unsigned)(g + 1));
    mbx[tid] = __uint_as_float((unsigned)(v >> 32));
  }
  __syncthreads();

  unsigned* hist = (unsigned*)buf;            // [2048]
  unsigned* candk = (unsigned*)(buf + 8192);  // [8192]
  unsigned* candi = (unsigned*)(buf + 40960); // [8192]
  const int ch = tid & 63;
  const float w10 = w1[ch], w11 = w1[64 + ch], w12 = w1[128 + ch];
  const float sx = mbx[0], sy = mbx[1], sz = mbx[2];
  const float s2 = __fadd_rn(__fadd_rn(__fmul_rn(sx, sx), __fmul_rn(sy, sy)),
                             __fmul_rn(sz, sz));
  for (int i = tid; i < 2048; i += 1024) hist[i] = 0u;
  if (tid == 0) { scnt[0] = 0u; scnt[1] = 0u; scnt[2] = 0u; scnt[3] = 0u; }
  __syncthreads();
  for (int i = tid; i < N_PTS; i += 1024) {
    float xv = xs[i], yv = ys[i], zv = zs[i];
    float pp = __fadd_rn(__fadd_rn(__fmul_rn(xv, xv), __fmul_rn(yv, yv)), __fmul_rn(zv, zv));
    unsigned k = knn_key(xv, yv, zv, pp, sx, sy, sz, s2);
    atomicAdd(&hist[k >> 21], 1u);
  }
  __syncthreads();
  if (tid < 64) select_bucket(hist, 2048, GS, sres, lane);
  __syncthreads();
  const unsigned b0 = sres[0];
  unsigned krem = GS - sres[1];
  __syncthreads();
  for (int i = tid; i < N_PTS; i += 1024) {
    float xv = xs[i], yv = ys[i], zv = zs[i];
    float pp = __fadd_rn(__fadd_rn(__fmul_rn(xv, xv), __fmul_rn(yv, yv)), __fmul_rn(zv, zv));
    unsigned k = knn_key(xv, yv, zv, pp, sx, sy, sz, s2);
    unsigned b = k >> 21;
    if (b < b0) {
      unsigned pos = atomicAdd(&scnt[0], 1u);
      idxL[pos] = i;
    } else if (b == b0) {
      unsigned e = atomicAdd(&scnt[1], 1u);
      if (e < 8192u) { candk[e] = k; candi[e] = i; }
    }
  }
  __syncthreads();
  const int m = (int)min(scnt[1], 8192u);
  const int base1 = (int)scnt[0];
  for (int i = tid; i < 2048; i += 1024) hist[i] = 0u;
  __syncthreads();
  for (int j = tid; j < m; j += 1024) atomicAdd(&hist[(candk[j] >> 10) & 2047u], 1u);
  __syncthreads();
  if (tid < 64) select_bucket(hist, 2048, krem, sres, lane);
  __syncthreads();
  const unsigned b2 = sres[0];
  krem -= sres[1];
  __syncthreads();
  if (tid < 1024) hist[tid] = 0u;
  __syncthreads();
  for (int j = tid; j < m; j += 1024)
    if (((candk[j] >> 10) & 2047u) == b2) atomicAdd(&hist[candk[j] & 1023u], 1u);
  __syncthreads();
  if (tid < 64) select_bucket(hist, 1024, krem, sres, lane);
  __syncthreads();
  const unsigned b3 = sres[0];
  krem -= sres[1];
  const unsigned T = (b0 << 21) | (b2 << 10) | b3;
  __syncthreads();
  for (int j = tid; j < m; j += 1024) {
    unsigned k = candk[j];
    if (k < T) {
      unsigned pos = atomicAdd(&scnt[2], 1u);
      idxL[base1 + (int)pos] = candi[j];
    } else if (k == T) {
      unsigned e = atomicAdd(&scnt[3], 1u);
      if (e < 2048u) hist[e] = candi[j];
    }
  }
  __syncthreads();
  if (tid < 64) {
    const int tc = (int)min(scnt[3], 2048u);
    const int base2 = base1 + (int)scnt[2];
    for (int j = 0; j < (int)krem; ++j) {
      int best = 0x7FFFFFFF;
      for (int q = lane; q < tc; q += 64) best = min(best, (int)hist[q]);
      for (int mm = 32; mm; mm >>= 1) best = min(best, __shfl_xor(best, mm));
      for (int q = lane; q < tc; q += 64)
        if ((int)hist[q] == best) hist[q] = 0x7FFFFFFFu;
      if (lane == 0) idxL[base2 + j] = best;
    }
  }
  __syncthreads();
  // ---- mlp phase (reuses buf) ----
  short* h1 = (short*)buf;                    // [128*72]
  short* h2 = (short*)(buf + 18432);          // [128*136]
  float* cxs = (float*)(buf + 53248);
  float* cys = (float*)(buf + 53760);
  float* czs = (float*)(buf + 54272);
  unsigned* gmaxL = (unsigned*)(buf + 54784); // [1024]
  gmaxL[tid] = 0u;
  const int cB = lane & 15, kB = (lane >> 4) * 8, r0 = (lane >> 4) * 4;
  const int rowblk = wv & 7, nh = wv >> 3;
  for (int t = 0; t < 8; ++t) {
    __syncthreads();
    if (tid < 128) {
      int pt = idxL[t * 128 + tid];
      cxs[tid] = xs[pt]; cys[tid] = ys[pt]; czs[tid] = zs[pt];
    }
    __syncthreads();
    {
      const int pg = tid >> 6;
      for (int q = 0; q < 8; ++q) {
        int pr = pg * 8 + q;
        float v = fmaxf(__fmaf_rn(cxs[pr], w10, __fmaf_rn(cys[pr], w11, czs[pr] * w12)), 0.f);
        h1[pr * 72 + ch] = (short)f2bf(v);
      }
    }
    __syncthreads();
    {
      short8 a[2];
#pragma unroll
      for (int ks = 0; ks < 2; ++ks)
        a[ks] = *(const short8*)&h1[(rowblk * 16 + cB) * 72 + kB + ks * 32];
#pragma unroll
      for (int n0 = nh * 4; n0 < nh * 4 + 4; ++n0) {
        short8 bb[2];
#pragma unroll
        for (int ks = 0; ks < 2; ++ks)
          bb[ks] = *(const short8*)&w2t[(n0 * 16 + cB) * 64 + kB + ks * 32];
        f32x4 acc = {0.f, 0.f, 0.f, 0.f};
        acc = mfma16(a[0], bb[0], acc);
        acc = mfma16(a[1], bb[1], acc);
#pragma unroll
        for (int r = 0; r < 4; ++r)
          h2[(rowblk * 16 + r0 + r) * 136 + n0 * 16 + cB] = (short)f2bf(fmaxf(acc[r], 0.f));
      }
    }
    __syncthreads();
    {
      short8 a2[4];
#pragma unroll
      for (int ks = 0; ks < 4; ++ks)
        a2[ks] = *(const short8*)&h2[(rowblk * 16 + cB) * 136 + kB + ks * 32];
      for (int n0 = nh * 32; n0 < nh * 32 + 32; ++n0) {
        short8 b3[4];
#pragma unroll
        for (int ks = 0; ks < 4; ++ks)
          b3[ks] = *(const short8*)&w3t[(n0 * 16 + cB) * 128 + kB + ks * 32];
        f32x4 acc = {0.f, 0.f, 0.f, 0.f};
#pragma unroll
        for (int ks = 0; ks < 4; ++ks) acc = mfma16(a2[ks], b3[ks], acc);
        float mv = fmaxf(fmaxf(acc[0], acc[1]), fmaxf(acc[2], acc[3]));
        mv = fmaxf(mv, __shfl_xor(mv, 16));
        mv = fmaxf(mv, __shfl_xor(mv, 32));
        if (lane < 16) atomicMax(&gmaxL[n0 * 16 + lane], ordenc(mv));
      }
    }
  }
  __syncthreads();
  {
    unsigned mm = gmaxL[tid];
    out[g * 1024 + tid] = (mm >> 31) ? __uint_as_float(mm ^ 0x80000000u)
                                     : __uint_as_float(~mm);
  }
}

extern "C" void kernel_launch(void* const* d_in, const int* in_sizes, int n_in,
                              void* d_out, int out_size, void* d_ws, size_t ws_size,
                              hipStream_t stream) {
  (void)in_sizes; (void)n_in; (void)out_size; (void)ws_size;
  const float* pc = (const float*)d_in[0];
  const float* w1 = (const float*)d_in[1];
  const float* w2 = (const float*)d_in[2];
  const float* w3 = (const float*)d_in[3];
  float* out = (float*)d_out;
  char* ws = (char*)d_ws;

  unsigned* cnts = (unsigned*)(ws + 0);       // centroid counter at [4]
  unsigned* prepcnt = (unsigned*)(ws + 64);   // prep barrier counter
  ull* kslots = (ull*)(ws + 128);             // 96 ull depth-2 × 3 lines
  ull* mb = (ull*)(ws + 1024);                // 512 ull group mailboxes
  ull* cslots = (ull*)(ws + 5632);            // 48 ull centroid partials
  unsigned short* w2t = (unsigned short*)(ws + 8192);    // 16 KiB
  unsigned short* w3t = (unsigned short*)(ws + 24576);   // 256 KiB

  hipMemsetAsync(ws, 0, 8192, stream);
  fused_kernel<<<FPS_B + NG, 1024, 0, stream>>>(pc, w1, w2, w3, w2t, w3t, out,
                                                cnts, prepcnt, kslots, mb, cslots);
}

// Round 9
// 1210.595 us; speedup vs baseline: 1.1871x; 1.1791x over previous
//
#include <hip/hip_runtime.h>

#define N_PTS 262144
#define NG 128
#define GS 1024
#define FPS_B 16

typedef __attribute__((ext_vector_type(8))) short short8;
typedef __attribute__((ext_vector_type(8))) __bf16 bf16x8;
typedef __attribute__((ext_vector_type(4))) float f32x4;
typedef unsigned long long ull;

__device__ __forceinline__ unsigned short f2bf(float f) {
  unsigned u = __float_as_uint(f);
  unsigned r = u + 0x7FFFu + ((u >> 16) & 1u);
  return (unsigned short)(r >> 16);
}

__device__ __forceinline__ f32x4 mfma16(short8 a, short8 b, f32x4 c) {
  return __builtin_amdgcn_mfma_f32_16x16x32_bf16(
      __builtin_bit_cast(bf16x8, a), __builtin_bit_cast(bf16x8, b), c, 0, 0, 0);
}

__device__ __forceinline__ ull shfl_xor_u64(ull v, int m) {
  unsigned lo = __shfl_xor((unsigned)v, m);
  unsigned hi = __shfl_xor((unsigned)(v >> 32), m);
  return ((ull)hi << 32) | lo;
}

__device__ __forceinline__ void st64(ull* p, ull v) {
  __hip_atomic_store(p, v, __ATOMIC_RELAXED, __HIP_MEMORY_SCOPE_AGENT);
}
__device__ __forceinline__ ull ld64(const ull* p) {
  return __hip_atomic_load(p, __ATOMIC_RELAXED, __HIP_MEMORY_SCOPE_AGENT);
}

__device__ __forceinline__ unsigned ordenc(float f) {
  unsigned u = __float_as_uint(f);
  return (u >> 31) ? ~u : (u | 0x80000000u);
}

__device__ __forceinline__ unsigned knn_key(float x, float y, float z, float pp,
                                            float sx, float sy, float sz, float s2) {
  float dot = __fmaf_rn(sx, x, __fmaf_rn(sy, y, __fmul_rn(sz, z)));
  float d2 = __fadd_rn(__fsub_rn(s2, __fadd_rn(dot, dot)), pp);
  return ordenc(d2);
}

__device__ __forceinline__ void select_bucket(const unsigned* hist, int nbins,
                                              unsigned krem, unsigned* sres, int lane) {
  const int per = nbins >> 6;
  unsigned local = 0;
  for (int j = 0; j < per; ++j) local += hist[lane * per + j];
  unsigned inc = local;
  for (int off = 1; off < 64; off <<= 1) {
    unsigned v = __shfl_up(inc, off);
    if (lane >= off) inc += v;
  }
  unsigned exc = inc - local;
  if (exc < krem && krem <= inc) {
    unsigned c = exc;
    for (int j = 0; j < per; ++j) {
      unsigned h = hist[lane * per + j];
      if (c + h >= krem) { sres[0] = (unsigned)(lane * per + j); sres[1] = c; break; }
      c += h;
    }
  }
}

// fused: fps (blocks 0..15, single-line exchange) + overlapped per-group
// workers (16..143). kslots[16]: {seq:14|dist:32|~idx:18}, one 128B line.
// mb[g*4+c] = {coord:32|seq:32} posted by fps block 0 at step g.
__global__ void __launch_bounds__(1024) fused_kernel(const float* __restrict__ pc,
    const float* __restrict__ w1, const float* __restrict__ w2,
    const float* __restrict__ w3, unsigned short* __restrict__ w2t,
    unsigned short* __restrict__ w3t, float* __restrict__ out,
    unsigned* __restrict__ cnts, unsigned* __restrict__ prepcnt,
    ull* __restrict__ kslots, ull* __restrict__ mb, ull* __restrict__ cslots) {
  __shared__ __align__(16) char buf[73728];
  __shared__ int idxL[1024];
  __shared__ unsigned sres[2];
  __shared__ unsigned scnt[4];
  __shared__ float mbx[3];
  __shared__ float rs[3][16];
  __shared__ float bc[3];
  __shared__ ull wkeyL[16];

  const int tid = threadIdx.x, lane = tid & 63, wv = tid >> 6;
  const float* xs = pc;
  const float* ys = pc + N_PTS;
  const float* zs = pc + 2 * N_PTS;

  if (blockIdx.x < FPS_B) {
    // ===================== FPS role (R5 single-line protocol) ================
    const int p = blockIdx.x;
    const int gt = p * 1024 + tid;
    float* sampled_out = out + 131072;
    float x[16], y[16], z[16], md[16];
    float sx = 0.f, sy = 0.f, sz = 0.f;
#pragma unroll
    for (int j = 0; j < 16; ++j) {
      int i = gt + j * 16384;
      x[j] = xs[i]; y[j] = ys[i]; z[j] = zs[i];
      sx += x[j]; sy += y[j]; sz += z[j];
    }
#pragma unroll
    for (int m = 32; m; m >>= 1) {
      sx += __shfl_xor(sx, m); sy += __shfl_xor(sy, m); sz += __shfl_xor(sz, m);
    }
    if (lane == 0) { rs[0][wv] = sx; rs[1][wv] = sy; rs[2][wv] = sz; }
    __syncthreads();
    if (tid == 0) {
      float ax = 0.f, ay = 0.f, az = 0.f;
      for (int w = 0; w < 16; ++w) { ax += rs[0][w]; ay += rs[1][w]; az += rs[2][w]; }
      st64(&cslots[0 + p], (ull)__float_as_uint(ax));
      st64(&cslots[16 + p], (ull)__float_as_uint(ay));
      st64(&cslots[32 + p], (ull)__float_as_uint(az));
      __hip_atomic_fetch_add(&cnts[4], 1u, __ATOMIC_RELEASE, __HIP_MEMORY_SCOPE_AGENT);
    }
    if (wv == 0) {
      while (__hip_atomic_load(&cnts[4], __ATOMIC_RELAXED, __HIP_MEMORY_SCOPE_AGENT) < 16u)
        __builtin_amdgcn_s_sleep(1);
      (void)__hip_atomic_load(&cnts[4], __ATOMIC_ACQUIRE, __HIP_MEMORY_SCOPE_AGENT);
      float f = 0.f;
      if (lane < 48) f = __uint_as_float((unsigned)ld64(&cslots[lane]));
      float s = 0.f;
      for (int q = 0; q < 16; ++q) s += __shfl(f, (lane & 48) + q);  // ascending
      if (lane == 0)  bc[0] = s * (1.f / N_PTS);
      if (lane == 16) bc[1] = s * (1.f / N_PTS);
      if (lane == 32) bc[2] = s * (1.f / N_PTS);
    }
    __syncthreads();
    ull lkey = 0ull;
    {
      float cx = bc[0], cy = bc[1], cz = bc[2];
#pragma unroll
      for (int j = 0; j < 16; ++j) {
        float dx = x[j] - cx, dy = y[j] - cy, dz = z[j] - cz;
        float d = sqrtf(dx * dx + dy * dy + dz * dz);
        md[j] = d;
        unsigned fb = __float_as_uint(d);
        ull k = ((ull)fb << 18) | (ull)(0x3FFFFu ^ (unsigned)(gt + j * 16384));
        if (k > lkey) lkey = k;
      }
    }
    for (int sel = 0; sel < NG; ++sel) {
      const ull seq = (ull)(sel + 1);
      ull rk = lkey;
#pragma unroll
      for (int m = 32; m; m >>= 1) {
        ull o = shfl_xor_u64(rk, m);
        if (o > rk) rk = o;
      }
      if (lane == 0) wkeyL[wv] = rk;
      __syncthreads();
      if (wv == 0) {
        ull bk = (lane < 16) ? wkeyL[lane] : 0ull;
#pragma unroll
        for (int m = 8; m; m >>= 1) {
          ull o = shfl_xor_u64(bk, m);
          if (o > bk) bk = o;
        }
        if (lane == 0) st64(&kslots[p], (seq << 50) | bk);  // fire-and-forget
        ull v = 0ull;
        for (;;) {  // poll one 128B line
          if (lane < 16) v = ld64(&kslots[lane]);
          bool ok = (lane >= 16) || ((v >> 50) == seq);
          if (__all((int)ok)) break;
          __builtin_amdgcn_s_sleep(1);
        }
        ull gk = (lane < 16) ? v : 0ull;
#pragma unroll
        for (int m = 32; m; m >>= 1) {
          ull o = shfl_xor_u64(gk, m);
          if (o > gk) gk = o;
        }
        unsigned wi = 0x3FFFFu ^ (unsigned)(gk & 0x3FFFFull);
        if (lane < 3) {
          float c = pc[lane * N_PTS + wi];  // clean L2-resident fetch
          bc[lane] = c;
          if (p == 0) {
            sampled_out[sel * 3 + lane] = c;
            st64(&mb[sel * 4 + lane], ((ull)__float_as_uint(c) << 32) | seq);
          }
        }
      }
      __syncthreads();
      {  // fused md-update + next-step candidate
        float wx = bc[0], wy = bc[1], wz = bc[2];
        ull nk = 0ull;
#pragma unroll
        for (int j = 0; j < 16; ++j) {
          float dx = x[j] - wx, dy = y[j] - wy, dz = z[j] - wz;
          float d = sqrtf(dx * dx + dy * dy + dz * dz);
          float m = (sel == 0) ? d : fminf(md[j], d);
          md[j] = m;
          unsigned fb = __float_as_uint(m);
          ull k = ((ull)fb << 18) | (ull)(0x3FFFFu ^ (unsigned)(gt + j * 16384));
          if (k > nk) nk = k;
        }
        lkey = nk;
      }
    }
    return;
  }

  // ===================== worker role (overlapped) =====================
  const int g = blockIdx.x - FPS_B;
  // prep slices (w3t/w2t transpose), then release; consumed before mlp.
  {
    int i3 = g * 1024 + tid;
    { int n = i3 >> 7, k = i3 & 127; w3t[i3] = f2bf(w3[k * 1024 + n]); }
    if (tid < 64) { int i2 = g * 64 + tid; int n = i2 >> 6, k = i2 & 63; w2t[i2] = f2bf(w2[k * 128 + n]); }
  }
  __syncthreads();
  if (tid == 0)
    __hip_atomic_fetch_add(prepcnt, 1u, __ATOMIC_RELEASE, __HIP_MEMORY_SCOPE_AGENT);
  // wait for this group's sampled point (long-interval poll: low MALL pressure)
  if (tid < 3) {
    ull v;
    for (;;) {
      v = ld64(&mb[g * 4 + tid]);
      if ((unsigned)v == (unsigned)(g + 1)) break;
      __builtin_amdgcn_s_sleep(127);
    }
    mbx[tid] = __uint_as_float((unsigned)(v >> 32));
  }
  if (tid == 0) { scnt[0] = 0u; scnt[1] = 0u; scnt[2] = 0u; scnt[3] = 0u; }
  __syncthreads();

  unsigned* hist = (unsigned*)buf;            // [2048]
  unsigned* candk = (unsigned*)(buf + 8192);  // [8192]
  unsigned* candi = (unsigned*)(buf + 40960); // [8192]
  const int ch = tid & 63;
  const float w10 = w1[ch], w11 = w1[64 + ch], w12 = w1[128 + ch];
  const float sx = mbx[0], sy = mbx[1], sz = mbx[2];
  const float s2 = __fadd_rn(__fadd_rn(__fmul_rn(sx, sx), __fmul_rn(sy, sy)),
                             __fmul_rn(sz, sz));
  for (int i = tid; i < 2048; i += 1024) hist[i] = 0u;
  __syncthreads();
  for (int i = tid; i < N_PTS; i += 1024) {
    float xv = xs[i], yv = ys[i], zv = zs[i];
    float pp = __fadd_rn(__fadd_rn(__fmul_rn(xv, xv), __fmul_rn(yv, yv)), __fmul_rn(zv, zv));
    unsigned k = knn_key(xv, yv, zv, pp, sx, sy, sz, s2);
    atomicAdd(&hist[k >> 21], 1u);
  }
  __syncthreads();
  if (tid < 64) select_bucket(hist, 2048, GS, sres, lane);
  __syncthreads();
  const unsigned b0 = sres[0];
  unsigned krem = GS - sres[1];
  __syncthreads();
  for (int i = tid; i < N_PTS; i += 1024) {
    float xv = xs[i], yv = ys[i], zv = zs[i];
    float pp = __fadd_rn(__fadd_rn(__fmul_rn(xv, xv), __fmul_rn(yv, yv)), __fmul_rn(zv, zv));
    unsigned k = knn_key(xv, yv, zv, pp, sx, sy, sz, s2);
    unsigned b = k >> 21;
    if (b < b0) {
      unsigned pos = atomicAdd(&scnt[0], 1u);
      idxL[pos] = i;
    } else if (b == b0) {
      unsigned e = atomicAdd(&scnt[1], 1u);
      if (e < 8192u) { candk[e] = k; candi[e] = i; }
    }
  }
  __syncthreads();
  const int m = (int)min(scnt[1], 8192u);
  const int base1 = (int)scnt[0];
  for (int i = tid; i < 2048; i += 1024) hist[i] = 0u;
  __syncthreads();
  for (int j = tid; j < m; j += 1024) atomicAdd(&hist[(candk[j] >> 10) & 2047u], 1u);
  __syncthreads();
  if (tid < 64) select_bucket(hist, 2048, krem, sres, lane);
  __syncthreads();
  const unsigned b2 = sres[0];
  krem -= sres[1];
  __syncthreads();
  if (tid < 1024) hist[tid] = 0u;
  __syncthreads();
  for (int j = tid; j < m; j += 1024)
    if (((candk[j] >> 10) & 2047u) == b2) atomicAdd(&hist[candk[j] & 1023u], 1u);
  __syncthreads();
  if (tid < 64) select_bucket(hist, 1024, krem, sres, lane);
  __syncthreads();
  const unsigned b3 = sres[0];
  krem -= sres[1];
  const unsigned T = (b0 << 21) | (b2 << 10) | b3;
  __syncthreads();
  for (int j = tid; j < m; j += 1024) {
    unsigned k = candk[j];
    if (k < T) {
      unsigned pos = atomicAdd(&scnt[2], 1u);
      idxL[base1 + (int)pos] = candi[j];
    } else if (k == T) {
      unsigned e = atomicAdd(&scnt[3], 1u);
      if (e < 2048u) hist[e] = candi[j];
    }
  }
  __syncthreads();
  if (tid < 64) {
    const int tc = (int)min(scnt[3], 2048u);
    const int base2 = base1 + (int)scnt[2];
    for (int j = 0; j < (int)krem; ++j) {
      int best = 0x7FFFFFFF;
      for (int q = lane; q < tc; q += 64) best = min(best, (int)hist[q]);
      for (int mm = 32; mm; mm >>= 1) best = min(best, __shfl_xor(best, mm));
      for (int q = lane; q < tc; q += 64)
        if ((int)hist[q] == best) hist[q] = 0x7FFFFFFFu;
      if (lane == 0) idxL[base2 + j] = best;
    }
  }
  __syncthreads();
  // ensure all workers' w2t/w3t prep is visible (long done by now)
  if (tid == 0) {
    while (__hip_atomic_load(prepcnt, __ATOMIC_RELAXED, __HIP_MEMORY_SCOPE_AGENT) < 128u)
      __builtin_amdgcn_s_sleep(8);
    (void)__hip_atomic_load(prepcnt, __ATOMIC_ACQUIRE, __HIP_MEMORY_SCOPE_AGENT);
  }
  __syncthreads();
  // ---- mlp phase (reuses buf) ----
  short* h1 = (short*)buf;                    // [128*72]
  short* h2 = (short*)(buf + 18432);          // [128*136]
  float* cxs = (float*)(buf + 53248);
  float* cys = (float*)(buf + 53760);
  float* czs = (float*)(buf + 54272);
  unsigned* gmaxL = (unsigned*)(buf + 54784); // [1024]
  gmaxL[tid] = 0u;
  const int cB = lane & 15, kB = (lane >> 4) * 8, r0 = (lane >> 4) * 4;
  const int rowblk = wv & 7, nh = wv >> 3;
  for (int t = 0; t < 8; ++t) {
    __syncthreads();
    if (tid < 128) {
      int pt = idxL[t * 128 + tid];
      cxs[tid] = xs[pt]; cys[tid] = ys[pt]; czs[tid] = zs[pt];
    }
    __syncthreads();
    {
      const int pg = tid >> 6;
      for (int q = 0; q < 8; ++q) {
        int pr = pg * 8 + q;
        float v = fmaxf(__fmaf_rn(cxs[pr], w10, __fmaf_rn(cys[pr], w11, czs[pr] * w12)), 0.f);
        h1[pr * 72 + ch] = (short)f2bf(v);
      }
    }
    __syncthreads();
    {
      short8 a[2];
#pragma unroll
      for (int ks = 0; ks < 2; ++ks)
        a[ks] = *(const short8*)&h1[(rowblk * 16 + cB) * 72 + kB + ks * 32];
#pragma unroll
      for (int n0 = nh * 4; n0 < nh * 4 + 4; ++n0) {
        short8 bb[2];
#pragma unroll
        for (int ks = 0; ks < 2; ++ks)
          bb[ks] = *(const short8*)&w2t[(n0 * 16 + cB) * 64 + kB + ks * 32];
        f32x4 acc = {0.f, 0.f, 0.f, 0.f};
        acc = mfma16(a[0], bb[0], acc);
        acc = mfma16(a[1], bb[1], acc);
#pragma unroll
        for (int r = 0; r < 4; ++r)
          h2[(rowblk * 16 + r0 + r) * 136 + n0 * 16 + cB] = (short)f2bf(fmaxf(acc[r], 0.f));
      }
    }
    __syncthreads();
    {
      short8 a2[4];
#pragma unroll
      for (int ks = 0; ks < 4; ++ks)
        a2[ks] = *(const short8*)&h2[(rowblk * 16 + cB) * 136 + kB + ks * 32];
      for (int n0 = nh * 32; n0 < nh * 32 + 32; ++n0) {
        short8 b3[4];
#pragma unroll
        for (int ks = 0; ks < 4; ++ks)
          b3[ks] = *(const short8*)&w3t[(n0 * 16 + cB) * 128 + kB + ks * 32];
        f32x4 acc = {0.f, 0.f, 0.f, 0.f};
#pragma unroll
        for (int ks = 0; ks < 4; ++ks) acc = mfma16(a2[ks], b3[ks], acc);
        float mv = fmaxf(fmaxf(acc[0], acc[1]), fmaxf(acc[2], acc[3]));
        mv = fmaxf(mv, __shfl_xor(mv, 16));
        mv = fmaxf(mv, __shfl_xor(mv, 32));
        if (lane < 16) atomicMax(&gmaxL[n0 * 16 + lane], ordenc(mv));
      }
    }
  }
  __syncthreads();
  {
    unsigned mm = gmaxL[tid];
    out[g * 1024 + tid] = (mm >> 31) ? __uint_as_float(mm ^ 0x80000000u)
                                     : __uint_as_float(~mm);
  }
}

extern "C" void kernel_launch(void* const* d_in, const int* in_sizes, int n_in,
                              void* d_out, int out_size, void* d_ws, size_t ws_size,
                              hipStream_t stream) {
  (void)in_sizes; (void)n_in; (void)out_size; (void)ws_size;
  const float* pc = (const float*)d_in[0];
  const float* w1 = (const float*)d_in[1];
  const float* w2 = (const float*)d_in[2];
  const float* w3 = (const float*)d_in[3];
  float* out = (float*)d_out;
  char* ws = (char*)d_ws;

  unsigned* cnts = (unsigned*)(ws + 0);       // centroid counter at [4]
  unsigned* prepcnt = (unsigned*)(ws + 64);   // prep barrier counter
  ull* kslots = (ull*)(ws + 128);             // 16 ull = one 128B line
  ull* mb = (ull*)(ws + 1024);                // 512 ull group mailboxes
  ull* cslots = (ull*)(ws + 5632);            // 48 ull centroid partials
  unsigned short* w2t = (unsigned short*)(ws + 8192);    // 16 KiB
  unsigned short* w3t = (unsigned short*)(ws + 24576);   // 256 KiB

  hipMemsetAsync(ws, 0, 8192, stream);
  fused_kernel<<<FPS_B + NG, 1024, 0, stream>>>(pc, w1, w2, w3, w2t, w3t, out,
                                                cnts, prepcnt, kslots, mb, cslots);
}

// Round 10
// 1193.548 us; speedup vs baseline: 1.2041x; 1.0143x over previous
//
#include <hip/hip_runtime.h>

#define N_PTS 262144
#define NG 128
#define GS 1024
#define FPS_B 16

typedef __attribute__((ext_vector_type(8))) short short8;
typedef __attribute__((ext_vector_type(8))) __bf16 bf16x8;
typedef __attribute__((ext_vector_type(4))) float f32x4;
typedef unsigned long long ull;

__device__ __forceinline__ unsigned short f2bf(float f) {
  unsigned u = __float_as_uint(f);
  unsigned r = u + 0x7FFFu + ((u >> 16) & 1u);
  return (unsigned short)(r >> 16);
}

__device__ __forceinline__ f32x4 mfma16(short8 a, short8 b, f32x4 c) {
  return __builtin_amdgcn_mfma_f32_16x16x32_bf16(
      __builtin_bit_cast(bf16x8, a), __builtin_bit_cast(bf16x8, b), c, 0, 0, 0);
}

__device__ __forceinline__ ull shfl_xor_u64(ull v, int m) {
  unsigned lo = __shfl_xor((unsigned)v, m);
  unsigned hi = __shfl_xor((unsigned)(v >> 32), m);
  return ((ull)hi << 32) | lo;
}

__device__ __forceinline__ void st64(ull* p, ull v) {
  __hip_atomic_store(p, v, __ATOMIC_RELAXED, __HIP_MEMORY_SCOPE_AGENT);
}
__device__ __forceinline__ ull ld64(const ull* p) {
  return __hip_atomic_load(p, __ATOMIC_RELAXED, __HIP_MEMORY_SCOPE_AGENT);
}

__device__ __forceinline__ unsigned ordenc(float f) {
  unsigned u = __float_as_uint(f);
  return (u >> 31) ? ~u : (u | 0x80000000u);
}

__device__ __forceinline__ unsigned knn_key(float x, float y, float z, float pp,
                                            float sx, float sy, float sz, float s2) {
  float dot = __fmaf_rn(sx, x, __fmaf_rn(sy, y, __fmul_rn(sz, z)));
  float d2 = __fadd_rn(__fsub_rn(s2, __fadd_rn(dot, dot)), pp);
  return ordenc(d2);
}

__device__ __forceinline__ void select_bucket(const unsigned* hist, int nbins,
                                              unsigned krem, unsigned* sres, int lane) {
  const int per = nbins >> 6;
  unsigned local = 0;
  for (int j = 0; j < per; ++j) local += hist[lane * per + j];
  unsigned inc = local;
  for (int off = 1; off < 64; off <<= 1) {
    unsigned v = __shfl_up(inc, off);
    if (lane >= off) inc += v;
  }
  unsigned exc = inc - local;
  if (exc < krem && krem <= inc) {
    unsigned c = exc;
    for (int j = 0; j < per; ++j) {
      unsigned h = hist[lane * per + j];
      if (c + h >= krem) { sres[0] = (unsigned)(lane * per + j); sres[1] = c; break; }
      c += h;
    }
  }
}

// fused: fps (blocks 0..15, single-line depth-2 exchange) + workers (16..143)
// serialized behind fps. kslots[2][16]: {seq:14|dist:32|~idx:18} per parity line.
// mb[g*4+c] = {coord:32|seq:32}; mb[508..510] (g=127) doubles as the done flag.
__global__ void __launch_bounds__(1024) fused_kernel(const float* __restrict__ pc,
    const float* __restrict__ w1, const float* __restrict__ w2,
    const float* __restrict__ w3, unsigned short* __restrict__ w2t,
    unsigned short* __restrict__ w3t, float* __restrict__ out,
    unsigned* __restrict__ cnts, unsigned* __restrict__ prepcnt,
    ull* __restrict__ kslots, ull* __restrict__ mb, ull* __restrict__ cslots) {
  __shared__ __align__(16) char buf[73728];
  __shared__ int idxL[1024];
  __shared__ unsigned sres[2];
  __shared__ unsigned scnt[4];
  __shared__ float mbx[3];
  __shared__ float rs[3][16];
  __shared__ float bc[3];
  __shared__ ull wkeyL[16];

  const int tid = threadIdx.x, lane = tid & 63, wv = tid >> 6;
  const float* xs = pc;
  const float* ys = pc + N_PTS;
  const float* zs = pc + 2 * N_PTS;

  if (blockIdx.x < FPS_B) {
    // ===================== FPS role =====================
    const int p = blockIdx.x;
    const int gt = p * 1024 + tid;
    float* sampled_out = out + 131072;
    float x[16], y[16], z[16], md[16];
    float sx = 0.f, sy = 0.f, sz = 0.f;
#pragma unroll
    for (int j = 0; j < 16; ++j) {
      int i = gt + j * 16384;
      x[j] = xs[i]; y[j] = ys[i]; z[j] = zs[i];
      sx += x[j]; sy += y[j]; sz += z[j];
    }
#pragma unroll
    for (int m = 32; m; m >>= 1) {
      sx += __shfl_xor(sx, m); sy += __shfl_xor(sy, m); sz += __shfl_xor(sz, m);
    }
    if (lane == 0) { rs[0][wv] = sx; rs[1][wv] = sy; rs[2][wv] = sz; }
    __syncthreads();
    if (tid == 0) {
      float ax = 0.f, ay = 0.f, az = 0.f;
      for (int w = 0; w < 16; ++w) { ax += rs[0][w]; ay += rs[1][w]; az += rs[2][w]; }
      st64(&cslots[0 + p], (ull)__float_as_uint(ax));
      st64(&cslots[16 + p], (ull)__float_as_uint(ay));
      st64(&cslots[32 + p], (ull)__float_as_uint(az));
      __hip_atomic_fetch_add(&cnts[4], 1u, __ATOMIC_RELEASE, __HIP_MEMORY_SCOPE_AGENT);
    }
    if (wv == 0) {
      while (__hip_atomic_load(&cnts[4], __ATOMIC_RELAXED, __HIP_MEMORY_SCOPE_AGENT) < 16u)
        __builtin_amdgcn_s_sleep(1);
      (void)__hip_atomic_load(&cnts[4], __ATOMIC_ACQUIRE, __HIP_MEMORY_SCOPE_AGENT);
      float f = 0.f;
      if (lane < 48) f = __uint_as_float((unsigned)ld64(&cslots[lane]));
      float s = 0.f;
      for (int q = 0; q < 16; ++q) s += __shfl(f, (lane & 48) + q);  // ascending
      if (lane == 0)  bc[0] = s * (1.f / N_PTS);
      if (lane == 16) bc[1] = s * (1.f / N_PTS);
      if (lane == 32) bc[2] = s * (1.f / N_PTS);
    }
    __syncthreads();
    ull lkey = 0ull;
    {
      float cx = bc[0], cy = bc[1], cz = bc[2];
#pragma unroll
      for (int j = 0; j < 16; ++j) {
        float dx = x[j] - cx, dy = y[j] - cy, dz = z[j] - cz;
        float d = sqrtf(dx * dx + dy * dy + dz * dz);
        md[j] = d;
        unsigned fb = __float_as_uint(d);
        ull k = ((ull)fb << 18) | (ull)(0x3FFFFu ^ (unsigned)(gt + j * 16384));
        if (k > lkey) lkey = k;
      }
    }
    for (int sel = 0; sel < NG; ++sel) {
      const ull seq = (ull)(sel + 1);
      ull rk = lkey;
#pragma unroll
      for (int m = 32; m; m >>= 1) {
        ull o = shfl_xor_u64(rk, m);
        if (o > rk) rk = o;
      }
      if (lane == 0) wkeyL[wv] = rk;
      __syncthreads();
      if (wv == 0) {
        const int pb = (sel & 1) * 16;  // depth-2 parity line
        ull bk = (lane < 16) ? wkeyL[lane] : 0ull;
#pragma unroll
        for (int m = 8; m; m >>= 1) {
          ull o = shfl_xor_u64(bk, m);
          if (o > bk) bk = o;
        }
        if (lane == 0) st64(&kslots[pb + p], (seq << 50) | bk);
        ull v = 0ull;
        for (;;) {  // poll one 128B line
          if (lane < 16) v = ld64(&kslots[pb + lane]);
          bool ok = (lane >= 16) || ((v >> 50) == seq);
          if (__all((int)ok)) break;
          __builtin_amdgcn_s_sleep(1);
        }
        ull gk = (lane < 16) ? v : 0ull;
#pragma unroll
        for (int m = 32; m; m >>= 1) {
          ull o = shfl_xor_u64(gk, m);
          if (o > gk) gk = o;
        }
        unsigned wi = 0x3FFFFu ^ (unsigned)(gk & 0x3FFFFull);
        if (lane < 3) {
          float c = pc[lane * N_PTS + wi];  // clean L2-resident fetch
          bc[lane] = c;
          if (p == 0) {
            sampled_out[sel * 3 + lane] = c;
            st64(&mb[sel * 4 + lane], ((ull)__float_as_uint(c) << 32) | seq);
          }
        }
      }
      __syncthreads();
      {  // fused md-update + next-step candidate
        float wx = bc[0], wy = bc[1], wz = bc[2];
        ull nk = 0ull;
#pragma unroll
        for (int j = 0; j < 16; ++j) {
          float dx = x[j] - wx, dy = y[j] - wy, dz = z[j] - wz;
          float d = sqrtf(dx * dx + dy * dy + dz * dz);
          float m = (sel == 0) ? d : fminf(md[j], d);
          md[j] = m;
          unsigned fb = __float_as_uint(m);
          ull k = ((ull)fb << 18) | (ull)(0x3FFFFu ^ (unsigned)(gt + j * 16384));
          if (k > nk) nk = k;
        }
        lkey = nk;
      }
    }
    return;
  }

  // ===================== worker role (serialized behind fps) ==================
  const int g = blockIdx.x - FPS_B;
  unsigned* hist = (unsigned*)buf;            // [2048]
  unsigned* candk = (unsigned*)(buf + 8192);  // [8192]
  unsigned* candi = (unsigned*)(buf + 40960); // [8192]
  const int ch = tid & 63;
  const float w10 = w1[ch], w11 = w1[64 + ch], w12 = w1[128 + ch];
  // prep slices (w3t/w2t transpose) — hidden under fps
  {
    int i3 = g * 1024 + tid;
    { int n = i3 >> 7, k = i3 & 127; w3t[i3] = f2bf(w3[k * 1024 + n]); }
    if (tid < 64) { int i2 = g * 64 + tid; int n = i2 >> 6, k = i2 & 63; w2t[i2] = f2bf(w2[k * 128 + n]); }
  }
  __syncthreads();
  if (tid == 0)
    __hip_atomic_fetch_add(prepcnt, 1u, __ATOMIC_RELEASE, __HIP_MEMORY_SCOPE_AGENT);
  // LDS init while fps runs
  for (int i = tid; i < 2048; i += 1024) hist[i] = 0u;
  if (tid == 0) { scnt[0] = 0u; scnt[1] = 0u; scnt[2] = 0u; scnt[3] = 0u; }
  // gate: wait for fps completion (g=127 mailbox carries seq 128)
  if (tid < 3) {
    for (;;) {
      if ((unsigned)ld64(&mb[508 + tid]) == 128u) break;
      __builtin_amdgcn_s_sleep(127);
    }
    ull v;
    do { v = ld64(&mb[g * 4 + tid]); } while ((unsigned)v != (unsigned)(g + 1));
    mbx[tid] = __uint_as_float((unsigned)(v >> 32));
  }
  __syncthreads();

  const float sx = mbx[0], sy = mbx[1], sz = mbx[2];
  const float s2 = __fadd_rn(__fadd_rn(__fmul_rn(sx, sx), __fmul_rn(sy, sy)),
                             __fmul_rn(sz, sz));
  const f32x4* xs4 = (const f32x4*)xs;
  const f32x4* ys4 = (const f32x4*)ys;
  const f32x4* zs4 = (const f32x4*)zs;
  // scan 1: histogram (vectorized 4 pts/thread/iter)
  for (int it = 0; it < 64; ++it) {
    int i4 = it * 1024 + tid;
    f32x4 xv = xs4[i4], yv = ys4[i4], zv = zs4[i4];
#pragma unroll
    for (int u = 0; u < 4; ++u) {
      float pp = __fadd_rn(__fadd_rn(__fmul_rn(xv[u], xv[u]), __fmul_rn(yv[u], yv[u])),
                           __fmul_rn(zv[u], zv[u]));
      unsigned k = knn_key(xv[u], yv[u], zv[u], pp, sx, sy, sz, s2);
      atomicAdd(&hist[k >> 21], 1u);
    }
  }
  __syncthreads();
  if (tid < 64) select_bucket(hist, 2048, GS, sres, lane);
  __syncthreads();
  const unsigned b0 = sres[0];
  unsigned krem = GS - sres[1];
  __syncthreads();
  // scan 2: emit + compact
  for (int it = 0; it < 64; ++it) {
    int i4 = it * 1024 + tid;
    f32x4 xv = xs4[i4], yv = ys4[i4], zv = zs4[i4];
#pragma unroll
    for (int u = 0; u < 4; ++u) {
      float pp = __fadd_rn(__fadd_rn(__fmul_rn(xv[u], xv[u]), __fmul_rn(yv[u], yv[u])),
                           __fmul_rn(zv[u], zv[u]));
      unsigned k = knn_key(xv[u], yv[u], zv[u], pp, sx, sy, sz, s2);
      unsigned b = k >> 21;
      if (b < b0) {
        unsigned pos = atomicAdd(&scnt[0], 1u);
        idxL[pos] = i4 * 4 + u;
      } else if (b == b0) {
        unsigned e = atomicAdd(&scnt[1], 1u);
        if (e < 8192u) { candk[e] = k; candi[e] = i4 * 4 + u; }
      }
    }
  }
  __syncthreads();
  const int m = (int)min(scnt[1], 8192u);
  const int base1 = (int)scnt[0];
  for (int i = tid; i < 2048; i += 1024) hist[i] = 0u;
  __syncthreads();
  for (int j = tid; j < m; j += 1024) atomicAdd(&hist[(candk[j] >> 10) & 2047u], 1u);
  __syncthreads();
  if (tid < 64) select_bucket(hist, 2048, krem, sres, lane);
  __syncthreads();
  const unsigned b2 = sres[0];
  krem -= sres[1];
  __syncthreads();
  if (tid < 1024) hist[tid] = 0u;
  __syncthreads();
  for (int j = tid; j < m; j += 1024)
    if (((candk[j] >> 10) & 2047u) == b2) atomicAdd(&hist[candk[j] & 1023u], 1u);
  __syncthreads();
  if (tid < 64) select_bucket(hist, 1024, krem, sres, lane);
  __syncthreads();
  const unsigned b3 = sres[0];
  krem -= sres[1];
  const unsigned T = (b0 << 21) | (b2 << 10) | b3;
  __syncthreads();
  for (int j = tid; j < m; j += 1024) {
    unsigned k = candk[j];
    if (k < T) {
      unsigned pos = atomicAdd(&scnt[2], 1u);
      idxL[base1 + (int)pos] = candi[j];
    } else if (k == T) {
      unsigned e = atomicAdd(&scnt[3], 1u);
      if (e < 2048u) hist[e] = candi[j];
    }
  }
  __syncthreads();
  if (tid < 64) {
    const int tc = (int)min(scnt[3], 2048u);
    const int base2 = base1 + (int)scnt[2];
    for (int j = 0; j < (int)krem; ++j) {
      int best = 0x7FFFFFFF;
      for (int q = lane; q < tc; q += 64) best = min(best, (int)hist[q]);
      for (int mm = 32; mm; mm >>= 1) best = min(best, __shfl_xor(best, mm));
      for (int q = lane; q < tc; q += 64)
        if ((int)hist[q] == best) hist[q] = 0x7FFFFFFFu;
      if (lane == 0) idxL[base2 + j] = best;
    }
  }
  __syncthreads();
  // ensure all workers' w2t/w3t prep is visible (done long ago)
  if (tid == 0) {
    while (__hip_atomic_load(prepcnt, __ATOMIC_RELAXED, __HIP_MEMORY_SCOPE_AGENT) < 128u)
      __builtin_amdgcn_s_sleep(8);
    (void)__hip_atomic_load(prepcnt, __ATOMIC_ACQUIRE, __HIP_MEMORY_SCOPE_AGENT);
  }
  __syncthreads();
  // ---- mlp phase (reuses buf) ----
  short* h1 = (short*)buf;                    // [128*72]  0..18431
  short* h2 = (short*)(buf + 18432);          // [128*136] ..53247
  float* cxs = (float*)(buf + 53248);         // [1024]
  float* cys = (float*)(buf + 57344);         // [1024]
  float* czs = (float*)(buf + 61440);         // [1024]
  unsigned* gmaxL = (unsigned*)(buf + 65536); // [1024]
  gmaxL[tid] = 0u;
  {
    int pt = idxL[tid];  // one upfront gather for all 1024 points
    cxs[tid] = xs[pt]; cys[tid] = ys[pt]; czs[tid] = zs[pt];
  }
  const int cB = lane & 15, kB = (lane >> 4) * 8, r0 = (lane >> 4) * 4;
  const int rowblk = wv & 7, nh = wv >> 3;
  for (int t = 0; t < 8; ++t) {
    __syncthreads();
    {
      const int pg = tid >> 6;
      for (int q = 0; q < 8; ++q) {
        int pr = pg * 8 + q;
        float v = fmaxf(__fmaf_rn(cxs[t * 128 + pr], w10,
                                  __fmaf_rn(cys[t * 128 + pr], w11,
                                            czs[t * 128 + pr] * w12)), 0.f);
        h1[pr * 72 + ch] = (short)f2bf(v);
      }
    }
    __syncthreads();
    {
      short8 a[2];
#pragma unroll
      for (int ks = 0; ks < 2; ++ks)
        a[ks] = *(const short8*)&h1[(rowblk * 16 + cB) * 72 + kB + ks * 32];
#pragma unroll
      for (int n0 = nh * 4; n0 < nh * 4 + 4; ++n0) {
        short8 bb[2];
#pragma unroll
        for (int ks = 0; ks < 2; ++ks)
          bb[ks] = *(const short8*)&w2t[(n0 * 16 + cB) * 64 + kB + ks * 32];
        f32x4 acc = {0.f, 0.f, 0.f, 0.f};
        acc = mfma16(a[0], bb[0], acc);
        acc = mfma16(a[1], bb[1], acc);
#pragma unroll
        for (int r = 0; r < 4; ++r)
          h2[(rowblk * 16 + r0 + r) * 136 + n0 * 16 + cB] = (short)f2bf(fmaxf(acc[r], 0.f));
      }
    }
    __syncthreads();
    {
      short8 a2[4];
#pragma unroll
      for (int ks = 0; ks < 4; ++ks)
        a2[ks] = *(const short8*)&h2[(rowblk * 16 + cB) * 136 + kB + ks * 32];
      for (int n0 = nh * 32; n0 < nh * 32 + 32; ++n0) {
        short8 b3[4];
#pragma unroll
        for (int ks = 0; ks < 4; ++ks)
          b3[ks] = *(const short8*)&w3t[(n0 * 16 + cB) * 128 + kB + ks * 32];
        f32x4 acc = {0.f, 0.f, 0.f, 0.f};
#pragma unroll
        for (int ks = 0; ks < 4; ++ks) acc = mfma16(a2[ks], b3[ks], acc);
        float mv = fmaxf(fmaxf(acc[0], acc[1]), fmaxf(acc[2], acc[3]));
        mv = fmaxf(mv, __shfl_xor(mv, 16));
        mv = fmaxf(mv, __shfl_xor(mv, 32));
        if (lane < 16) atomicMax(&gmaxL[n0 * 16 + lane], ordenc(mv));
      }
    }
  }
  __syncthreads();
  {
    unsigned mm = gmaxL[tid];
    out[g * 1024 + tid] = (mm >> 31) ? __uint_as_float(mm ^ 0x80000000u)
                                     : __uint_as_float(~mm);
  }
}

extern "C" void kernel_launch(void* const* d_in, const int* in_sizes, int n_in,
                              void* d_out, int out_size, void* d_ws, size_t ws_size,
                              hipStream_t stream) {
  (void)in_sizes; (void)n_in; (void)out_size; (void)ws_size;
  const float* pc = (const float*)d_in[0];
  const float* w1 = (const float*)d_in[1];
  const float* w2 = (const float*)d_in[2];
  const float* w3 = (const float*)d_in[3];
  float* out = (float*)d_out;
  char* ws = (char*)d_ws;

  unsigned* cnts = (unsigned*)(ws + 0);       // centroid counter at [4]
  unsigned* prepcnt = (unsigned*)(ws + 64);   // prep barrier counter
  ull* kslots = (ull*)(ws + 128);             // 32 ull = two 128B parity lines
  ull* mb = (ull*)(ws + 1024);                // 512 ull group mailboxes
  ull* cslots = (ull*)(ws + 5632);            // 48 ull centroid partials
  unsigned short* w2t = (unsigned short*)(ws + 8192);    // 16 KiB
  unsigned short* w3t = (unsigned short*)(ws + 24576);   // 256 KiB

  hipMemsetAsync(ws, 0, 8192, stream);
  fused_kernel<<<FPS_B + NG, 1024, 0, stream>>>(pc, w1, w2, w3, w2t, w3t, out,
                                                cnts, prepcnt, kslots, mb, cslots);
}

// Round 11
// 859.110 us; speedup vs baseline: 1.6728x; 1.3893x over previous
//
#include <hip/hip_runtime.h>

#define N_PTS 262144
#define NG 128
#define GS 1024
#define FPS_B 16

typedef __attribute__((ext_vector_type(8))) short short8;
typedef __attribute__((ext_vector_type(8))) __bf16 bf16x8;
typedef __attribute__((ext_vector_type(4))) float f32x4;
typedef unsigned long long ull;

__device__ __forceinline__ unsigned short f2bf(float f) {
  unsigned u = __float_as_uint(f);
  unsigned r = u + 0x7FFFu + ((u >> 16) & 1u);
  return (unsigned short)(r >> 16);
}

__device__ __forceinline__ f32x4 mfma16(short8 a, short8 b, f32x4 c) {
  return __builtin_amdgcn_mfma_f32_16x16x32_bf16(
      __builtin_bit_cast(bf16x8, a), __builtin_bit_cast(bf16x8, b), c, 0, 0, 0);
}

__device__ __forceinline__ ull shfl_xor_u64(ull v, int m) {
  unsigned lo = __shfl_xor((unsigned)v, m);
  unsigned hi = __shfl_xor((unsigned)(v >> 32), m);
  return ((ull)hi << 32) | lo;
}

__device__ __forceinline__ void st64(ull* p, ull v) {
  __hip_atomic_store(p, v, __ATOMIC_RELAXED, __HIP_MEMORY_SCOPE_AGENT);
}
__device__ __forceinline__ ull ld64(const ull* p) {
  return __hip_atomic_load(p, __ATOMIC_RELAXED, __HIP_MEMORY_SCOPE_AGENT);
}

// ordered-uint encode for float (monotone for all finite floats)
__device__ __forceinline__ unsigned ordenc(float f) {
  unsigned u = __float_as_uint(f);
  return (u >> 31) ? ~u : (u | 0x80000000u);
}

__device__ __forceinline__ unsigned knn_key(float x, float y, float z, float pp,
                                            float sx, float sy, float sz, float s2) {
  float dot = __fmaf_rn(sx, x, __fmaf_rn(sy, y, __fmul_rn(sz, z)));
  float d2 = __fadd_rn(__fsub_rn(s2, __fadd_rn(dot, dot)), pp);
  return ordenc(d2);
}

// ---------------- prep: bf16 transposed weights only -------------------------
__global__ void __launch_bounds__(256) prep_kernel(const float* __restrict__ w2,
    const float* __restrict__ w3, unsigned short* __restrict__ w2t,
    unsigned short* __restrict__ w3t) {
  int i = blockIdx.x * 256 + threadIdx.x;
  if (i < 131072) { int n = i >> 7, k = i & 127; w3t[i] = f2bf(w3[k * 1024 + n]); }
  if (i < 8192)  { int n = i >> 6, k = i & 63;  w2t[i] = f2bf(w2[k * 128 + n]); }
}

// ---------------- FPS: single-line depth-2 exchange (R5 protocol + parity) ---
// kslots[2][16]: {seq:14|dist:32|~idx:18} per parity line, relaxed stores.
__global__ void __launch_bounds__(1024) fps_kernel(const float* __restrict__ pc,
    float* __restrict__ sampled_out, unsigned* __restrict__ cnts,
    ull* __restrict__ kslots, ull* __restrict__ cslots) {
  const int p = blockIdx.x;
  const int tid = threadIdx.x;
  const int lane = tid & 63, wv = tid >> 6;
  const int gt = p * 1024 + tid;
  const float* xs = pc;
  const float* ys = pc + N_PTS;
  const float* zs = pc + 2 * N_PTS;
  float x[16], y[16], z[16], md[16];
  float sx = 0.f, sy = 0.f, sz = 0.f;
#pragma unroll
  for (int j = 0; j < 16; ++j) {
    int i = gt + j * 16384;
    x[j] = xs[i]; y[j] = ys[i]; z[j] = zs[i];
    sx += x[j]; sy += y[j]; sz += z[j];
  }
#pragma unroll
  for (int m = 32; m; m >>= 1) {
    sx += __shfl_xor(sx, m); sy += __shfl_xor(sy, m); sz += __shfl_xor(sz, m);
  }
  __shared__ float rs[3][16];
  __shared__ ull wkeyL[16];
  __shared__ float bc[3];
  if (lane == 0) { rs[0][wv] = sx; rs[1][wv] = sy; rs[2][wv] = sz; }
  __syncthreads();
  if (tid == 0) {
    float ax = 0.f, ay = 0.f, az = 0.f;
    for (int w = 0; w < 16; ++w) { ax += rs[0][w]; ay += rs[1][w]; az += rs[2][w]; }
    st64(&cslots[0 + p], (ull)__float_as_uint(ax));
    st64(&cslots[16 + p], (ull)__float_as_uint(ay));
    st64(&cslots[32 + p], (ull)__float_as_uint(az));
    __hip_atomic_fetch_add(&cnts[4], 1u, __ATOMIC_RELEASE, __HIP_MEMORY_SCOPE_AGENT);
  }
  if (wv == 0) {
    while (__hip_atomic_load(&cnts[4], __ATOMIC_RELAXED, __HIP_MEMORY_SCOPE_AGENT) < 16u)
      __builtin_amdgcn_s_sleep(1);
    (void)__hip_atomic_load(&cnts[4], __ATOMIC_ACQUIRE, __HIP_MEMORY_SCOPE_AGENT);
    float f = 0.f;
    if (lane < 48) f = __uint_as_float((unsigned)ld64(&cslots[lane]));
    float s = 0.f;
    for (int q = 0; q < 16; ++q) s += __shfl(f, (lane & 48) + q);  // ascending order
    if (lane == 0)  bc[0] = s * (1.f / N_PTS);
    if (lane == 16) bc[1] = s * (1.f / N_PTS);
    if (lane == 32) bc[2] = s * (1.f / N_PTS);
  }
  __syncthreads();
  ull lkey = 0ull;
  {
    float cx = bc[0], cy = bc[1], cz = bc[2];
#pragma unroll
    for (int j = 0; j < 16; ++j) {
      float dx = x[j] - cx, dy = y[j] - cy, dz = z[j] - cz;
      float d = sqrtf(dx * dx + dy * dy + dz * dz);
      md[j] = d;
      unsigned fb = __float_as_uint(d);
      ull k = ((ull)fb << 18) | (ull)(0x3FFFFu ^ (unsigned)(gt + j * 16384));
      if (k > lkey) lkey = k;
    }
  }
  for (int sel = 0; sel < NG; ++sel) {
    const ull seq = (ull)(sel + 1);
    ull rk = lkey;
#pragma unroll
    for (int m = 32; m; m >>= 1) {
      ull o = shfl_xor_u64(rk, m);
      if (o > rk) rk = o;
    }
    if (lane == 0) wkeyL[wv] = rk;
    __syncthreads();
    if (wv == 0) {
      const int pb = (sel & 1) * 16;  // depth-2 parity line
      ull bk = (lane < 16) ? wkeyL[lane] : 0ull;
#pragma unroll
      for (int m = 8; m; m >>= 1) {
        ull o = shfl_xor_u64(bk, m);
        if (o > bk) bk = o;
      }
      if (lane == 0) st64(&kslots[pb + p], (seq << 50) | bk);  // fire-and-forget
      ull v = 0ull;
      for (;;) {  // poll one 128B line
        if (lane < 16) v = ld64(&kslots[pb + lane]);
        bool ok = (lane >= 16) || ((v >> 50) == seq);
        if (__all((int)ok)) break;
        __builtin_amdgcn_s_sleep(1);
      }
      ull gk = (lane < 16) ? v : 0ull;
#pragma unroll
      for (int m = 32; m; m >>= 1) {
        ull o = shfl_xor_u64(gk, m);
        if (o > gk) gk = o;
      }
      unsigned wi = 0x3FFFFu ^ (unsigned)(gk & 0x3FFFFull);
      if (lane < 3) {
        float c = pc[lane * N_PTS + wi];  // clean L2-resident fetch
        bc[lane] = c;
        if (p == 0) sampled_out[sel * 3 + lane] = c;
      }
    }
    __syncthreads();
    {  // fused md-update + next-step candidate
      float wx = bc[0], wy = bc[1], wz = bc[2];
      ull nk = 0ull;
#pragma unroll
      for (int j = 0; j < 16; ++j) {
        float dx = x[j] - wx, dy = y[j] - wy, dz = z[j] - wz;
        float d = sqrtf(dx * dx + dy * dy + dz * dz);
        float m = (sel == 0) ? d : fminf(md[j], d);
        md[j] = m;
        unsigned fb = __float_as_uint(m);
        ull k = ((ull)fb << 18) | (ull)(0x3FFFFu ^ (unsigned)(gt + j * 16384));
        if (k > nk) nk = k;
      }
      lkey = nk;
    }
  }
}

// ---------------- KNN: vectorized 2-scan radix select, p2 inline -------------
__device__ __forceinline__ void select_bucket(const unsigned* hist, int nbins,
                                              unsigned krem, unsigned* sres, int lane) {
  const int per = nbins >> 6;
  unsigned local = 0;
  for (int j = 0; j < per; ++j) local += hist[lane * per + j];
  unsigned inc = local;
  for (int off = 1; off < 64; off <<= 1) {
    unsigned v = __shfl_up(inc, off);
    if (lane >= off) inc += v;
  }
  unsigned exc = inc - local;
  if (exc < krem && krem <= inc) {
    unsigned c = exc;
    for (int j = 0; j < per; ++j) {
      unsigned h = hist[lane * per + j];
      if (c + h >= krem) { sres[0] = (unsigned)(lane * per + j); sres[1] = c; break; }
      c += h;
    }
  }
}

__global__ void __launch_bounds__(1024) knn_kernel(const float* __restrict__ pc,
    const float* __restrict__ sampled, int* __restrict__ knn) {
  const int g = blockIdx.x;
  const int tid = threadIdx.x;
  const int lane = tid & 63;
  __shared__ unsigned hist[2048];
  __shared__ unsigned candk[8192];
  __shared__ unsigned candi[8192];
  __shared__ unsigned sres[2];
  __shared__ unsigned scnt[4];
  const f32x4* xs4 = (const f32x4*)pc;
  const f32x4* ys4 = (const f32x4*)(pc + N_PTS);
  const f32x4* zs4 = (const f32x4*)(pc + 2 * N_PTS);
  const float sx = sampled[g * 3 + 0], sy = sampled[g * 3 + 1], sz = sampled[g * 3 + 2];
  const float s2 = __fadd_rn(__fadd_rn(__fmul_rn(sx, sx), __fmul_rn(sy, sy)),
                             __fmul_rn(sz, sz));
  for (int i = tid; i < 2048; i += 1024) hist[i] = 0u;
  if (tid == 0) { scnt[0] = 0u; scnt[1] = 0u; scnt[2] = 0u; scnt[3] = 0u; }
  __syncthreads();
  for (int it = 0; it < 64; ++it) {
    int i4 = it * 1024 + tid;
    f32x4 xv = xs4[i4], yv = ys4[i4], zv = zs4[i4];
#pragma unroll
    for (int u = 0; u < 4; ++u) {
      float pp = __fadd_rn(__fadd_rn(__fmul_rn(xv[u], xv[u]), __fmul_rn(yv[u], yv[u])),
                           __fmul_rn(zv[u], zv[u]));
      unsigned k = knn_key(xv[u], yv[u], zv[u], pp, sx, sy, sz, s2);
      atomicAdd(&hist[k >> 21], 1u);
    }
  }
  __syncthreads();
  if (tid < 64) select_bucket(hist, 2048, GS, sres, lane);
  __syncthreads();
  const unsigned b0 = sres[0];
  unsigned krem = GS - sres[1];
  __syncthreads();
  for (int it = 0; it < 64; ++it) {
    int i4 = it * 1024 + tid;
    f32x4 xv = xs4[i4], yv = ys4[i4], zv = zs4[i4];
#pragma unroll
    for (int u = 0; u < 4; ++u) {
      float pp = __fadd_rn(__fadd_rn(__fmul_rn(xv[u], xv[u]), __fmul_rn(yv[u], yv[u])),
                           __fmul_rn(zv[u], zv[u]));
      unsigned k = knn_key(xv[u], yv[u], zv[u], pp, sx, sy, sz, s2);
      unsigned b = k >> 21;
      if (b < b0) {
        unsigned pos = atomicAdd(&scnt[0], 1u);
        knn[g * GS + pos] = i4 * 4 + u;
      } else if (b == b0) {
        unsigned e = atomicAdd(&scnt[1], 1u);
        if (e < 8192u) { candk[e] = k; candi[e] = i4 * 4 + u; }
      }
    }
  }
  __syncthreads();
  const int m = (int)min(scnt[1], 8192u);
  const int base1 = (int)scnt[0];
  for (int i = tid; i < 2048; i += 1024) hist[i] = 0u;
  __syncthreads();
  for (int j = tid; j < m; j += 1024) atomicAdd(&hist[(candk[j] >> 10) & 2047u], 1u);
  __syncthreads();
  if (tid < 64) select_bucket(hist, 2048, krem, sres, lane);
  __syncthreads();
  const unsigned b2 = sres[0];
  krem -= sres[1];
  __syncthreads();
  if (tid < 1024) hist[tid] = 0u;
  __syncthreads();
  for (int j = tid; j < m; j += 1024)
    if (((candk[j] >> 10) & 2047u) == b2) atomicAdd(&hist[candk[j] & 1023u], 1u);
  __syncthreads();
  if (tid < 64) select_bucket(hist, 1024, krem, sres, lane);
  __syncthreads();
  const unsigned b3 = sres[0];
  krem -= sres[1];
  const unsigned T = (b0 << 21) | (b2 << 10) | b3;
  __syncthreads();
  for (int j = tid; j < m; j += 1024) {
    unsigned k = candk[j];
    if (k < T) {
      unsigned pos = atomicAdd(&scnt[2], 1u);
      knn[g * GS + base1 + (int)pos] = candi[j];
    } else if (k == T) {
      unsigned e = atomicAdd(&scnt[3], 1u);
      if (e < 2048u) hist[e] = candi[j];
    }
  }
  __syncthreads();
  if (tid < 64) {
    const int tc = (int)min(scnt[3], 2048u);
    const int base2 = base1 + (int)scnt[2];
    for (int j = 0; j < (int)krem; ++j) {
      int best = 0x7FFFFFFF;
      for (int q = lane; q < tc; q += 64) best = min(best, (int)hist[q]);
      for (int mm = 32; mm; mm >>= 1) best = min(best, __shfl_xor(best, mm));
      for (int q = lane; q < tc; q += 64)
        if ((int)hist[q] == best) hist[q] = 0x7FFFFFFFu;
      if (lane == 0) knn[g * GS + base2 + j] = best;
    }
  }
}

// ---------------- fused MLP (3->64->128->1024) + max-pool, bf16 MFMA ---------
__global__ void __launch_bounds__(256, 2) mlp_kernel(const float* __restrict__ pc,
    const int* __restrict__ knn, const float* __restrict__ w1,
    const unsigned short* __restrict__ w2t, const unsigned short* __restrict__ w3t,
    unsigned* __restrict__ gout) {
  const int blk = blockIdx.x, g = blk >> 2, split = blk & 3;
  const int tid = threadIdx.x, lane = tid & 63, wv = tid >> 6;
  __shared__ unsigned gmax[1024];
  __shared__ __align__(16) short h1[128 * 72];
  __shared__ __align__(16) short h2[128 * 136];
  __shared__ float cxs[128], cys[128], czs[128];
  for (int i = tid; i < 1024; i += 256) gmax[i] = 0u;
  const float* xs = pc;
  const float* ys = pc + N_PTS;
  const float* zs = pc + 2 * N_PTS;
  const int ch = tid & 63;
  const int pgrp = tid >> 6;
  const float w10 = w1[ch], w11 = w1[64 + ch], w12 = w1[128 + ch];
  const int r0 = (lane >> 4) * 4;
  const int cB = lane & 15;
  const int kB = (lane >> 4) * 8;
  for (int tile = 0; tile < 2; ++tile) {
    __syncthreads();
    if (tid < 128) {
      int i = knn[g * 1024 + split * 256 + tile * 128 + tid];
      cxs[tid] = xs[i]; cys[tid] = ys[i]; czs[tid] = zs[i];
    }
    __syncthreads();
    for (int q = 0; q < 32; ++q) {
      int p = pgrp * 32 + q;
      float v = fmaxf(__fmaf_rn(cxs[p], w10, __fmaf_rn(cys[p], w11, czs[p] * w12)), 0.f);
      h1[p * 72 + ch] = (short)f2bf(v);
    }
    __syncthreads();
    {
      short8 a[2][2];
#pragma unroll
      for (int mt = 0; mt < 2; ++mt)
#pragma unroll
        for (int ks = 0; ks < 2; ++ks)
          a[mt][ks] = *(const short8*)&h1[((2 * wv + mt) * 16 + cB) * 72 + kB + ks * 32];
#pragma unroll
      for (int n0 = 0; n0 < 8; ++n0) {
        short8 bb[2];
#pragma unroll
        for (int ks = 0; ks < 2; ++ks)
          bb[ks] = *(const short8*)&w2t[(n0 * 16 + cB) * 64 + kB + ks * 32];
#pragma unroll
        for (int mt = 0; mt < 2; ++mt) {
          f32x4 acc = {0.f, 0.f, 0.f, 0.f};
          acc = mfma16(a[mt][0], bb[0], acc);
          acc = mfma16(a[mt][1], bb[1], acc);
          int rr = (2 * wv + mt) * 16 + r0;
#pragma unroll
          for (int r = 0; r < 4; ++r)
            h2[(rr + r) * 136 + n0 * 16 + cB] = (short)f2bf(fmaxf(acc[r], 0.f));
        }
      }
    }
    __syncthreads();
    {
      short8 a2[2][4];
#pragma unroll
      for (int mt = 0; mt < 2; ++mt)
#pragma unroll
        for (int ks = 0; ks < 4; ++ks)
          a2[mt][ks] = *(const short8*)&h2[((2 * wv + mt) * 16 + cB) * 136 + kB + ks * 32];
      for (int n0 = 0; n0 < 64; ++n0) {
        short8 b3[4];
#pragma unroll
        for (int ks = 0; ks < 4; ++ks)
          b3[ks] = *(const short8*)&w3t[(n0 * 16 + cB) * 128 + kB + ks * 32];
        f32x4 acc0 = {0.f, 0.f, 0.f, 0.f}, acc1 = {0.f, 0.f, 0.f, 0.f};
#pragma unroll
        for (int ks = 0; ks < 4; ++ks) acc0 = mfma16(a2[0][ks], b3[ks], acc0);
#pragma unroll
        for (int ks = 0; ks < 4; ++ks) acc1 = mfma16(a2[1][ks], b3[ks], acc1);
        float mv = fmaxf(fmaxf(fmaxf(acc0[0], acc0[1]), fmaxf(acc0[2], acc0[3])),
                         fmaxf(fmaxf(acc1[0], acc1[1]), fmaxf(acc1[2], acc1[3])));
        mv = fmaxf(mv, __shfl_xor(mv, 16));
        mv = fmaxf(mv, __shfl_xor(mv, 32));
        if (lane < 16) atomicMax(&gmax[n0 * 16 + lane], ordenc(mv));
      }
    }
  }
  __syncthreads();
  for (int i = tid; i < 1024; i += 256)
    gout[(g * 4 + split) * 1024 + i] = gmax[i];
}

// ---------------- combine split partials -> d_out ----------------------------
__global__ void __launch_bounds__(256) combine_kernel(const unsigned* __restrict__ gm,
                                                      float* __restrict__ out) {
  int c = blockIdx.x * 256 + threadIdx.x;
  int g = c >> 10, chn = c & 1023;
  unsigned m = 0u;
#pragma unroll
  for (int s = 0; s < 4; ++s) {
    unsigned v = gm[(g * 4 + s) * 1024 + chn];
    if (v > m) m = v;
  }
  out[c] = (m >> 31) ? __uint_as_float(m ^ 0x80000000u) : __uint_as_float(~m);
}

extern "C" void kernel_launch(void* const* d_in, const int* in_sizes, int n_in,
                              void* d_out, int out_size, void* d_ws, size_t ws_size,
                              hipStream_t stream) {
  (void)in_sizes; (void)n_in; (void)out_size; (void)ws_size;
  const float* pc = (const float*)d_in[0];
  const float* w1 = (const float*)d_in[1];
  const float* w2 = (const float*)d_in[2];
  const float* w3 = (const float*)d_in[3];
  float* out = (float*)d_out;
  char* ws = (char*)d_ws;

  unsigned* cnts = (unsigned*)(ws + 0);        // centroid counter at [4]
  ull* kslots = (ull*)(ws + 128);              // 32 ull = two 128B parity lines
  ull* cslots = (ull*)(ws + 1024);             // 48 ull centroid partials
  unsigned short* w2t = (unsigned short*)(ws + 4096);            // 16 KiB
  unsigned short* w3t = (unsigned short*)(ws + 4096 + 16384);    // 256 KiB
  int* knn = (int*)(ws + 4096 + 16384 + 262144);                 // 512 KiB
  unsigned* gout = (unsigned*)(ws + 4096 + 16384 + 262144 + 524288); // 2 MiB
  float* sampled = out + 131072;

  hipMemsetAsync(ws, 0, 4096, stream);
  prep_kernel<<<512, 256, 0, stream>>>(w2, w3, w2t, w3t);
  fps_kernel<<<FPS_B, 1024, 0, stream>>>(pc, sampled, cnts, kslots, cslots);
  knn_kernel<<<NG, 1024, 0, stream>>>(pc, sampled, knn);
  mlp_kernel<<<NG * 4, 256, 0, stream>>>(pc, knn, w1, w2t, w3t, gout);
  combine_kernel<<<512, 256, 0, stream>>>(gout, out);
}

// Round 12
// 849.529 us; speedup vs baseline: 1.6917x; 1.0113x over previous
//
#include <hip/hip_runtime.h>

#define N_PTS 262144
#define NG 128
#define GS 1024
#define FPS_B 16

typedef __attribute__((ext_vector_type(8))) short short8;
typedef __attribute__((ext_vector_type(8))) __bf16 bf16x8;
typedef __attribute__((ext_vector_type(4))) float f32x4;
typedef unsigned long long ull;

__device__ __forceinline__ unsigned short f2bf(float f) {
  unsigned u = __float_as_uint(f);
  unsigned r = u + 0x7FFFu + ((u >> 16) & 1u);
  return (unsigned short)(r >> 16);
}

__device__ __forceinline__ f32x4 mfma16(short8 a, short8 b, f32x4 c) {
  return __builtin_amdgcn_mfma_f32_16x16x32_bf16(
      __builtin_bit_cast(bf16x8, a), __builtin_bit_cast(bf16x8, b), c, 0, 0, 0);
}

__device__ __forceinline__ ull shfl_xor_u64(ull v, int m) {
  unsigned lo = __shfl_xor((unsigned)v, m);
  unsigned hi = __shfl_xor((unsigned)(v >> 32), m);
  return ((ull)hi << 32) | lo;
}

__device__ __forceinline__ void st64(ull* p, ull v) {
  __hip_atomic_store(p, v, __ATOMIC_RELAXED, __HIP_MEMORY_SCOPE_AGENT);
}
__device__ __forceinline__ ull ld64(const ull* p) {
  return __hip_atomic_load(p, __ATOMIC_RELAXED, __HIP_MEMORY_SCOPE_AGENT);
}

// ordered-uint encode for float (monotone for all finite floats)
__device__ __forceinline__ unsigned ordenc(float f) {
  unsigned u = __float_as_uint(f);
  return (u >> 31) ? ~u : (u | 0x80000000u);
}

__device__ __forceinline__ unsigned knn_key(float x, float y, float z, float pp,
                                            float sx, float sy, float sz, float s2) {
  float dot = __fmaf_rn(sx, x, __fmaf_rn(sy, y, __fmul_rn(sz, z)));
  float d2 = __fadd_rn(__fsub_rn(s2, __fadd_rn(dot, dot)), pp);
  return ordenc(d2);
}

// ---------------- FPS (blocks 0..15) + weight-prep (blocks 16..143) ----------
// kslots[2][16]: {seq:14|dist:32|~idx:18} per parity line, relaxed stores.
__global__ void __launch_bounds__(1024) fps_kernel(const float* __restrict__ pc,
    const float* __restrict__ w2, const float* __restrict__ w3,
    unsigned short* __restrict__ w2t, unsigned short* __restrict__ w3t,
    float* __restrict__ sampled_out, unsigned* __restrict__ cnts,
    ull* __restrict__ kslots, ull* __restrict__ cslots) {
  const int tid = threadIdx.x;
  if (blockIdx.x >= FPS_B) {
    // prep role: transpose weights to bf16, then exit (no exchange participation)
    const int pb = blockIdx.x - FPS_B;
    int i3 = pb * 1024 + tid;  // 128 blocks cover 131072
    { int n = i3 >> 7, k = i3 & 127; w3t[i3] = f2bf(w3[k * 1024 + n]); }
    if (pb < 8) { int i2 = pb * 1024 + tid; int n = i2 >> 6, k = i2 & 63; w2t[i2] = f2bf(w2[k * 128 + n]); }
    return;
  }
  const int p = blockIdx.x;
  const int lane = tid & 63, wv = tid >> 6;
  const int gt = p * 1024 + tid;
  const float* xs = pc;
  const float* ys = pc + N_PTS;
  const float* zs = pc + 2 * N_PTS;
  float x[16], y[16], z[16], md[16];
  float sx = 0.f, sy = 0.f, sz = 0.f;
#pragma unroll
  for (int j = 0; j < 16; ++j) {
    int i = gt + j * 16384;
    x[j] = xs[i]; y[j] = ys[i]; z[j] = zs[i];
    sx += x[j]; sy += y[j]; sz += z[j];
  }
#pragma unroll
  for (int m = 32; m; m >>= 1) {
    sx += __shfl_xor(sx, m); sy += __shfl_xor(sy, m); sz += __shfl_xor(sz, m);
  }
  __shared__ float rs[3][16];
  __shared__ ull wkeyL[16];
  __shared__ float bc[3];
  if (lane == 0) { rs[0][wv] = sx; rs[1][wv] = sy; rs[2][wv] = sz; }
  __syncthreads();
  if (tid == 0) {
    float ax = 0.f, ay = 0.f, az = 0.f;
    for (int w = 0; w < 16; ++w) { ax += rs[0][w]; ay += rs[1][w]; az += rs[2][w]; }
    st64(&cslots[0 + p], (ull)__float_as_uint(ax));
    st64(&cslots[16 + p], (ull)__float_as_uint(ay));
    st64(&cslots[32 + p], (ull)__float_as_uint(az));
    __hip_atomic_fetch_add(&cnts[4], 1u, __ATOMIC_RELEASE, __HIP_MEMORY_SCOPE_AGENT);
  }
  if (wv == 0) {
    while (__hip_atomic_load(&cnts[4], __ATOMIC_RELAXED, __HIP_MEMORY_SCOPE_AGENT) < 16u)
      __builtin_amdgcn_s_sleep(1);
    (void)__hip_atomic_load(&cnts[4], __ATOMIC_ACQUIRE, __HIP_MEMORY_SCOPE_AGENT);
    float f = 0.f;
    if (lane < 48) f = __uint_as_float((unsigned)ld64(&cslots[lane]));
    float s = 0.f;
    for (int q = 0; q < 16; ++q) s += __shfl(f, (lane & 48) + q);  // ascending order
    if (lane == 0)  bc[0] = s * (1.f / N_PTS);
    if (lane == 16) bc[1] = s * (1.f / N_PTS);
    if (lane == 32) bc[2] = s * (1.f / N_PTS);
  }
  __syncthreads();
  ull lkey = 0ull;
  {
    float cx = bc[0], cy = bc[1], cz = bc[2];
#pragma unroll
    for (int j = 0; j < 16; ++j) {
      float dx = x[j] - cx, dy = y[j] - cy, dz = z[j] - cz;
      float d = sqrtf(dx * dx + dy * dy + dz * dz);
      md[j] = d;
      unsigned fb = __float_as_uint(d);
      ull k = ((ull)fb << 18) | (ull)(0x3FFFFu ^ (unsigned)(gt + j * 16384));
      if (k > lkey) lkey = k;
    }
  }
  for (int sel = 0; sel < NG; ++sel) {
    const ull seq = (ull)(sel + 1);
    ull rk = lkey;
#pragma unroll
    for (int m = 32; m; m >>= 1) {
      ull o = shfl_xor_u64(rk, m);
      if (o > rk) rk = o;
    }
    if (lane == 0) wkeyL[wv] = rk;
    __syncthreads();
    if (wv == 0) {
      const int pb = (sel & 1) * 16;  // depth-2 parity line
      ull bk = (lane < 16) ? wkeyL[lane] : 0ull;
#pragma unroll
      for (int m = 8; m; m >>= 1) {
        ull o = shfl_xor_u64(bk, m);
        if (o > bk) bk = o;
      }
      if (lane == 0) st64(&kslots[pb + p], (seq << 50) | bk);  // fire-and-forget
      ull v = 0ull;
      for (;;) {  // hot-spin poll on one 128B line (no sleep quantization)
        if (lane < 16) v = ld64(&kslots[pb + lane]);
        bool ok = (lane >= 16) || ((v >> 50) == seq);
        if (__all((int)ok)) break;
      }
      ull gk = (lane < 16) ? v : 0ull;
#pragma unroll
      for (int m = 32; m; m >>= 1) {
        ull o = shfl_xor_u64(gk, m);
        if (o > gk) gk = o;
      }
      unsigned wi = 0x3FFFFu ^ (unsigned)(gk & 0x3FFFFull);
      if (lane < 3) {
        float c = pc[lane * N_PTS + wi];  // clean L2-resident fetch
        bc[lane] = c;
        if (p == 0) sampled_out[sel * 3 + lane] = c;
      }
    }
    __syncthreads();
    {  // fused md-update + next-step candidate
      float wx = bc[0], wy = bc[1], wz = bc[2];
      ull nk = 0ull;
#pragma unroll
      for (int j = 0; j < 16; ++j) {
        float dx = x[j] - wx, dy = y[j] - wy, dz = z[j] - wz;
        float d = sqrtf(dx * dx + dy * dy + dz * dz);
        float m = (sel == 0) ? d : fminf(md[j], d);
        md[j] = m;
        unsigned fb = __float_as_uint(m);
        ull k = ((ull)fb << 18) | (ull)(0x3FFFFu ^ (unsigned)(gt + j * 16384));
        if (k > nk) nk = k;
      }
      lkey = nk;
    }
  }
}

// ---------------- KNN: vectorized 2-scan radix select, p2 inline -------------
__device__ __forceinline__ void select_bucket(const unsigned* hist, int nbins,
                                              unsigned krem, unsigned* sres, int lane) {
  const int per = nbins >> 6;
  unsigned local = 0;
  for (int j = 0; j < per; ++j) local += hist[lane * per + j];
  unsigned inc = local;
  for (int off = 1; off < 64; off <<= 1) {
    unsigned v = __shfl_up(inc, off);
    if (lane >= off) inc += v;
  }
  unsigned exc = inc - local;
  if (exc < krem && krem <= inc) {
    unsigned c = exc;
    for (int j = 0; j < per; ++j) {
      unsigned h = hist[lane * per + j];
      if (c + h >= krem) { sres[0] = (unsigned)(lane * per + j); sres[1] = c; break; }
      c += h;
    }
  }
}

__global__ void __launch_bounds__(1024) knn_kernel(const float* __restrict__ pc,
    const float* __restrict__ sampled, int* __restrict__ knn) {
  const int g = blockIdx.x;
  const int tid = threadIdx.x;
  const int lane = tid & 63;
  __shared__ unsigned hist[2048];
  __shared__ unsigned candk[8192];
  __shared__ unsigned candi[8192];
  __shared__ unsigned sres[2];
  __shared__ unsigned scnt[4];
  const f32x4* xs4 = (const f32x4*)pc;
  const f32x4* ys4 = (const f32x4*)(pc + N_PTS);
  const f32x4* zs4 = (const f32x4*)(pc + 2 * N_PTS);
  const float sx = sampled[g * 3 + 0], sy = sampled[g * 3 + 1], sz = sampled[g * 3 + 2];
  const float s2 = __fadd_rn(__fadd_rn(__fmul_rn(sx, sx), __fmul_rn(sy, sy)),
                             __fmul_rn(sz, sz));
  for (int i = tid; i < 2048; i += 1024) hist[i] = 0u;
  if (tid == 0) { scnt[0] = 0u; scnt[1] = 0u; scnt[2] = 0u; scnt[3] = 0u; }
  __syncthreads();
  for (int it = 0; it < 64; ++it) {
    int i4 = it * 1024 + tid;
    f32x4 xv = xs4[i4], yv = ys4[i4], zv = zs4[i4];
#pragma unroll
    for (int u = 0; u < 4; ++u) {
      float pp = __fadd_rn(__fadd_rn(__fmul_rn(xv[u], xv[u]), __fmul_rn(yv[u], yv[u])),
                           __fmul_rn(zv[u], zv[u]));
      unsigned k = knn_key(xv[u], yv[u], zv[u], pp, sx, sy, sz, s2);
      atomicAdd(&hist[k >> 21], 1u);
    }
  }
  __syncthreads();
  if (tid < 64) select_bucket(hist, 2048, GS, sres, lane);
  __syncthreads();
  const unsigned b0 = sres[0];
  unsigned krem = GS - sres[1];
  __syncthreads();
  for (int it = 0; it < 64; ++it) {
    int i4 = it * 1024 + tid;
    f32x4 xv = xs4[i4], yv = ys4[i4], zv = zs4[i4];
#pragma unroll
    for (int u = 0; u < 4; ++u) {
      float pp = __fadd_rn(__fadd_rn(__fmul_rn(xv[u], xv[u]), __fmul_rn(yv[u], yv[u])),
                           __fmul_rn(zv[u], zv[u]));
      unsigned k = knn_key(xv[u], yv[u], zv[u], pp, sx, sy, sz, s2);
      unsigned b = k >> 21;
      if (b < b0) {
        unsigned pos = atomicAdd(&scnt[0], 1u);
        knn[g * GS + pos] = i4 * 4 + u;
      } else if (b == b0) {
        unsigned e = atomicAdd(&scnt[1], 1u);
        if (e < 8192u) { candk[e] = k; candi[e] = i4 * 4 + u; }
      }
    }
  }
  __syncthreads();
  const int m = (int)min(scnt[1], 8192u);
  const int base1 = (int)scnt[0];
  for (int i = tid; i < 2048; i += 1024) hist[i] = 0u;
  __syncthreads();
  for (int j = tid; j < m; j += 1024) atomicAdd(&hist[(candk[j] >> 10) & 2047u], 1u);
  __syncthreads();
  if (tid < 64) select_bucket(hist, 2048, krem, sres, lane);
  __syncthreads();
  const unsigned b2 = sres[0];
  krem -= sres[1];
  __syncthreads();
  if (tid < 1024) hist[tid] = 0u;
  __syncthreads();
  for (int j = tid; j < m; j += 1024)
    if (((candk[j] >> 10) & 2047u) == b2) atomicAdd(&hist[candk[j] & 1023u], 1u);
  __syncthreads();
  if (tid < 64) select_bucket(hist, 1024, krem, sres, lane);
  __syncthreads();
  const unsigned b3 = sres[0];
  krem -= sres[1];
  const unsigned T = (b0 << 21) | (b2 << 10) | b3;
  __syncthreads();
  for (int j = tid; j < m; j += 1024) {
    unsigned k = candk[j];
    if (k < T) {
      unsigned pos = atomicAdd(&scnt[2], 1u);
      knn[g * GS + base1 + (int)pos] = candi[j];
    } else if (k == T) {
      unsigned e = atomicAdd(&scnt[3], 1u);
      if (e < 2048u) hist[e] = candi[j];
    }
  }
  __syncthreads();
  if (tid < 64) {
    const int tc = (int)min(scnt[3], 2048u);
    const int base2 = base1 + (int)scnt[2];
    for (int j = 0; j < (int)krem; ++j) {
      int best = 0x7FFFFFFF;
      for (int q = lane; q < tc; q += 64) best = min(best, (int)hist[q]);
      for (int mm = 32; mm; mm >>= 1) best = min(best, __shfl_xor(best, mm));
      for (int q = lane; q < tc; q += 64)
        if ((int)hist[q] == best) hist[q] = 0x7FFFFFFFu;
      if (lane == 0) knn[g * GS + base2 + j] = best;
    }
  }
}

// ---------------- fused MLP (3->64->128->1024) + max-pool, bf16 MFMA ---------
__global__ void __launch_bounds__(256, 2) mlp_kernel(const float* __restrict__ pc,
    const int* __restrict__ knn, const float* __restrict__ w1,
    const unsigned short* __restrict__ w2t, const unsigned short* __restrict__ w3t,
    unsigned* __restrict__ gout) {
  const int blk = blockIdx.x, g = blk >> 2, split = blk & 3;
  const int tid = threadIdx.x, lane = tid & 63, wv = tid >> 6;
  __shared__ unsigned gmax[1024];
  __shared__ __align__(16) short h1[128 * 72];
  __shared__ __align__(16) short h2[128 * 136];
  __shared__ float cxs[128], cys[128], czs[128];
  for (int i = tid; i < 1024; i += 256) gmax[i] = 0u;
  const float* xs = pc;
  const float* ys = pc + N_PTS;
  const float* zs = pc + 2 * N_PTS;
  const int ch = tid & 63;
  const int pgrp = tid >> 6;
  const float w10 = w1[ch], w11 = w1[64 + ch], w12 = w1[128 + ch];
  const int r0 = (lane >> 4) * 4;
  const int cB = lane & 15;
  const int kB = (lane >> 4) * 8;
  for (int tile = 0; tile < 2; ++tile) {
    __syncthreads();
    if (tid < 128) {
      int i = knn[g * 1024 + split * 256 + tile * 128 + tid];
      cxs[tid] = xs[i]; cys[tid] = ys[i]; czs[tid] = zs[i];
    }
    __syncthreads();
    for (int q = 0; q < 32; ++q) {
      int p = pgrp * 32 + q;
      float v = fmaxf(__fmaf_rn(cxs[p], w10, __fmaf_rn(cys[p], w11, czs[p] * w12)), 0.f);
      h1[p * 72 + ch] = (short)f2bf(v);
    }
    __syncthreads();
    {
      short8 a[2][2];
#pragma unroll
      for (int mt = 0; mt < 2; ++mt)
#pragma unroll
        for (int ks = 0; ks < 2; ++ks)
          a[mt][ks] = *(const short8*)&h1[((2 * wv + mt) * 16 + cB) * 72 + kB + ks * 32];
#pragma unroll
      for (int n0 = 0; n0 < 8; ++n0) {
        short8 bb[2];
#pragma unroll
        for (int ks = 0; ks < 2; ++ks)
          bb[ks] = *(const short8*)&w2t[(n0 * 16 + cB) * 64 + kB + ks * 32];
#pragma unroll
        for (int mt = 0; mt < 2; ++mt) {
          f32x4 acc = {0.f, 0.f, 0.f, 0.f};
          acc = mfma16(a[mt][0], bb[0], acc);
          acc = mfma16(a[mt][1], bb[1], acc);
          int rr = (2 * wv + mt) * 16 + r0;
#pragma unroll
          for (int r = 0; r < 4; ++r)
            h2[(rr + r) * 136 + n0 * 16 + cB] = (short)f2bf(fmaxf(acc[r], 0.f));
        }
      }
    }
    __syncthreads();
    {
      short8 a2[2][4];
#pragma unroll
      for (int mt = 0; mt < 2; ++mt)
#pragma unroll
        for (int ks = 0; ks < 4; ++ks)
          a2[mt][ks] = *(const short8*)&h2[((2 * wv + mt) * 16 + cB) * 136 + kB + ks * 32];
      for (int n0 = 0; n0 < 64; ++n0) {
        short8 b3[4];
#pragma unroll
        for (int ks = 0; ks < 4; ++ks)
          b3[ks] = *(const short8*)&w3t[(n0 * 16 + cB) * 128 + kB + ks * 32];
        f32x4 acc0 = {0.f, 0.f, 0.f, 0.f}, acc1 = {0.f, 0.f, 0.f, 0.f};
#pragma unroll
        for (int ks = 0; ks < 4; ++ks) acc0 = mfma16(a2[0][ks], b3[ks], acc0);
#pragma unroll
        for (int ks = 0; ks < 4; ++ks) acc1 = mfma16(a2[1][ks], b3[ks], acc1);
        float mv = fmaxf(fmaxf(fmaxf(acc0[0], acc0[1]), fmaxf(acc0[2], acc0[3])),
                         fmaxf(fmaxf(acc1[0], acc1[1]), fmaxf(acc1[2], acc1[3])));
        mv = fmaxf(mv, __shfl_xor(mv, 16));
        mv = fmaxf(mv, __shfl_xor(mv, 32));
        if (lane < 16) atomicMax(&gmax[n0 * 16 + lane], ordenc(mv));
      }
    }
  }
  __syncthreads();
  for (int i = tid; i < 1024; i += 256)
    gout[(g * 4 + split) * 1024 + i] = gmax[i];
}

// ---------------- combine split partials -> d_out ----------------------------
__global__ void __launch_bounds__(256) combine_kernel(const unsigned* __restrict__ gm,
                                                      float* __restrict__ out) {
  int c = blockIdx.x * 256 + threadIdx.x;
  int g = c >> 10, chn = c & 1023;
  unsigned m = 0u;
#pragma unroll
  for (int s = 0; s < 4; ++s) {
    unsigned v = gm[(g * 4 + s) * 1024 + chn];
    if (v > m) m = v;
  }
  out[c] = (m >> 31) ? __uint_as_float(m ^ 0x80000000u) : __uint_as_float(~m);
}

extern "C" void kernel_launch(void* const* d_in, const int* in_sizes, int n_in,
                              void* d_out, int out_size, void* d_ws, size_t ws_size,
                              hipStream_t stream) {
  (void)in_sizes; (void)n_in; (void)out_size; (void)ws_size;
  const float* pc = (const float*)d_in[0];
  const float* w1 = (const float*)d_in[1];
  const float* w2 = (const float*)d_in[2];
  const float* w3 = (const float*)d_in[3];
  float* out = (float*)d_out;
  char* ws = (char*)d_ws;

  unsigned* cnts = (unsigned*)(ws + 0);        // centroid counter at [4]
  ull* kslots = (ull*)(ws + 128);              // 32 ull = two 128B parity lines
  ull* cslots = (ull*)(ws + 1024);             // 48 ull centroid partials
  unsigned short* w2t = (unsigned short*)(ws + 4096);            // 16 KiB
  unsigned short* w3t = (unsigned short*)(ws + 4096 + 16384);    // 256 KiB
  int* knn = (int*)(ws + 4096 + 16384 + 262144);                 // 512 KiB
  unsigned* gout = (unsigned*)(ws + 4096 + 16384 + 262144 + 524288); // 2 MiB
  float* sampled = out + 131072;

  hipMemsetAsync(ws, 0, 4096, stream);
  fps_kernel<<<FPS_B + 128, 1024, 0, stream>>>(pc, w2, w3, w2t, w3t, sampled,
                                               cnts, kslots, cslots);
  knn_kernel<<<NG, 1024, 0, stream>>>(pc, sampled, knn);
  mlp_kernel<<<NG * 4, 256, 0, stream>>>(pc, knn, w1, w2t, w3t, gout);
  combine_kernel<<<512, 256, 0, stream>>>(gout, out);
}

// Round 13
// 801.157 us; speedup vs baseline: 1.7938x; 1.0604x over previous
//
#include <hip/hip_runtime.h>

#define N_PTS 262144
#define NG 128
#define GS 1024
#define FPS_B 16

typedef __attribute__((ext_vector_type(8))) short short8;
typedef __attribute__((ext_vector_type(8))) __bf16 bf16x8;
typedef __attribute__((ext_vector_type(4))) float f32x4;
typedef unsigned long long ull;

__device__ __forceinline__ unsigned short f2bf(float f) {
  unsigned u = __float_as_uint(f);
  unsigned r = u + 0x7FFFu + ((u >> 16) & 1u);
  return (unsigned short)(r >> 16);
}

__device__ __forceinline__ f32x4 mfma16(short8 a, short8 b, f32x4 c) {
  return __builtin_amdgcn_mfma_f32_16x16x32_bf16(
      __builtin_bit_cast(bf16x8, a), __builtin_bit_cast(bf16x8, b), c, 0, 0, 0);
}

__device__ __forceinline__ ull shfl_xor_u64(ull v, int m) {
  unsigned lo = __shfl_xor((unsigned)v, m);
  unsigned hi = __shfl_xor((unsigned)(v >> 32), m);
  return ((ull)hi << 32) | lo;
}

__device__ __forceinline__ void st64(ull* p, ull v) {
  __hip_atomic_store(p, v, __ATOMIC_RELAXED, __HIP_MEMORY_SCOPE_AGENT);
}
__device__ __forceinline__ ull ld64(const ull* p) {
  return __hip_atomic_load(p, __ATOMIC_RELAXED, __HIP_MEMORY_SCOPE_AGENT);
}

// ordered-uint encode for float (monotone for all finite floats)
__device__ __forceinline__ unsigned ordenc(float f) {
  unsigned u = __float_as_uint(f);
  return (u >> 31) ? ~u : (u | 0x80000000u);
}

__device__ __forceinline__ unsigned knn_key(float x, float y, float z, float pp,
                                            float sx, float sy, float sz, float s2) {
  float dot = __fmaf_rn(sx, x, __fmaf_rn(sy, y, __fmul_rn(sz, z)));
  float d2 = __fadd_rn(__fsub_rn(s2, __fadd_rn(dot, dot)), pp);
  return ordenc(d2);
}

// ---------------- FPS (blocks 0..15) + weight-prep (blocks 16..143) ----------
// kslots[2][16]: {seq:14|dist:32|~idx:18} per parity line, relaxed stores.
__global__ void __launch_bounds__(1024) fps_kernel(const float* __restrict__ pc,
    const float* __restrict__ w2, const float* __restrict__ w3,
    unsigned short* __restrict__ w2t, unsigned short* __restrict__ w3t,
    float* __restrict__ sampled_out, unsigned* __restrict__ cnts,
    ull* __restrict__ kslots, ull* __restrict__ cslots) {
  const int tid = threadIdx.x;
  if (blockIdx.x >= FPS_B) {
    // prep role: transpose weights to bf16, then exit (no exchange participation)
    const int pb = blockIdx.x - FPS_B;
    int i3 = pb * 1024 + tid;  // 128 blocks cover 131072
    { int n = i3 >> 7, k = i3 & 127; w3t[i3] = f2bf(w3[k * 1024 + n]); }
    if (pb < 8) { int i2 = pb * 1024 + tid; int n = i2 >> 6, k = i2 & 63; w2t[i2] = f2bf(w2[k * 128 + n]); }
    return;
  }
  const int p = blockIdx.x;
  const int lane = tid & 63, wv = tid >> 6;
  const int gt = p * 1024 + tid;
  const float* xs = pc;
  const float* ys = pc + N_PTS;
  const float* zs = pc + 2 * N_PTS;
  float x[16], y[16], z[16], md[16];
  float sx = 0.f, sy = 0.f, sz = 0.f;
#pragma unroll
  for (int j = 0; j < 16; ++j) {
    int i = gt + j * 16384;
    x[j] = xs[i]; y[j] = ys[i]; z[j] = zs[i];
    sx += x[j]; sy += y[j]; sz += z[j];
  }
#pragma unroll
  for (int m = 32; m; m >>= 1) {
    sx += __shfl_xor(sx, m); sy += __shfl_xor(sy, m); sz += __shfl_xor(sz, m);
  }
  __shared__ float rs[3][16];
  __shared__ ull wkeyL[16];
  __shared__ float bc[3];
  if (lane == 0) { rs[0][wv] = sx; rs[1][wv] = sy; rs[2][wv] = sz; }
  __syncthreads();
  if (tid == 0) {
    float ax = 0.f, ay = 0.f, az = 0.f;
    for (int w = 0; w < 16; ++w) { ax += rs[0][w]; ay += rs[1][w]; az += rs[2][w]; }
    st64(&cslots[0 + p], (ull)__float_as_uint(ax));
    st64(&cslots[16 + p], (ull)__float_as_uint(ay));
    st64(&cslots[32 + p], (ull)__float_as_uint(az));
    __hip_atomic_fetch_add(&cnts[4], 1u, __ATOMIC_RELEASE, __HIP_MEMORY_SCOPE_AGENT);
  }
  if (wv == 0) {
    while (__hip_atomic_load(&cnts[4], __ATOMIC_RELAXED, __HIP_MEMORY_SCOPE_AGENT) < 16u)
      __builtin_amdgcn_s_sleep(1);
    (void)__hip_atomic_load(&cnts[4], __ATOMIC_ACQUIRE, __HIP_MEMORY_SCOPE_AGENT);
    float f = 0.f;
    if (lane < 48) f = __uint_as_float((unsigned)ld64(&cslots[lane]));
    float s = 0.f;
    for (int q = 0; q < 16; ++q) s += __shfl(f, (lane & 48) + q);  // ascending order
    if (lane == 0)  bc[0] = s * (1.f / N_PTS);
    if (lane == 16) bc[1] = s * (1.f / N_PTS);
    if (lane == 32) bc[2] = s * (1.f / N_PTS);
  }
  __syncthreads();
  ull lkey = 0ull;
  {
    float cx = bc[0], cy = bc[1], cz = bc[2];
#pragma unroll
    for (int j = 0; j < 16; ++j) {
      float dx = x[j] - cx, dy = y[j] - cy, dz = z[j] - cz;
      float d = sqrtf(dx * dx + dy * dy + dz * dz);
      md[j] = d;
      unsigned fb = __float_as_uint(d);
      ull k = ((ull)fb << 18) | (ull)(0x3FFFFu ^ (unsigned)(gt + j * 16384));
      if (k > lkey) lkey = k;
    }
  }
  for (int sel = 0; sel < NG; ++sel) {
    const ull seq = (ull)(sel + 1);
    ull rk = lkey;
#pragma unroll
    for (int m = 32; m; m >>= 1) {
      ull o = shfl_xor_u64(rk, m);
      if (o > rk) rk = o;
    }
    if (lane == 0) wkeyL[wv] = rk;
    __syncthreads();
    if (wv == 0) {
      const int pb = (sel & 1) * 16;  // depth-2 parity line
      ull bk = (lane < 16) ? wkeyL[lane] : 0ull;
#pragma unroll
      for (int m = 8; m; m >>= 1) {
        ull o = shfl_xor_u64(bk, m);
        if (o > bk) bk = o;
      }
      if (lane == 0) st64(&kslots[pb + p], (seq << 50) | bk);  // fire-and-forget
      ull v = 0ull;
      for (;;) {  // hot-spin poll on one 128B line
        if (lane < 16) v = ld64(&kslots[pb + lane]);
        bool ok = (lane >= 16) || ((v >> 50) == seq);
        if (__all((int)ok)) break;
      }
      ull gk = (lane < 16) ? v : 0ull;
#pragma unroll
      for (int m = 32; m; m >>= 1) {
        ull o = shfl_xor_u64(gk, m);
        if (o > gk) gk = o;
      }
      unsigned wi = 0x3FFFFu ^ (unsigned)(gk & 0x3FFFFull);
      if (lane < 3) {
        float c = pc[lane * N_PTS + wi];  // clean L2-resident fetch
        bc[lane] = c;
        if (p == 0) sampled_out[sel * 3 + lane] = c;
      }
    }
    __syncthreads();
    {  // fused md-update + next-step candidate
      float wx = bc[0], wy = bc[1], wz = bc[2];
      ull nk = 0ull;
#pragma unroll
      for (int j = 0; j < 16; ++j) {
        float dx = x[j] - wx, dy = y[j] - wy, dz = z[j] - wz;
        float d = sqrtf(dx * dx + dy * dy + dz * dz);
        float m = (sel == 0) ? d : fminf(md[j], d);
        md[j] = m;
        unsigned fb = __float_as_uint(m);
        ull k = ((ull)fb << 18) | (ull)(0x3FFFFu ^ (unsigned)(gt + j * 16384));
        if (k > nk) nk = k;
      }
      lkey = nk;
    }
  }
}

// ---------------- KNN v2: subsample threshold + 1-pass candidates ------------
__device__ __forceinline__ void select_bucket(const unsigned* hist, int nbins,
                                              unsigned krem, unsigned* sres, int lane) {
  const int per = nbins >> 6;
  unsigned local = 0;
  for (int j = 0; j < per; ++j) local += hist[lane * per + j];
  unsigned inc = local;
  for (int off = 1; off < 64; off <<= 1) {
    unsigned v = __shfl_up(inc, off);
    if (lane >= off) inc += v;
  }
  unsigned exc = inc - local;
  if (exc < krem && krem <= inc) {
    unsigned c = exc;
    for (int j = 0; j < per; ++j) {
      unsigned h = hist[lane * per + j];
      if (c + h >= krem) { sres[0] = (unsigned)(lane * per + j); sres[1] = c; break; }
      c += h;
    }
  }
}

__global__ void __launch_bounds__(1024) knn_kernel(const float* __restrict__ pc,
    const float* __restrict__ sampled, int* __restrict__ knn) {
  const int g = blockIdx.x;
  const int tid = threadIdx.x;
  const int lane = tid & 63;
  __shared__ unsigned hist[2048];
  __shared__ unsigned candk[8192];
  __shared__ unsigned candi[8192];
  __shared__ unsigned candk2[2048];
  __shared__ unsigned candi2[2048];
  __shared__ unsigned sres[2];
  __shared__ unsigned scnt[6];
  const f32x4* xs4 = (const f32x4*)pc;
  const f32x4* ys4 = (const f32x4*)(pc + N_PTS);
  const f32x4* zs4 = (const f32x4*)(pc + 2 * N_PTS);
  const float sx = sampled[g * 3 + 0], sy = sampled[g * 3 + 1], sz = sampled[g * 3 + 2];
  const float s2 = __fadd_rn(__fadd_rn(__fmul_rn(sx, sx), __fmul_rn(sy, sy)),
                             __fmul_rn(sz, sz));
  for (int i = tid; i < 2048; i += 1024) hist[i] = 0u;
  if (tid < 6) scnt[tid] = 0u;
  __syncthreads();
  // subsample scan: first 16384 points -> rank-160 bucket => threshold T'
  for (int it = 0; it < 4; ++it) {
    int i4 = it * 1024 + tid;
    f32x4 xv = xs4[i4], yv = ys4[i4], zv = zs4[i4];
#pragma unroll
    for (int u = 0; u < 4; ++u) {
      float pp = __fadd_rn(__fadd_rn(__fmul_rn(xv[u], xv[u]), __fmul_rn(yv[u], yv[u])),
                           __fmul_rn(zv[u], zv[u]));
      unsigned k = knn_key(xv[u], yv[u], zv[u], pp, sx, sy, sz, s2);
      atomicAdd(&hist[k >> 21], 1u);
    }
  }
  __syncthreads();
  if (tid < 64) select_bucket(hist, 2048, 160u, sres, lane);
  __syncthreads();
  const unsigned Tp = (sres[0] >= 2047u) ? 0xFFFFFFFFu : ((sres[0] + 1u) << 21);
  __syncthreads();
  // full scan: collect candidates with key < T' (exact superset of top-1024 w.h.p.)
  for (int it = 0; it < 64; ++it) {
    int i4 = it * 1024 + tid;
    f32x4 xv = xs4[i4], yv = ys4[i4], zv = zs4[i4];
#pragma unroll
    for (int u = 0; u < 4; ++u) {
      float pp = __fadd_rn(__fadd_rn(__fmul_rn(xv[u], xv[u]), __fmul_rn(yv[u], yv[u])),
                           __fmul_rn(zv[u], zv[u]));
      unsigned k = knn_key(xv[u], yv[u], zv[u], pp, sx, sy, sz, s2);
      if (k < Tp) {
        unsigned e = atomicAdd(&scnt[0], 1u);
        if (e < 8192u) { candk[e] = k; candi[e] = (unsigned)(i4 * 4 + u); }
      }
    }
  }
  __syncthreads();
  const int m = (int)min(scnt[0], 8192u);
  // level A: bits 31..21 over candidates
  for (int i = tid; i < 2048; i += 1024) hist[i] = 0u;
  __syncthreads();
  for (int j = tid; j < m; j += 1024) atomicAdd(&hist[candk[j] >> 21], 1u);
  __syncthreads();
  if (tid < 64) select_bucket(hist, 2048, GS, sres, lane);
  __syncthreads();
  const unsigned bA = sres[0];
  unsigned krem = GS - sres[1];
  __syncthreads();
  // emit bucket < bA ; compact bucket == bA
  for (int j = tid; j < m; j += 1024) {
    unsigned k = candk[j], b = k >> 21;
    if (b < bA) {
      unsigned pos = atomicAdd(&scnt[1], 1u);
      knn[g * GS + (int)pos] = (int)candi[j];
    } else if (b == bA) {
      unsigned e = atomicAdd(&scnt[2], 1u);
      if (e < 2048u) { candk2[e] = k; candi2[e] = candi[j]; }
    }
  }
  __syncthreads();
  const int m2 = (int)min(scnt[2], 2048u);
  const int base1 = (int)scnt[1];
  // level B: bits 20..10
  for (int i = tid; i < 2048; i += 1024) hist[i] = 0u;
  __syncthreads();
  for (int j = tid; j < m2; j += 1024) atomicAdd(&hist[(candk2[j] >> 10) & 2047u], 1u);
  __syncthreads();
  if (tid < 64) select_bucket(hist, 2048, krem, sres, lane);
  __syncthreads();
  const unsigned bB = sres[0];
  krem -= sres[1];
  __syncthreads();
  // level C: bits 9..0 among == bB
  if (tid < 1024) hist[tid] = 0u;
  __syncthreads();
  for (int j = tid; j < m2; j += 1024)
    if (((candk2[j] >> 10) & 2047u) == bB) atomicAdd(&hist[candk2[j] & 1023u], 1u);
  __syncthreads();
  if (tid < 64) select_bucket(hist, 1024, krem, sres, lane);
  __syncthreads();
  const unsigned bC = sres[0];
  krem -= sres[1];
  const unsigned T = (bA << 21) | (bB << 10) | bC;
  __syncthreads();
  // emit < T from == bA set; collect == T ties
  for (int j = tid; j < m2; j += 1024) {
    unsigned k = candk2[j];
    if (k < T) {
      unsigned pos = atomicAdd(&scnt[3], 1u);
      knn[g * GS + base1 + (int)pos] = (int)candi2[j];
    } else if (k == T) {
      unsigned e = atomicAdd(&scnt[4], 1u);
      if (e < 2048u) hist[e] = candi2[j];
    }
  }
  __syncthreads();
  if (tid < 64) {
    const int tc = (int)min(scnt[4], 2048u);
    const int base2 = base1 + (int)scnt[3];
    for (int j = 0; j < (int)krem; ++j) {
      int best = 0x7FFFFFFF;
      for (int q = lane; q < tc; q += 64) best = min(best, (int)hist[q]);
      for (int mm = 32; mm; mm >>= 1) best = min(best, __shfl_xor(best, mm));
      for (int q = lane; q < tc; q += 64)
        if ((int)hist[q] == best) hist[q] = 0x7FFFFFFFu;
      if (lane == 0) knn[g * GS + base2 + j] = best;
    }
  }
}

// ---------------- fused MLP (3->64->128->1024) + max-pool, bf16 MFMA ---------
__global__ void __launch_bounds__(256, 2) mlp_kernel(const float* __restrict__ pc,
    const int* __restrict__ knn, const float* __restrict__ w1,
    const unsigned short* __restrict__ w2t, const unsigned short* __restrict__ w3t,
    unsigned* __restrict__ gout) {
  const int blk = blockIdx.x, g = blk >> 2, split = blk & 3;
  const int tid = threadIdx.x, lane = tid & 63, wv = tid >> 6;
  __shared__ unsigned gmax[1024];
  __shared__ __align__(16) short h1[128 * 72];
  __shared__ __align__(16) short h2[128 * 136];
  __shared__ float cxs[128], cys[128], czs[128];
  for (int i = tid; i < 1024; i += 256) gmax[i] = 0u;
  const float* xs = pc;
  const float* ys = pc + N_PTS;
  const float* zs = pc + 2 * N_PTS;
  const int ch = tid & 63;
  const int pgrp = tid >> 6;
  const float w10 = w1[ch], w11 = w1[64 + ch], w12 = w1[128 + ch];
  const int r0 = (lane >> 4) * 4;
  const int cB = lane & 15;
  const int kB = (lane >> 4) * 8;
  for (int tile = 0; tile < 2; ++tile) {
    __syncthreads();
    if (tid < 128) {
      int i = knn[g * 1024 + split * 256 + tile * 128 + tid];
      cxs[tid] = xs[i]; cys[tid] = ys[i]; czs[tid] = zs[i];
    }
    __syncthreads();
    for (int q = 0; q < 32; ++q) {
      int p = pgrp * 32 + q;
      float v = fmaxf(__fmaf_rn(cxs[p], w10, __fmaf_rn(cys[p], w11, czs[p] * w12)), 0.f);
      h1[p * 72 + ch] = (short)f2bf(v);
    }
    __syncthreads();
    {
      short8 a[2][2];
#pragma unroll
      for (int mt = 0; mt < 2; ++mt)
#pragma unroll
        for (int ks = 0; ks < 2; ++ks)
          a[mt][ks] = *(const short8*)&h1[((2 * wv + mt) * 16 + cB) * 72 + kB + ks * 32];
#pragma unroll
      for (int n0 = 0; n0 < 8; ++n0) {
        short8 bb[2];
#pragma unroll
        for (int ks = 0; ks < 2; ++ks)
          bb[ks] = *(const short8*)&w2t[(n0 * 16 + cB) * 64 + kB + ks * 32];
#pragma unroll
        for (int mt = 0; mt < 2; ++mt) {
          f32x4 acc = {0.f, 0.f, 0.f, 0.f};
          acc = mfma16(a[mt][0], bb[0], acc);
          acc = mfma16(a[mt][1], bb[1], acc);
          int rr = (2 * wv + mt) * 16 + r0;
#pragma unroll
          for (int r = 0; r < 4; ++r)
            h2[(rr + r) * 136 + n0 * 16 + cB] = (short)f2bf(fmaxf(acc[r], 0.f));
        }
      }
    }
    __syncthreads();
    {
      short8 a2[2][4];
#pragma unroll
      for (int mt = 0; mt < 2; ++mt)
#pragma unroll
        for (int ks = 0; ks < 4; ++ks)
          a2[mt][ks] = *(const short8*)&h2[((2 * wv + mt) * 16 + cB) * 136 + kB + ks * 32];
      for (int n0 = 0; n0 < 64; ++n0) {
        short8 b3[4];
#pragma unroll
        for (int ks = 0; ks < 4; ++ks)
          b3[ks] = *(const short8*)&w3t[(n0 * 16 + cB) * 128 + kB + ks * 32];
        f32x4 acc0 = {0.f, 0.f, 0.f, 0.f}, acc1 = {0.f, 0.f, 0.f, 0.f};
#pragma unroll
        for (int ks = 0; ks < 4; ++ks) acc0 = mfma16(a2[0][ks], b3[ks], acc0);
#pragma unroll
        for (int ks = 0; ks < 4; ++ks) acc1 = mfma16(a2[1][ks], b3[ks], acc1);
        float mv = fmaxf(fmaxf(fmaxf(acc0[0], acc0[1]), fmaxf(acc0[2], acc0[3])),
                         fmaxf(fmaxf(acc1[0], acc1[1]), fmaxf(acc1[2], acc1[3])));
        mv = fmaxf(mv, __shfl_xor(mv, 16));
        mv = fmaxf(mv, __shfl_xor(mv, 32));
        if (lane < 16) atomicMax(&gmax[n0 * 16 + lane], ordenc(mv));
      }
    }
  }
  __syncthreads();
  for (int i = tid; i < 1024; i += 256)
    gout[(g * 4 + split) * 1024 + i] = gmax[i];
}

// ---------------- combine split partials -> d_out ----------------------------
__global__ void __launch_bounds__(256) combine_kernel(const unsigned* __restrict__ gm,
                                                      float* __restrict__ out) {
  int c = blockIdx.x * 256 + threadIdx.x;
  int g = c >> 10, chn = c & 1023;
  unsigned m = 0u;
#pragma unroll
  for (int s = 0; s < 4; ++s) {
    unsigned v = gm[(g * 4 + s) * 1024 + chn];
    if (v > m) m = v;
  }
  out[c] = (m >> 31) ? __uint_as_float(m ^ 0x80000000u) : __uint_as_float(~m);
}

extern "C" void kernel_launch(void* const* d_in, const int* in_sizes, int n_in,
                              void* d_out, int out_size, void* d_ws, size_t ws_size,
                              hipStream_t stream) {
  (void)in_sizes; (void)n_in; (void)out_size; (void)ws_size;
  const float* pc = (const float*)d_in[0];
  const float* w1 = (const float*)d_in[1];
  const float* w2 = (const float*)d_in[2];
  const float* w3 = (const float*)d_in[3];
  float* out = (float*)d_out;
  char* ws = (char*)d_ws;

  unsigned* cnts = (unsigned*)(ws + 0);        // centroid counter at [4]
  ull* kslots = (ull*)(ws + 128);              // 32 ull = two 128B parity lines
  ull* cslots = (ull*)(ws + 1024);             // 48 ull centroid partials
  unsigned short* w2t = (unsigned short*)(ws + 4096);            // 16 KiB
  unsigned short* w3t = (unsigned short*)(ws + 4096 + 16384);    // 256 KiB
  int* knn = (int*)(ws + 4096 + 16384 + 262144);                 // 512 KiB
  unsigned* gout = (unsigned*)(ws + 4096 + 16384 + 262144 + 524288); // 2 MiB
  float* sampled = out + 131072;

  hipMemsetAsync(ws, 0, 4096, stream);
  fps_kernel<<<FPS_B + 128, 1024, 0, stream>>>(pc, w2, w3, w2t, w3t, sampled,
                                               cnts, kslots, cslots);
  knn_kernel<<<NG, 1024, 0, stream>>>(pc, sampled, knn);
  mlp_kernel<<<NG * 4, 256, 0, stream>>>(pc, knn, w1, w2t, w3t, gout);
  combine_kernel<<<512, 256, 0, stream>>>(gout, out);
}

// Round 14
// 598.964 us; speedup vs baseline: 2.3994x; 1.3376x over previous
//
#include <hip/hip_runtime.h>

#define N_PTS 262144
#define NG 128
#define GS 1024
#define FPS_B 16

typedef __attribute__((ext_vector_type(8))) short short8;
typedef __attribute__((ext_vector_type(8))) __bf16 bf16x8;
typedef __attribute__((ext_vector_type(4))) float f32x4;
typedef unsigned long long ull;

__device__ __forceinline__ unsigned short f2bf(float f) {
  unsigned u = __float_as_uint(f);
  unsigned r = u + 0x7FFFu + ((u >> 16) & 1u);
  return (unsigned short)(r >> 16);
}

__device__ __forceinline__ f32x4 mfma16(short8 a, short8 b, f32x4 c) {
  return __builtin_amdgcn_mfma_f32_16x16x32_bf16(
      __builtin_bit_cast(bf16x8, a), __builtin_bit_cast(bf16x8, b), c, 0, 0, 0);
}

__device__ __forceinline__ ull shfl_xor_u64(ull v, int m) {
  unsigned lo = __shfl_xor((unsigned)v, m);
  unsigned hi = __shfl_xor((unsigned)(v >> 32), m);
  return ((ull)hi << 32) | lo;
}

__device__ __forceinline__ void st64(ull* p, ull v) {
  __hip_atomic_store(p, v, __ATOMIC_RELAXED, __HIP_MEMORY_SCOPE_AGENT);
}
__device__ __forceinline__ ull ld64(const ull* p) {
  return __hip_atomic_load(p, __ATOMIC_RELAXED, __HIP_MEMORY_SCOPE_AGENT);
}

// ordered-uint encode for float (monotone for all finite floats)
__device__ __forceinline__ unsigned ordenc(float f) {
  unsigned u = __float_as_uint(f);
  return (u >> 31) ? ~u : (u | 0x80000000u);
}

__device__ __forceinline__ unsigned knn_key(float x, float y, float z, float pp,
                                            float sx, float sy, float sz, float s2) {
  float dot = __fmaf_rn(sx, x, __fmaf_rn(sy, y, __fmul_rn(sz, z)));
  float d2 = __fadd_rn(__fsub_rn(s2, __fadd_rn(dot, dot)), pp);
  return ordenc(d2);
}

// ---------------- FPS (blocks 0..15, squared-distance metric) + prep ---------
// sqrt dropped: argmax/min over d^2 select the same indices (monotone map).
// kslots[2][16]: {seq:14|dist2:32|~idx:18} per parity line, relaxed stores.
__global__ void __launch_bounds__(1024) fps_kernel(const float* __restrict__ pc,
    const float* __restrict__ w2, const float* __restrict__ w3,
    unsigned short* __restrict__ w2t, unsigned short* __restrict__ w3t,
    float* __restrict__ sampled_out, unsigned* __restrict__ cnts,
    ull* __restrict__ kslots, ull* __restrict__ cslots) {
  const int tid = threadIdx.x;
  if (blockIdx.x >= FPS_B) {
    const int pb = blockIdx.x - FPS_B;
    int i3 = pb * 1024 + tid;  // 128 blocks cover 131072
    { int n = i3 >> 7, k = i3 & 127; w3t[i3] = f2bf(w3[k * 1024 + n]); }
    if (pb < 8) { int i2 = pb * 1024 + tid; int n = i2 >> 6, k = i2 & 63; w2t[i2] = f2bf(w2[k * 128 + n]); }
    return;
  }
  const int p = blockIdx.x;
  const int lane = tid & 63, wv = tid >> 6;
  const int gt = p * 1024 + tid;
  const float* xs = pc;
  const float* ys = pc + N_PTS;
  const float* zs = pc + 2 * N_PTS;
  float x[16], y[16], z[16], md[16];
  float sx = 0.f, sy = 0.f, sz = 0.f;
#pragma unroll
  for (int j = 0; j < 16; ++j) {
    int i = gt + j * 16384;
    x[j] = xs[i]; y[j] = ys[i]; z[j] = zs[i];
    sx += x[j]; sy += y[j]; sz += z[j];
  }
#pragma unroll
  for (int m = 32; m; m >>= 1) {
    sx += __shfl_xor(sx, m); sy += __shfl_xor(sy, m); sz += __shfl_xor(sz, m);
  }
  __shared__ float rs[3][16];
  __shared__ ull wkeyL[16];
  __shared__ float bc[3];
  if (lane == 0) { rs[0][wv] = sx; rs[1][wv] = sy; rs[2][wv] = sz; }
  __syncthreads();
  if (tid == 0) {
    float ax = 0.f, ay = 0.f, az = 0.f;
    for (int w = 0; w < 16; ++w) { ax += rs[0][w]; ay += rs[1][w]; az += rs[2][w]; }
    st64(&cslots[0 + p], (ull)__float_as_uint(ax));
    st64(&cslots[16 + p], (ull)__float_as_uint(ay));
    st64(&cslots[32 + p], (ull)__float_as_uint(az));
    __hip_atomic_fetch_add(&cnts[4], 1u, __ATOMIC_RELEASE, __HIP_MEMORY_SCOPE_AGENT);
  }
  if (wv == 0) {
    while (__hip_atomic_load(&cnts[4], __ATOMIC_RELAXED, __HIP_MEMORY_SCOPE_AGENT) < 16u)
      __builtin_amdgcn_s_sleep(1);
    (void)__hip_atomic_load(&cnts[4], __ATOMIC_ACQUIRE, __HIP_MEMORY_SCOPE_AGENT);
    float f = 0.f;
    if (lane < 48) f = __uint_as_float((unsigned)ld64(&cslots[lane]));
    float s = 0.f;
    for (int q = 0; q < 16; ++q) s += __shfl(f, (lane & 48) + q);  // ascending order
    if (lane == 0)  bc[0] = s * (1.f / N_PTS);
    if (lane == 16) bc[1] = s * (1.f / N_PTS);
    if (lane == 32) bc[2] = s * (1.f / N_PTS);
  }
  __syncthreads();
  ull lkey = 0ull;
  {
    float cx = bc[0], cy = bc[1], cz = bc[2];
#pragma unroll
    for (int j = 0; j < 16; ++j) {
      float dx = x[j] - cx, dy = y[j] - cy, dz = z[j] - cz;
      float d = __fmaf_rn(dx, dx, __fmaf_rn(dy, dy, dz * dz));  // squared dist
      md[j] = d;
      unsigned fb = __float_as_uint(d);
      ull k = ((ull)fb << 18) | (ull)(0x3FFFFu ^ (unsigned)(gt + j * 16384));
      if (k > lkey) lkey = k;
    }
  }
  for (int sel = 0; sel < NG; ++sel) {
    const ull seq = (ull)(sel + 1);
    ull rk = lkey;
#pragma unroll
    for (int m = 32; m; m >>= 1) {
      ull o = shfl_xor_u64(rk, m);
      if (o > rk) rk = o;
    }
    if (lane == 0) wkeyL[wv] = rk;
    __syncthreads();
    if (wv == 0) {
      const int pb = (sel & 1) * 16;  // depth-2 parity line
      ull bk = (lane < 16) ? wkeyL[lane] : 0ull;
#pragma unroll
      for (int m = 8; m; m >>= 1) {
        ull o = shfl_xor_u64(bk, m);
        if (o > bk) bk = o;
      }
      if (lane == 0) st64(&kslots[pb + p], (seq << 50) | bk);  // fire-and-forget
      ull v = 0ull;
      for (;;) {  // hot-spin poll on one 128B line
        if (lane < 16) v = ld64(&kslots[pb + lane]);
        bool ok = (lane >= 16) || ((v >> 50) == seq);
        if (__all((int)ok)) break;
      }
      ull gk = (lane < 16) ? v : 0ull;
#pragma unroll
      for (int m = 32; m; m >>= 1) {
        ull o = shfl_xor_u64(gk, m);
        if (o > gk) gk = o;
      }
      unsigned wi = 0x3FFFFu ^ (unsigned)(gk & 0x3FFFFull);
      if (lane < 3) {
        float c = pc[lane * N_PTS + wi];  // clean L2-resident fetch
        bc[lane] = c;
        if (p == 0) sampled_out[sel * 3 + lane] = c;
      }
    }
    __syncthreads();
    {  // fused md-update + next-step candidate (squared metric)
      float wx = bc[0], wy = bc[1], wz = bc[2];
      ull nk = 0ull;
#pragma unroll
      for (int j = 0; j < 16; ++j) {
        float dx = x[j] - wx, dy = y[j] - wy, dz = z[j] - wz;
        float d = __fmaf_rn(dx, dx, __fmaf_rn(dy, dy, dz * dz));
        float m = (sel == 0) ? d : fminf(md[j], d);
        md[j] = m;
        unsigned fb = __float_as_uint(m);
        ull k = ((ull)fb << 18) | (ull)(0x3FFFFu ^ (unsigned)(gt + j * 16384));
        if (k > nk) nk = k;
      }
      lkey = nk;
    }
  }
}

// ---------------- KNN v2: subsample threshold + 1-pass candidates ------------
__device__ __forceinline__ void select_bucket(const unsigned* hist, int nbins,
                                              unsigned krem, unsigned* sres, int lane) {
  const int per = nbins >> 6;
  unsigned local = 0;
  for (int j = 0; j < per; ++j) local += hist[lane * per + j];
  unsigned inc = local;
  for (int off = 1; off < 64; off <<= 1) {
    unsigned v = __shfl_up(inc, off);
    if (lane >= off) inc += v;
  }
  unsigned exc = inc - local;
  if (exc < krem && krem <= inc) {
    unsigned c = exc;
    for (int j = 0; j < per; ++j) {
      unsigned h = hist[lane * per + j];
      if (c + h >= krem) { sres[0] = (unsigned)(lane * per + j); sres[1] = c; break; }
      c += h;
    }
  }
}

__global__ void __launch_bounds__(1024) knn_kernel(const float* __restrict__ pc,
    const float* __restrict__ sampled, int* __restrict__ knn) {
  const int g = blockIdx.x;
  const int tid = threadIdx.x;
  const int lane = tid & 63;
  __shared__ unsigned hist[2048];
  __shared__ unsigned candk[8192];
  __shared__ unsigned candi[8192];
  __shared__ unsigned candk2[2048];
  __shared__ unsigned candi2[2048];
  __shared__ unsigned sres[2];
  __shared__ unsigned scnt[6];
  const f32x4* xs4 = (const f32x4*)pc;
  const f32x4* ys4 = (const f32x4*)(pc + N_PTS);
  const f32x4* zs4 = (const f32x4*)(pc + 2 * N_PTS);
  const float sx = sampled[g * 3 + 0], sy = sampled[g * 3 + 1], sz = sampled[g * 3 + 2];
  const float s2 = __fadd_rn(__fadd_rn(__fmul_rn(sx, sx), __fmul_rn(sy, sy)),
                             __fmul_rn(sz, sz));
  for (int i = tid; i < 2048; i += 1024) hist[i] = 0u;
  if (tid < 6) scnt[tid] = 0u;
  __syncthreads();
  // subsample scan: first 16384 points -> rank-160 bucket => threshold T'
  for (int it = 0; it < 4; ++it) {
    int i4 = it * 1024 + tid;
    f32x4 xv = xs4[i4], yv = ys4[i4], zv = zs4[i4];
#pragma unroll
    for (int u = 0; u < 4; ++u) {
      float pp = __fadd_rn(__fadd_rn(__fmul_rn(xv[u], xv[u]), __fmul_rn(yv[u], yv[u])),
                           __fmul_rn(zv[u], zv[u]));
      unsigned k = knn_key(xv[u], yv[u], zv[u], pp, sx, sy, sz, s2);
      atomicAdd(&hist[k >> 21], 1u);
    }
  }
  __syncthreads();
  if (tid < 64) select_bucket(hist, 2048, 160u, sres, lane);
  __syncthreads();
  const unsigned Tp = (sres[0] >= 2047u) ? 0xFFFFFFFFu : ((sres[0] + 1u) << 21);
  __syncthreads();
  // full scan: collect candidates with key < T' (exact superset of top-1024 w.h.p.)
  for (int it = 0; it < 64; ++it) {
    int i4 = it * 1024 + tid;
    f32x4 xv = xs4[i4], yv = ys4[i4], zv = zs4[i4];
#pragma unroll
    for (int u = 0; u < 4; ++u) {
      float pp = __fadd_rn(__fadd_rn(__fmul_rn(xv[u], xv[u]), __fmul_rn(yv[u], yv[u])),
                           __fmul_rn(zv[u], zv[u]));
      unsigned k = knn_key(xv[u], yv[u], zv[u], pp, sx, sy, sz, s2);
      if (k < Tp) {
        unsigned e = atomicAdd(&scnt[0], 1u);
        if (e < 8192u) { candk[e] = k; candi[e] = (unsigned)(i4 * 4 + u); }
      }
    }
  }
  __syncthreads();
  const int m = (int)min(scnt[0], 8192u);
  // level A: bits 31..21 over candidates
  for (int i = tid; i < 2048; i += 1024) hist[i] = 0u;
  __syncthreads();
  for (int j = tid; j < m; j += 1024) atomicAdd(&hist[candk[j] >> 21], 1u);
  __syncthreads();
  if (tid < 64) select_bucket(hist, 2048, GS, sres, lane);
  __syncthreads();
  const unsigned bA = sres[0];
  unsigned krem = GS - sres[1];
  __syncthreads();
  for (int j = tid; j < m; j += 1024) {
    unsigned k = candk[j], b = k >> 21;
    if (b < bA) {
      unsigned pos = atomicAdd(&scnt[1], 1u);
      knn[g * GS + (int)pos] = (int)candi[j];
    } else if (b == bA) {
      unsigned e = atomicAdd(&scnt[2], 1u);
      if (e < 2048u) { candk2[e] = k; candi2[e] = candi[j]; }
    }
  }
  __syncthreads();
  const int m2 = (int)min(scnt[2], 2048u);
  const int base1 = (int)scnt[1];
  for (int i = tid; i < 2048; i += 1024) hist[i] = 0u;
  __syncthreads();
  for (int j = tid; j < m2; j += 1024) atomicAdd(&hist[(candk2[j] >> 10) & 2047u], 1u);
  __syncthreads();
  if (tid < 64) select_bucket(hist, 2048, krem, sres, lane);
  __syncthreads();
  const unsigned bB = sres[0];
  krem -= sres[1];
  __syncthreads();
  if (tid < 1024) hist[tid] = 0u;
  __syncthreads();
  for (int j = tid; j < m2; j += 1024)
    if (((candk2[j] >> 10) & 2047u) == bB) atomicAdd(&hist[candk2[j] & 1023u], 1u);
  __syncthreads();
  if (tid < 64) select_bucket(hist, 1024, krem, sres, lane);
  __syncthreads();
  const unsigned bC = sres[0];
  krem -= sres[1];
  const unsigned T = (bA << 21) | (bB << 10) | bC;
  __syncthreads();
  for (int j = tid; j < m2; j += 1024) {
    unsigned k = candk2[j];
    if (k < T) {
      unsigned pos = atomicAdd(&scnt[3], 1u);
      knn[g * GS + base1 + (int)pos] = (int)candi2[j];
    } else if (k == T) {
      unsigned e = atomicAdd(&scnt[4], 1u);
      if (e < 2048u) hist[e] = candi2[j];
    }
  }
  __syncthreads();
  if (tid < 64) {
    const int tc = (int)min(scnt[4], 2048u);
    const int base2 = base1 + (int)scnt[3];
    for (int j = 0; j < (int)krem; ++j) {
      int best = 0x7FFFFFFF;
      for (int q = lane; q < tc; q += 64) best = min(best, (int)hist[q]);
      for (int mm = 32; mm; mm >>= 1) best = min(best, __shfl_xor(best, mm));
      for (int q = lane; q < tc; q += 64)
        if ((int)hist[q] == best) hist[q] = 0x7FFFFFFFu;
      if (lane == 0) knn[g * GS + base2 + j] = best;
    }
  }
}

// ---------------- fused MLP + max-pool, bf16 MFMA, b3 prefetch pipeline ------
__global__ void __launch_bounds__(256, 2) mlp_kernel(const float* __restrict__ pc,
    const int* __restrict__ knn, const float* __restrict__ w1,
    const unsigned short* __restrict__ w2t, const unsigned short* __restrict__ w3t,
    unsigned* __restrict__ gout) {
  const int blk = blockIdx.x, g = blk >> 2, split = blk & 3;
  const int tid = threadIdx.x, lane = tid & 63, wv = tid >> 6;
  __shared__ unsigned gmax[1024];
  __shared__ __align__(16) short h1[128 * 72];
  __shared__ __align__(16) short h2[128 * 136];
  __shared__ float cxs[128], cys[128], czs[128];
  for (int i = tid; i < 1024; i += 256) gmax[i] = 0u;
  const float* xs = pc;
  const float* ys = pc + N_PTS;
  const float* zs = pc + 2 * N_PTS;
  const int ch = tid & 63;
  const int pgrp = tid >> 6;
  const float w10 = w1[ch], w11 = w1[64 + ch], w12 = w1[128 + ch];
  const int r0 = (lane >> 4) * 4;
  const int cB = lane & 15;
  const int kB = (lane >> 4) * 8;
  for (int tile = 0; tile < 2; ++tile) {
    __syncthreads();
    if (tid < 128) {
      int i = knn[g * 1024 + split * 256 + tile * 128 + tid];
      cxs[tid] = xs[i]; cys[tid] = ys[i]; czs[tid] = zs[i];
    }
    __syncthreads();
    for (int q = 0; q < 32; ++q) {
      int p = pgrp * 32 + q;
      float v = fmaxf(__fmaf_rn(cxs[p], w10, __fmaf_rn(cys[p], w11, czs[p] * w12)), 0.f);
      h1[p * 72 + ch] = (short)f2bf(v);
    }
    __syncthreads();
    {
      short8 a[2][2];
#pragma unroll
      for (int mt = 0; mt < 2; ++mt)
#pragma unroll
        for (int ks = 0; ks < 2; ++ks)
          a[mt][ks] = *(const short8*)&h1[((2 * wv + mt) * 16 + cB) * 72 + kB + ks * 32];
      short8 bbn[2];
#pragma unroll
      for (int ks = 0; ks < 2; ++ks)
        bbn[ks] = *(const short8*)&w2t[cB * 64 + kB + ks * 32];
#pragma unroll
      for (int n0 = 0; n0 < 8; ++n0) {
        short8 bb[2];
#pragma unroll
        for (int ks = 0; ks < 2; ++ks) bb[ks] = bbn[ks];
        if (n0 < 7) {
#pragma unroll
          for (int ks = 0; ks < 2; ++ks)
            bbn[ks] = *(const short8*)&w2t[((n0 + 1) * 16 + cB) * 64 + kB + ks * 32];
        }
#pragma unroll
        for (int mt = 0; mt < 2; ++mt) {
          f32x4 acc = {0.f, 0.f, 0.f, 0.f};
          acc = mfma16(a[mt][0], bb[0], acc);
          acc = mfma16(a[mt][1], bb[1], acc);
          int rr = (2 * wv + mt) * 16 + r0;
#pragma unroll
          for (int r = 0; r < 4; ++r)
            h2[(rr + r) * 136 + n0 * 16 + cB] = (short)f2bf(fmaxf(acc[r], 0.f));
        }
      }
    }
    __syncthreads();
    {
      short8 a2[2][4];
#pragma unroll
      for (int mt = 0; mt < 2; ++mt)
#pragma unroll
        for (int ks = 0; ks < 4; ++ks)
          a2[mt][ks] = *(const short8*)&h2[((2 * wv + mt) * 16 + cB) * 136 + kB + ks * 32];
      short8 b3n[4];
#pragma unroll
      for (int ks = 0; ks < 4; ++ks)
        b3n[ks] = *(const short8*)&w3t[cB * 128 + kB + ks * 32];  // n0 = 0
      for (int n0 = 0; n0 < 64; ++n0) {
        short8 b3[4];
#pragma unroll
        for (int ks = 0; ks < 4; ++ks) b3[ks] = b3n[ks];
        if (n0 < 63) {  // prefetch next iteration's weights (hides L2 latency)
#pragma unroll
          for (int ks = 0; ks < 4; ++ks)
            b3n[ks] = *(const short8*)&w3t[((n0 + 1) * 16 + cB) * 128 + kB + ks * 32];
        }
        f32x4 acc0 = {0.f, 0.f, 0.f, 0.f}, acc1 = {0.f, 0.f, 0.f, 0.f};
#pragma unroll
        for (int ks = 0; ks < 4; ++ks) acc0 = mfma16(a2[0][ks], b3[ks], acc0);
#pragma unroll
        for (int ks = 0; ks < 4; ++ks) acc1 = mfma16(a2[1][ks], b3[ks], acc1);
        float mv = fmaxf(fmaxf(fmaxf(acc0[0], acc0[1]), fmaxf(acc0[2], acc0[3])),
                         fmaxf(fmaxf(acc1[0], acc1[1]), fmaxf(acc1[2], acc1[3])));
        mv = fmaxf(mv, __shfl_xor(mv, 16));
        mv = fmaxf(mv, __shfl_xor(mv, 32));
        if (lane < 16) atomicMax(&gmax[n0 * 16 + lane], ordenc(mv));
      }
    }
  }
  __syncthreads();
  for (int i = tid; i < 1024; i += 256)
    gout[(g * 4 + split) * 1024 + i] = gmax[i];
}

// ---------------- combine split partials -> d_out ----------------------------
__global__ void __launch_bounds__(256) combine_kernel(const unsigned* __restrict__ gm,
                                                      float* __restrict__ out) {
  int c = blockIdx.x * 256 + threadIdx.x;
  int g = c >> 10, chn = c & 1023;
  unsigned m = 0u;
#pragma unroll
  for (int s = 0; s < 4; ++s) {
    unsigned v = gm[(g * 4 + s) * 1024 + chn];
    if (v > m) m = v;
  }
  out[c] = (m >> 31) ? __uint_as_float(m ^ 0x80000000u) : __uint_as_float(~m);
}

extern "C" void kernel_launch(void* const* d_in, const int* in_sizes, int n_in,
                              void* d_out, int out_size, void* d_ws, size_t ws_size,
                              hipStream_t stream) {
  (void)in_sizes; (void)n_in; (void)out_size; (void)ws_size;
  const float* pc = (const float*)d_in[0];
  const float* w1 = (const float*)d_in[1];
  const float* w2 = (const float*)d_in[2];
  const float* w3 = (const float*)d_in[3];
  float* out = (float*)d_out;
  char* ws = (char*)d_ws;

  unsigned* cnts = (unsigned*)(ws + 0);        // centroid counter at [4]
  ull* kslots = (ull*)(ws + 128);              // 32 ull = two 128B parity lines
  ull* cslots = (ull*)(ws + 1024);             // 48 ull centroid partials
  unsigned short* w2t = (unsigned short*)(ws + 4096);            // 16 KiB
  unsigned short* w3t = (unsigned short*)(ws + 4096 + 16384);    // 256 KiB
  int* knn = (int*)(ws + 4096 + 16384 + 262144);                 // 512 KiB
  unsigned* gout = (unsigned*)(ws + 4096 + 16384 + 262144 + 524288); // 2 MiB
  float* sampled = out + 131072;

  hipMemsetAsync(ws, 0, 4096, stream);
  fps_kernel<<<FPS_B + 128, 1024, 0, stream>>>(pc, w2, w3, w2t, w3t, sampled,
                                               cnts, kslots, cslots);
  knn_kernel<<<NG, 1024, 0, stream>>>(pc, sampled, knn);
  mlp_kernel<<<NG * 4, 256, 0, stream>>>(pc, knn, w1, w2t, w3t, gout);
  combine_kernel<<<512, 256, 0, stream>>>(gout, out);
}

// Round 15
// 584.986 us; speedup vs baseline: 2.4567x; 1.0239x over previous
//
#include <hip/hip_runtime.h>

#define N_PTS 262144
#define NG 128
#define GS 1024
#define FPS_B 16

typedef __attribute__((ext_vector_type(8))) short short8;
typedef __attribute__((ext_vector_type(8))) __bf16 bf16x8;
typedef __attribute__((ext_vector_type(4))) float f32x4;
typedef unsigned long long ull;

__device__ __forceinline__ unsigned short f2bf(float f) {
  unsigned u = __float_as_uint(f);
  unsigned r = u + 0x7FFFu + ((u >> 16) & 1u);
  return (unsigned short)(r >> 16);
}

__device__ __forceinline__ f32x4 mfma16(short8 a, short8 b, f32x4 c) {
  return __builtin_amdgcn_mfma_f32_16x16x32_bf16(
      __builtin_bit_cast(bf16x8, a), __builtin_bit_cast(bf16x8, b), c, 0, 0, 0);
}

__device__ __forceinline__ ull shfl_xor_u64(ull v, int m) {
  unsigned lo = __shfl_xor((unsigned)v, m);
  unsigned hi = __shfl_xor((unsigned)(v >> 32), m);
  return ((ull)hi << 32) | lo;
}

__device__ __forceinline__ void st64(ull* p, ull v) {
  __hip_atomic_store(p, v, __ATOMIC_RELAXED, __HIP_MEMORY_SCOPE_AGENT);
}
__device__ __forceinline__ ull ld64(const ull* p) {
  return __hip_atomic_load(p, __ATOMIC_RELAXED, __HIP_MEMORY_SCOPE_AGENT);
}

// ordered-uint encode for float (monotone for all finite floats)
__device__ __forceinline__ unsigned ordenc(float f) {
  unsigned u = __float_as_uint(f);
  return (u >> 31) ? ~u : (u | 0x80000000u);
}

__device__ __forceinline__ unsigned knn_key(float x, float y, float z, float pp,
                                            float sx, float sy, float sz, float s2) {
  float dot = __fmaf_rn(sx, x, __fmaf_rn(sy, y, __fmul_rn(sz, z)));
  float d2 = __fadd_rn(__fsub_rn(s2, __fadd_rn(dot, dot)), pp);
  return ordenc(d2);
}

// ---------------- FPS (blocks 0..15, squared metric) + prep ------------------
// kslots[2][16]: {seq:14|dist2:32|~idx:18} per parity line, relaxed stores.
// Poll does per-slot speculative coord prefetch (lanes 0..47: slot lane&15,
// coord plane lane>>4) so the winner's coords are in-flight before the reduce.
__global__ void __launch_bounds__(1024) fps_kernel(const float* __restrict__ pc,
    const float* __restrict__ w2, const float* __restrict__ w3,
    unsigned short* __restrict__ w2t, unsigned short* __restrict__ w3t,
    float* __restrict__ sampled_out, unsigned* __restrict__ cnts,
    ull* __restrict__ kslots, ull* __restrict__ cslots) {
  const int tid = threadIdx.x;
  if (blockIdx.x >= FPS_B) {
    const int pb = blockIdx.x - FPS_B;
    int i3 = pb * 1024 + tid;  // 128 blocks cover 131072
    { int n = i3 >> 7, k = i3 & 127; w3t[i3] = f2bf(w3[k * 1024 + n]); }
    if (pb < 8) { int i2 = pb * 1024 + tid; int n = i2 >> 6, k = i2 & 63; w2t[i2] = f2bf(w2[k * 128 + n]); }
    return;
  }
  const int p = blockIdx.x;
  const int lane = tid & 63, wv = tid >> 6;
  const int gt = p * 1024 + tid;
  const float* xs = pc;
  const float* ys = pc + N_PTS;
  const float* zs = pc + 2 * N_PTS;
  float x[16], y[16], z[16], md[16];
  float sx = 0.f, sy = 0.f, sz = 0.f;
#pragma unroll
  for (int j = 0; j < 16; ++j) {
    int i = gt + j * 16384;
    x[j] = xs[i]; y[j] = ys[i]; z[j] = zs[i];
    sx += x[j]; sy += y[j]; sz += z[j];
  }
#pragma unroll
  for (int m = 32; m; m >>= 1) {
    sx += __shfl_xor(sx, m); sy += __shfl_xor(sy, m); sz += __shfl_xor(sz, m);
  }
  __shared__ float rs[3][16];
  __shared__ ull wkeyL[16];
  __shared__ float bc[3];
  if (lane == 0) { rs[0][wv] = sx; rs[1][wv] = sy; rs[2][wv] = sz; }
  __syncthreads();
  if (tid == 0) {
    float ax = 0.f, ay = 0.f, az = 0.f;
    for (int w = 0; w < 16; ++w) { ax += rs[0][w]; ay += rs[1][w]; az += rs[2][w]; }
    st64(&cslots[0 + p], (ull)__float_as_uint(ax));
    st64(&cslots[16 + p], (ull)__float_as_uint(ay));
    st64(&cslots[32 + p], (ull)__float_as_uint(az));
    __hip_atomic_fetch_add(&cnts[4], 1u, __ATOMIC_RELEASE, __HIP_MEMORY_SCOPE_AGENT);
  }
  if (wv == 0) {
    while (__hip_atomic_load(&cnts[4], __ATOMIC_RELAXED, __HIP_MEMORY_SCOPE_AGENT) < 16u)
      __builtin_amdgcn_s_sleep(1);
    (void)__hip_atomic_load(&cnts[4], __ATOMIC_ACQUIRE, __HIP_MEMORY_SCOPE_AGENT);
    float f = 0.f;
    if (lane < 48) f = __uint_as_float((unsigned)ld64(&cslots[lane]));
    float s = 0.f;
    for (int q = 0; q < 16; ++q) s += __shfl(f, (lane & 48) + q);  // ascending order
    if (lane == 0)  bc[0] = s * (1.f / N_PTS);
    if (lane == 16) bc[1] = s * (1.f / N_PTS);
    if (lane == 32) bc[2] = s * (1.f / N_PTS);
  }
  __syncthreads();
  ull lkey = 0ull;
  {
    float cx = bc[0], cy = bc[1], cz = bc[2];
#pragma unroll
    for (int j = 0; j < 16; ++j) {
      float dx = x[j] - cx, dy = y[j] - cy, dz = z[j] - cz;
      float d = __fmaf_rn(dx, dx, __fmaf_rn(dy, dy, dz * dz));  // squared dist
      md[j] = d;
      unsigned fb = __float_as_uint(d);
      ull k = ((ull)fb << 18) | (ull)(0x3FFFFu ^ (unsigned)(gt + j * 16384));
      if (k > lkey) lkey = k;
    }
  }
  for (int sel = 0; sel < NG; ++sel) {
    const ull seq = (ull)(sel + 1);
    ull rk = lkey;
#pragma unroll
    for (int m = 32; m; m >>= 1) {
      ull o = shfl_xor_u64(rk, m);
      if (o > rk) rk = o;
    }
    if (lane == 0) wkeyL[wv] = rk;
    __syncthreads();
    if (wv == 0) {
      const int pb = (sel & 1) * 16;  // depth-2 parity line
      ull bk = (lane < 16) ? wkeyL[lane] : 0ull;
#pragma unroll
      for (int m = 8; m; m >>= 1) {
        ull o = shfl_xor_u64(bk, m);
        if (o > bk) bk = o;
      }
      if (lane == 0) st64(&kslots[pb + p], (seq << 50) | bk);  // fire-and-forget
      // poll + speculative per-slot coord prefetch
      ull v = 0ull; float c = 0.f;
      bool got = (lane >= 48);
      for (;;) {
        if (!got) {
          v = ld64(&kslots[pb + (lane & 15)]);
          if ((v >> 50) == seq) {
            got = true;
            unsigned idx = 0x3FFFFu ^ (unsigned)(v & 0x3FFFFull);
            c = pc[(lane >> 4) * N_PTS + idx];  // in-flight while others poll
          }
        }
        if (__all((int)got)) break;
      }
      ull gk = v;  // lanes 0..47 hold their slot's key (groups agree); 48+ hold 0
      int ws_ = lane & 15;
#pragma unroll
      for (int m = 8; m; m >>= 1) {  // winner within each 16-lane group
        ull o = shfl_xor_u64(gk, m);
        int ow = __shfl_xor(ws_, m);
        if (o > gk) { gk = o; ws_ = ow; }
      }
      if (lane < 48 && (lane & 15) == ws_) {  // 3 lanes: winner's x, y, z
        bc[lane >> 4] = c;
        if (p == 0) sampled_out[sel * 3 + (lane >> 4)] = c;
      }
    }
    __syncthreads();
    {  // fused md-update + next-step candidate (squared metric)
      float wx = bc[0], wy = bc[1], wz = bc[2];
      ull nk = 0ull;
#pragma unroll
      for (int j = 0; j < 16; ++j) {
        float dx = x[j] - wx, dy = y[j] - wy, dz = z[j] - wz;
        float d = __fmaf_rn(dx, dx, __fmaf_rn(dy, dy, dz * dz));
        float m = (sel == 0) ? d : fminf(md[j], d);
        md[j] = m;
        unsigned fb = __float_as_uint(m);
        ull k = ((ull)fb << 18) | (ull)(0x3FFFFu ^ (unsigned)(gt + j * 16384));
        if (k > nk) nk = k;
      }
      lkey = nk;
    }
  }
}

// ---------------- KNN v2: subsample threshold + 1-pass candidates ------------
__device__ __forceinline__ void select_bucket(const unsigned* hist, int nbins,
                                              unsigned krem, unsigned* sres, int lane) {
  const int per = nbins >> 6;
  unsigned local = 0;
  for (int j = 0; j < per; ++j) local += hist[lane * per + j];
  unsigned inc = local;
  for (int off = 1; off < 64; off <<= 1) {
    unsigned v = __shfl_up(inc, off);
    if (lane >= off) inc += v;
  }
  unsigned exc = inc - local;
  if (exc < krem && krem <= inc) {
    unsigned c = exc;
    for (int j = 0; j < per; ++j) {
      unsigned h = hist[lane * per + j];
      if (c + h >= krem) { sres[0] = (unsigned)(lane * per + j); sres[1] = c; break; }
      c += h;
    }
  }
}

__global__ void __launch_bounds__(1024) knn_kernel(const float* __restrict__ pc,
    const float* __restrict__ sampled, int* __restrict__ knn) {
  const int g = blockIdx.x;
  const int tid = threadIdx.x;
  const int lane = tid & 63;
  __shared__ unsigned hist[2048];
  __shared__ unsigned candk[8192];
  __shared__ unsigned candi[8192];
  __shared__ unsigned candk2[2048];
  __shared__ unsigned candi2[2048];
  __shared__ unsigned sres[2];
  __shared__ unsigned scnt[6];
  const f32x4* xs4 = (const f32x4*)pc;
  const f32x4* ys4 = (const f32x4*)(pc + N_PTS);
  const f32x4* zs4 = (const f32x4*)(pc + 2 * N_PTS);
  const float sx = sampled[g * 3 + 0], sy = sampled[g * 3 + 1], sz = sampled[g * 3 + 2];
  const float s2 = __fadd_rn(__fadd_rn(__fmul_rn(sx, sx), __fmul_rn(sy, sy)),
                             __fmul_rn(sz, sz));
  for (int i = tid; i < 2048; i += 1024) hist[i] = 0u;
  if (tid < 6) scnt[tid] = 0u;
  __syncthreads();
  // subsample scan: first 16384 points -> rank-160 bucket => threshold T'
  for (int it = 0; it < 4; ++it) {
    int i4 = it * 1024 + tid;
    f32x4 xv = xs4[i4], yv = ys4[i4], zv = zs4[i4];
#pragma unroll
    for (int u = 0; u < 4; ++u) {
      float pp = __fadd_rn(__fadd_rn(__fmul_rn(xv[u], xv[u]), __fmul_rn(yv[u], yv[u])),
                           __fmul_rn(zv[u], zv[u]));
      unsigned k = knn_key(xv[u], yv[u], zv[u], pp, sx, sy, sz, s2);
      atomicAdd(&hist[k >> 21], 1u);
    }
  }
  __syncthreads();
  if (tid < 64) select_bucket(hist, 2048, 160u, sres, lane);
  __syncthreads();
  const unsigned Tp = (sres[0] >= 2047u) ? 0xFFFFFFFFu : ((sres[0] + 1u) << 21);
  __syncthreads();
  // full scan: collect candidates with key < T' (exact superset of top-1024 w.h.p.)
  for (int it = 0; it < 64; ++it) {
    int i4 = it * 1024 + tid;
    f32x4 xv = xs4[i4], yv = ys4[i4], zv = zs4[i4];
#pragma unroll
    for (int u = 0; u < 4; ++u) {
      float pp = __fadd_rn(__fadd_rn(__fmul_rn(xv[u], xv[u]), __fmul_rn(yv[u], yv[u])),
                           __fmul_rn(zv[u], zv[u]));
      unsigned k = knn_key(xv[u], yv[u], zv[u], pp, sx, sy, sz, s2);
      if (k < Tp) {
        unsigned e = atomicAdd(&scnt[0], 1u);
        if (e < 8192u) { candk[e] = k; candi[e] = (unsigned)(i4 * 4 + u); }
      }
    }
  }
  __syncthreads();
  const int m = (int)min(scnt[0], 8192u);
  // level A: bits 31..21 over candidates
  for (int i = tid; i < 2048; i += 1024) hist[i] = 0u;
  __syncthreads();
  for (int j = tid; j < m; j += 1024) atomicAdd(&hist[candk[j] >> 21], 1u);
  __syncthreads();
  if (tid < 64) select_bucket(hist, 2048, GS, sres, lane);
  __syncthreads();
  const unsigned bA = sres[0];
  unsigned krem = GS - sres[1];
  __syncthreads();
  for (int j = tid; j < m; j += 1024) {
    unsigned k = candk[j], b = k >> 21;
    if (b < bA) {
      unsigned pos = atomicAdd(&scnt[1], 1u);
      knn[g * GS + (int)pos] = (int)candi[j];
    } else if (b == bA) {
      unsigned e = atomicAdd(&scnt[2], 1u);
      if (e < 2048u) { candk2[e] = k; candi2[e] = candi[j]; }
    }
  }
  __syncthreads();
  const int m2 = (int)min(scnt[2], 2048u);
  const int base1 = (int)scnt[1];
  for (int i = tid; i < 2048; i += 1024) hist[i] = 0u;
  __syncthreads();
  for (int j = tid; j < m2; j += 1024) atomicAdd(&hist[(candk2[j] >> 10) & 2047u], 1u);
  __syncthreads();
  if (tid < 64) select_bucket(hist, 2048, krem, sres, lane);
  __syncthreads();
  const unsigned bB = sres[0];
  krem -= sres[1];
  __syncthreads();
  if (tid < 1024) hist[tid] = 0u;
  __syncthreads();
  for (int j = tid; j < m2; j += 1024)
    if (((candk2[j] >> 10) & 2047u) == bB) atomicAdd(&hist[candk2[j] & 1023u], 1u);
  __syncthreads();
  if (tid < 64) select_bucket(hist, 1024, krem, sres, lane);
  __syncthreads();
  const unsigned bC = sres[0];
  krem -= sres[1];
  const unsigned T = (bA << 21) | (bB << 10) | bC;
  __syncthreads();
  for (int j = tid; j < m2; j += 1024) {
    unsigned k = candk2[j];
    if (k < T) {
      unsigned pos = atomicAdd(&scnt[3], 1u);
      knn[g * GS + base1 + (int)pos] = (int)candi2[j];
    } else if (k == T) {
      unsigned e = atomicAdd(&scnt[4], 1u);
      if (e < 2048u) hist[e] = candi2[j];
    }
  }
  __syncthreads();
  if (tid < 64) {
    const int tc = (int)min(scnt[4], 2048u);
    const int base2 = base1 + (int)scnt[3];
    for (int j = 0; j < (int)krem; ++j) {
      int best = 0x7FFFFFFF;
      for (int q = lane; q < tc; q += 64) best = min(best, (int)hist[q]);
      for (int mm = 32; mm; mm >>= 1) best = min(best, __shfl_xor(best, mm));
      for (int q = lane; q < tc; q += 64)
        if ((int)hist[q] == best) hist[q] = 0x7FFFFFFFu;
      if (lane == 0) knn[g * GS + base2 + j] = best;
    }
  }
}

// ---------------- fused MLP + max-pool, bf16 MFMA ----------------------------
__global__ void __launch_bounds__(256, 2) mlp_kernel(const float* __restrict__ pc,
    const int* __restrict__ knn, const float* __restrict__ w1,
    const unsigned short* __restrict__ w2t, const unsigned short* __restrict__ w3t,
    unsigned* __restrict__ gout) {
  const int blk = blockIdx.x, g = blk >> 2, split = blk & 3;
  const int tid = threadIdx.x, lane = tid & 63, wv = tid >> 6;
  __shared__ unsigned gmax[1024];
  __shared__ __align__(16) short h1[128 * 72];
  __shared__ __align__(16) short h2[128 * 136];
  __shared__ float cxs[128], cys[128], czs[128];
  for (int i = tid; i < 1024; i += 256) gmax[i] = 0u;
  const float* xs = pc;
  const float* ys = pc + N_PTS;
  const float* zs = pc + 2 * N_PTS;
  const int ch = tid & 63;
  const int pgrp = tid >> 6;
  const float w10 = w1[ch], w11 = w1[64 + ch], w12 = w1[128 + ch];
  const int r0 = (lane >> 4) * 4;
  const int cB = lane & 15;
  const int kB = (lane >> 4) * 8;
  for (int tile = 0; tile < 2; ++tile) {
    __syncthreads();
    if (tid < 128) {
      int i = knn[g * 1024 + split * 256 + tile * 128 + tid];
      cxs[tid] = xs[i]; cys[tid] = ys[i]; czs[tid] = zs[i];
    }
    __syncthreads();
    for (int q = 0; q < 32; ++q) {
      int p = pgrp * 32 + q;
      float v = fmaxf(__fmaf_rn(cxs[p], w10, __fmaf_rn(cys[p], w11, czs[p] * w12)), 0.f);
      h1[p * 72 + ch] = (short)f2bf(v);
    }
    __syncthreads();
    {
      short8 a[2][2];
#pragma unroll
      for (int mt = 0; mt < 2; ++mt)
#pragma unroll
        for (int ks = 0; ks < 2; ++ks)
          a[mt][ks] = *(const short8*)&h1[((2 * wv + mt) * 16 + cB) * 72 + kB + ks * 32];
#pragma unroll
      for (int n0 = 0; n0 < 8; ++n0) {
        short8 bb[2];
#pragma unroll
        for (int ks = 0; ks < 2; ++ks)
          bb[ks] = *(const short8*)&w2t[(n0 * 16 + cB) * 64 + kB + ks * 32];
#pragma unroll
        for (int mt = 0; mt < 2; ++mt) {
          f32x4 acc = {0.f, 0.f, 0.f, 0.f};
          acc = mfma16(a[mt][0], bb[0], acc);
          acc = mfma16(a[mt][1], bb[1], acc);
          int rr = (2 * wv + mt) * 16 + r0;
#pragma unroll
          for (int r = 0; r < 4; ++r)
            h2[(rr + r) * 136 + n0 * 16 + cB] = (short)f2bf(fmaxf(acc[r], 0.f));
        }
      }
    }
    __syncthreads();
    {
      short8 a2[2][4];
#pragma unroll
      for (int mt = 0; mt < 2; ++mt)
#pragma unroll
        for (int ks = 0; ks < 4; ++ks)
          a2[mt][ks] = *(const short8*)&h2[((2 * wv + mt) * 16 + cB) * 136 + kB + ks * 32];
      for (int n0 = 0; n0 < 64; ++n0) {
        short8 b3[4];
#pragma unroll
        for (int ks = 0; ks < 4; ++ks)
          b3[ks] = *(const short8*)&w3t[(n0 * 16 + cB) * 128 + kB + ks * 32];
        f32x4 acc0 = {0.f, 0.f, 0.f, 0.f}, acc1 = {0.f, 0.f, 0.f, 0.f};
#pragma unroll
        for (int ks = 0; ks < 4; ++ks) acc0 = mfma16(a2[0][ks], b3[ks], acc0);
#pragma unroll
        for (int ks = 0; ks < 4; ++ks) acc1 = mfma16(a2[1][ks], b3[ks], acc1);
        float mv = fmaxf(fmaxf(fmaxf(acc0[0], acc0[1]), fmaxf(acc0[2], acc0[3])),
                         fmaxf(fmaxf(acc1[0], acc1[1]), fmaxf(acc1[2], acc1[3])));
        mv = fmaxf(mv, __shfl_xor(mv, 16));
        mv = fmaxf(mv, __shfl_xor(mv, 32));
        if (lane < 16) atomicMax(&gmax[n0 * 16 + lane], ordenc(mv));
      }
    }
  }
  __syncthreads();
  for (int i = tid; i < 1024; i += 256)
    gout[(g * 4 + split) * 1024 + i] = gmax[i];
}

// ---------------- combine split partials -> d_out ----------------------------
__global__ void __launch_bounds__(256) combine_kernel(const unsigned* __restrict__ gm,
                                                      float* __restrict__ out) {
  int c = blockIdx.x * 256 + threadIdx.x;
  int g = c >> 10, chn = c & 1023;
  unsigned m = 0u;
#pragma unroll
  for (int s = 0; s < 4; ++s) {
    unsigned v = gm[(g * 4 + s) * 1024 + chn];
    if (v > m) m = v;
  }
  out[c] = (m >> 31) ? __uint_as_float(m ^ 0x80000000u) : __uint_as_float(~m);
}

extern "C" void kernel_launch(void* const* d_in, const int* in_sizes, int n_in,
                              void* d_out, int out_size, void* d_ws, size_t ws_size,
                              hipStream_t stream) {
  (void)in_sizes; (void)n_in; (void)out_size; (void)ws_size;
  const float* pc = (const float*)d_in[0];
  const float* w1 = (const float*)d_in[1];
  const float* w2 = (const float*)d_in[2];
  const float* w3 = (const float*)d_in[3];
  float* out = (float*)d_out;
  char* ws = (char*)d_ws;

  unsigned* cnts = (unsigned*)(ws + 0);        // centroid counter at [4]
  ull* kslots = (ull*)(ws + 128);              // 32 ull = two 128B parity lines
  ull* cslots = (ull*)(ws + 1024);             // 48 ull centroid partials
  unsigned short* w2t = (unsigned short*)(ws + 4096);            // 16 KiB
  unsigned short* w3t = (unsigned short*)(ws + 4096 + 16384);    // 256 KiB
  int* knn = (int*)(ws + 4096 + 16384 + 262144);                 // 512 KiB
  unsigned* gout = (unsigned*)(ws + 4096 + 16384 + 262144 + 524288); // 2 MiB
  float* sampled = out + 131072;

  hipMemsetAsync(ws, 0, 4096, stream);
  fps_kernel<<<FPS_B + 128, 1024, 0, stream>>>(pc, w2, w3, w2t, w3t, sampled,
                                               cnts, kslots, cslots);
  knn_kernel<<<NG, 1024, 0, stream>>>(pc, sampled, knn);
  mlp_kernel<<<NG * 4, 256, 0, stream>>>(pc, knn, w1, w2t, w3t, gout);
  combine_kernel<<<512, 256, 0, stream>>>(gout, out);
}

// Round 16
// 573.056 us; speedup vs baseline: 2.5078x; 1.0208x over previous
//
#include <hip/hip_runtime.h>

#define N_PTS 262144
#define NG 128
#define GS 1024
#define FPS_B 16

typedef __attribute__((ext_vector_type(8))) short short8;
typedef __attribute__((ext_vector_type(8))) __bf16 bf16x8;
typedef __attribute__((ext_vector_type(4))) float f32x4;
typedef unsigned long long ull;

__device__ __forceinline__ unsigned short f2bf(float f) {
  unsigned u = __float_as_uint(f);
  unsigned r = u + 0x7FFFu + ((u >> 16) & 1u);
  return (unsigned short)(r >> 16);
}

__device__ __forceinline__ f32x4 mfma16(short8 a, short8 b, f32x4 c) {
  return __builtin_amdgcn_mfma_f32_16x16x32_bf16(
      __builtin_bit_cast(bf16x8, a), __builtin_bit_cast(bf16x8, b), c, 0, 0, 0);
}

__device__ __forceinline__ ull shfl_xor_u64(ull v, int m) {
  unsigned lo = __shfl_xor((unsigned)v, m);
  unsigned hi = __shfl_xor((unsigned)(v >> 32), m);
  return ((ull)hi << 32) | lo;
}

__device__ __forceinline__ void st64(ull* p, ull v) {
  __hip_atomic_store(p, v, __ATOMIC_RELAXED, __HIP_MEMORY_SCOPE_AGENT);
}
__device__ __forceinline__ ull ld64(const ull* p) {
  return __hip_atomic_load(p, __ATOMIC_RELAXED, __HIP_MEMORY_SCOPE_AGENT);
}

// ordered-uint encode for float (monotone for all finite floats)
__device__ __forceinline__ unsigned ordenc(float f) {
  unsigned u = __float_as_uint(f);
  return (u >> 31) ? ~u : (u | 0x80000000u);
}

__device__ __forceinline__ unsigned knn_key(float x, float y, float z, float pp,
                                            float sx, float sy, float sz, float s2) {
  float dot = __fmaf_rn(sx, x, __fmaf_rn(sy, y, __fmul_rn(sz, z)));
  float d2 = __fadd_rn(__fsub_rn(s2, __fadd_rn(dot, dot)), pp);
  return ordenc(d2);
}

__device__ __forceinline__ void select_bucket(const unsigned* hist, int nbins,
                                              unsigned krem, unsigned* sres, int lane) {
  const int per = nbins >> 6;
  unsigned local = 0;
  for (int j = 0; j < per; ++j) local += hist[lane * per + j];
  unsigned inc = local;
  for (int off = 1; off < 64; off <<= 1) {
    unsigned v = __shfl_up(inc, off);
    if (lane >= off) inc += v;
  }
  unsigned exc = inc - local;
  if (exc < krem && krem <= inc) {
    unsigned c = exc;
    for (int j = 0; j < per; ++j) {
      unsigned h = hist[lane * per + j];
      if (c + h >= krem) { sres[0] = (unsigned)(lane * per + j); sres[1] = c; break; }
      c += h;
    }
  }
}

// ---- fused: fps (blocks 0..15) + prep+knn workers (16..143), overlapped -----
// kslots[2][16]: {seq:14|dist2:32|~idx:18} parity lines.
// mb[g*16+c] = {coord:32|seq:32}: one 128B line per group, posted at step g.
__global__ void __launch_bounds__(1024) fps_knn_kernel(const float* __restrict__ pc,
    const float* __restrict__ w2, const float* __restrict__ w3,
    unsigned short* __restrict__ w2t, unsigned short* __restrict__ w3t,
    float* __restrict__ sampled_out, int* __restrict__ knn,
    unsigned* __restrict__ cnts, ull* __restrict__ kslots, ull* __restrict__ mb,
    ull* __restrict__ cslots) {
  __shared__ __align__(16) char sbuf[90112];
  __shared__ unsigned sres[2];
  __shared__ unsigned scnt[6];
  __shared__ float mbx[3];
  __shared__ float rs[3][16];
  __shared__ ull wkeyL[16];
  __shared__ float bc[3];
  const int tid = threadIdx.x;
  const int lane = tid & 63, wv = tid >> 6;

  if (blockIdx.x >= FPS_B) {
    // =============== worker role: prep slice, then knn for group g ===========
    const int g = blockIdx.x - FPS_B;
    {  // weight transpose slice (runs during fps)
      int i3 = g * 1024 + tid;
      { int n = i3 >> 7, k = i3 & 127; w3t[i3] = f2bf(w3[k * 1024 + n]); }
      if (g < 8) { int i2 = g * 1024 + tid; int n = i2 >> 6, k = i2 & 63; w2t[i2] = f2bf(w2[k * 128 + n]); }
    }
    unsigned* hist = (unsigned*)sbuf;              // 8 KiB
    unsigned* candk = (unsigned*)(sbuf + 8192);    // 32 KiB
    unsigned* candi = (unsigned*)(sbuf + 40960);   // 32 KiB
    unsigned* candk2 = (unsigned*)(sbuf + 73728);  // 8 KiB
    unsigned* candi2 = (unsigned*)(sbuf + 81920);  // 8 KiB
    for (int i = tid; i < 2048; i += 1024) hist[i] = 0u;
    if (tid < 6) scnt[tid] = 0u;
    if (tid < 3) {  // wait for this group's sampled point (long-interval poll)
      ull v;
      for (;;) {
        v = ld64(&mb[g * 16 + tid]);
        if ((unsigned)v == (unsigned)(g + 1)) break;
        __builtin_amdgcn_s_sleep(64);
      }
      mbx[tid] = __uint_as_float((unsigned)(v >> 32));
    }
    __syncthreads();
    const float sx = mbx[0], sy = mbx[1], sz = mbx[2];
    const float s2 = __fadd_rn(__fadd_rn(__fmul_rn(sx, sx), __fmul_rn(sy, sy)),
                               __fmul_rn(sz, sz));
    const f32x4* xs4 = (const f32x4*)pc;
    const f32x4* ys4 = (const f32x4*)(pc + N_PTS);
    const f32x4* zs4 = (const f32x4*)(pc + 2 * N_PTS);
    // subsample scan: first 16384 points -> rank-160 bucket => threshold T'
    for (int it = 0; it < 4; ++it) {
      int i4 = it * 1024 + tid;
      f32x4 xv = xs4[i4], yv = ys4[i4], zv = zs4[i4];
#pragma unroll
      for (int u = 0; u < 4; ++u) {
        float pp = __fadd_rn(__fadd_rn(__fmul_rn(xv[u], xv[u]), __fmul_rn(yv[u], yv[u])),
                             __fmul_rn(zv[u], zv[u]));
        unsigned k = knn_key(xv[u], yv[u], zv[u], pp, sx, sy, sz, s2);
        atomicAdd(&hist[k >> 21], 1u);
      }
    }
    __syncthreads();
    if (tid < 64) select_bucket(hist, 2048, 160u, sres, lane);
    __syncthreads();
    const unsigned Tp = (sres[0] >= 2047u) ? 0xFFFFFFFFu : ((sres[0] + 1u) << 21);
    __syncthreads();
    // full scan: collect candidates with key < T'
    for (int it = 0; it < 64; ++it) {
      int i4 = it * 1024 + tid;
      f32x4 xv = xs4[i4], yv = ys4[i4], zv = zs4[i4];
#pragma unroll
      for (int u = 0; u < 4; ++u) {
        float pp = __fadd_rn(__fadd_rn(__fmul_rn(xv[u], xv[u]), __fmul_rn(yv[u], yv[u])),
                             __fmul_rn(zv[u], zv[u]));
        unsigned k = knn_key(xv[u], yv[u], zv[u], pp, sx, sy, sz, s2);
        if (k < Tp) {
          unsigned e = atomicAdd(&scnt[0], 1u);
          if (e < 8192u) { candk[e] = k; candi[e] = (unsigned)(i4 * 4 + u); }
        }
      }
    }
    __syncthreads();
    const int m = (int)min(scnt[0], 8192u);
    for (int i = tid; i < 2048; i += 1024) hist[i] = 0u;
    __syncthreads();
    for (int j = tid; j < m; j += 1024) atomicAdd(&hist[candk[j] >> 21], 1u);
    __syncthreads();
    if (tid < 64) select_bucket(hist, 2048, GS, sres, lane);
    __syncthreads();
    const unsigned bA = sres[0];
    unsigned krem = GS - sres[1];
    __syncthreads();
    for (int j = tid; j < m; j += 1024) {
      unsigned k = candk[j], b = k >> 21;
      if (b < bA) {
        unsigned pos = atomicAdd(&scnt[1], 1u);
        knn[g * GS + (int)pos] = (int)candi[j];
      } else if (b == bA) {
        unsigned e = atomicAdd(&scnt[2], 1u);
        if (e < 2048u) { candk2[e] = k; candi2[e] = candi[j]; }
      }
    }
    __syncthreads();
    const int m2 = (int)min(scnt[2], 2048u);
    const int base1 = (int)scnt[1];
    for (int i = tid; i < 2048; i += 1024) hist[i] = 0u;
    __syncthreads();
    for (int j = tid; j < m2; j += 1024) atomicAdd(&hist[(candk2[j] >> 10) & 2047u], 1u);
    __syncthreads();
    if (tid < 64) select_bucket(hist, 2048, krem, sres, lane);
    __syncthreads();
    const unsigned bB = sres[0];
    krem -= sres[1];
    __syncthreads();
    if (tid < 1024) hist[tid] = 0u;
    __syncthreads();
    for (int j = tid; j < m2; j += 1024)
      if (((candk2[j] >> 10) & 2047u) == bB) atomicAdd(&hist[candk2[j] & 1023u], 1u);
    __syncthreads();
    if (tid < 64) select_bucket(hist, 1024, krem, sres, lane);
    __syncthreads();
    const unsigned bC = sres[0];
    krem -= sres[1];
    const unsigned T = (bA << 21) | (bB << 10) | bC;
    __syncthreads();
    for (int j = tid; j < m2; j += 1024) {
      unsigned k = candk2[j];
      if (k < T) {
        unsigned pos = atomicAdd(&scnt[3], 1u);
        knn[g * GS + base1 + (int)pos] = (int)candi2[j];
      } else if (k == T) {
        unsigned e = atomicAdd(&scnt[4], 1u);
        if (e < 2048u) hist[e] = candi2[j];
      }
    }
    __syncthreads();
    if (tid < 64) {
      const int tc = (int)min(scnt[4], 2048u);
      const int base2 = base1 + (int)scnt[3];
      for (int j = 0; j < (int)krem; ++j) {
        int best = 0x7FFFFFFF;
        for (int q = lane; q < tc; q += 64) best = min(best, (int)hist[q]);
        for (int mm = 32; mm; mm >>= 1) best = min(best, __shfl_xor(best, mm));
        for (int q = lane; q < tc; q += 64)
          if ((int)hist[q] == best) hist[q] = 0x7FFFFFFFu;
        if (lane == 0) knn[g * GS + base2 + j] = best;
      }
    }
    return;
  }

  // ===================== FPS role (R15, + mailbox posts) =====================
  const int p = blockIdx.x;
  const int gt = p * 1024 + tid;
  const float* xs = pc;
  const float* ys = pc + N_PTS;
  const float* zs = pc + 2 * N_PTS;
  float x[16], y[16], z[16], md[16];
  float sx = 0.f, sy = 0.f, sz = 0.f;
#pragma unroll
  for (int j = 0; j < 16; ++j) {
    int i = gt + j * 16384;
    x[j] = xs[i]; y[j] = ys[i]; z[j] = zs[i];
    sx += x[j]; sy += y[j]; sz += z[j];
  }
#pragma unroll
  for (int m = 32; m; m >>= 1) {
    sx += __shfl_xor(sx, m); sy += __shfl_xor(sy, m); sz += __shfl_xor(sz, m);
  }
  if (lane == 0) { rs[0][wv] = sx; rs[1][wv] = sy; rs[2][wv] = sz; }
  __syncthreads();
  if (tid == 0) {
    float ax = 0.f, ay = 0.f, az = 0.f;
    for (int w = 0; w < 16; ++w) { ax += rs[0][w]; ay += rs[1][w]; az += rs[2][w]; }
    st64(&cslots[0 + p], (ull)__float_as_uint(ax));
    st64(&cslots[16 + p], (ull)__float_as_uint(ay));
    st64(&cslots[32 + p], (ull)__float_as_uint(az));
    __hip_atomic_fetch_add(&cnts[4], 1u, __ATOMIC_RELEASE, __HIP_MEMORY_SCOPE_AGENT);
  }
  if (wv == 0) {
    while (__hip_atomic_load(&cnts[4], __ATOMIC_RELAXED, __HIP_MEMORY_SCOPE_AGENT) < 16u)
      __builtin_amdgcn_s_sleep(1);
    (void)__hip_atomic_load(&cnts[4], __ATOMIC_ACQUIRE, __HIP_MEMORY_SCOPE_AGENT);
    float f = 0.f;
    if (lane < 48) f = __uint_as_float((unsigned)ld64(&cslots[lane]));
    float s = 0.f;
    for (int q = 0; q < 16; ++q) s += __shfl(f, (lane & 48) + q);  // ascending order
    if (lane == 0)  bc[0] = s * (1.f / N_PTS);
    if (lane == 16) bc[1] = s * (1.f / N_PTS);
    if (lane == 32) bc[2] = s * (1.f / N_PTS);
  }
  __syncthreads();
  ull lkey = 0ull;
  {
    float cx = bc[0], cy = bc[1], cz = bc[2];
#pragma unroll
    for (int j = 0; j < 16; ++j) {
      float dx = x[j] - cx, dy = y[j] - cy, dz = z[j] - cz;
      float d = __fmaf_rn(dx, dx, __fmaf_rn(dy, dy, dz * dz));  // squared dist
      md[j] = d;
      unsigned fb = __float_as_uint(d);
      ull k = ((ull)fb << 18) | (ull)(0x3FFFFu ^ (unsigned)(gt + j * 16384));
      if (k > lkey) lkey = k;
    }
  }
  for (int sel = 0; sel < NG; ++sel) {
    const ull seq = (ull)(sel + 1);
    ull rk = lkey;
#pragma unroll
    for (int m = 32; m; m >>= 1) {
      ull o = shfl_xor_u64(rk, m);
      if (o > rk) rk = o;
    }
    if (lane == 0) wkeyL[wv] = rk;
    __syncthreads();
    if (wv == 0) {
      const int pb = (sel & 1) * 16;  // depth-2 parity line
      ull bk = (lane < 16) ? wkeyL[lane] : 0ull;
#pragma unroll
      for (int m = 8; m; m >>= 1) {
        ull o = shfl_xor_u64(bk, m);
        if (o > bk) bk = o;
      }
      if (lane == 0) st64(&kslots[pb + p], (seq << 50) | bk);  // fire-and-forget
      // poll + speculative per-slot coord prefetch
      ull v = 0ull; float c = 0.f;
      bool got = (lane >= 48);
      for (;;) {
        if (!got) {
          v = ld64(&kslots[pb + (lane & 15)]);
          if ((v >> 50) == seq) {
            got = true;
            unsigned idx = 0x3FFFFu ^ (unsigned)(v & 0x3FFFFull);
            c = pc[(lane >> 4) * N_PTS + idx];  // in-flight while others poll
          }
        }
        if (__all((int)got)) break;
      }
      ull gk = v;
      int ws_ = lane & 15;
#pragma unroll
      for (int m = 8; m; m >>= 1) {  // winner within each 16-lane group
        ull o = shfl_xor_u64(gk, m);
        int ow = __shfl_xor(ws_, m);
        if (o > gk) { gk = o; ws_ = ow; }
      }
      if (lane < 48 && (lane & 15) == ws_) {  // 3 lanes: winner's x, y, z
        bc[lane >> 4] = c;
        if (p == 0) {
          sampled_out[sel * 3 + (lane >> 4)] = c;
          st64(&mb[sel * 16 + (lane >> 4)], ((ull)__float_as_uint(c) << 32) | seq);
        }
      }
    }
    __syncthreads();
    {  // fused md-update + next-step candidate (squared metric)
      float wx = bc[0], wy = bc[1], wz = bc[2];
      ull nk = 0ull;
#pragma unroll
      for (int j = 0; j < 16; ++j) {
        float dx = x[j] - wx, dy = y[j] - wy, dz = z[j] - wz;
        float d = __fmaf_rn(dx, dx, __fmaf_rn(dy, dy, dz * dz));
        float m = (sel == 0) ? d : fminf(md[j], d);
        md[j] = m;
        unsigned fb = __float_as_uint(m);
        ull k = ((ull)fb << 18) | (ull)(0x3FFFFu ^ (unsigned)(gt + j * 16384));
        if (k > nk) nk = k;
      }
      lkey = nk;
    }
  }
}

// ---------------- fused MLP + max-pool, bf16 MFMA ----------------------------
__global__ void __launch_bounds__(256, 2) mlp_kernel(const float* __restrict__ pc,
    const int* __restrict__ knn, const float* __restrict__ w1,
    const unsigned short* __restrict__ w2t, const unsigned short* __restrict__ w3t,
    unsigned* __restrict__ gout) {
  const int blk = blockIdx.x, g = blk >> 2, split = blk & 3;
  const int tid = threadIdx.x, lane = tid & 63, wv = tid >> 6;
  __shared__ unsigned gmax[1024];
  __shared__ __align__(16) short h1[128 * 72];
  __shared__ __align__(16) short h2[128 * 136];
  __shared__ float cxs[128], cys[128], czs[128];
  for (int i = tid; i < 1024; i += 256) gmax[i] = 0u;
  const float* xs = pc;
  const float* ys = pc + N_PTS;
  const float* zs = pc + 2 * N_PTS;
  const int ch = tid & 63;
  const int pgrp = tid >> 6;
  const float w10 = w1[ch], w11 = w1[64 + ch], w12 = w1[128 + ch];
  const int r0 = (lane >> 4) * 4;
  const int cB = lane & 15;
  const int kB = (lane >> 4) * 8;
  for (int tile = 0; tile < 2; ++tile) {
    __syncthreads();
    if (tid < 128) {
      int i = knn[g * 1024 + split * 256 + tile * 128 + tid];
      cxs[tid] = xs[i]; cys[tid] = ys[i]; czs[tid] = zs[i];
    }
    __syncthreads();
    for (int q = 0; q < 32; ++q) {
      int p = pgrp * 32 + q;
      float v = fmaxf(__fmaf_rn(cxs[p], w10, __fmaf_rn(cys[p], w11, czs[p] * w12)), 0.f);
      h1[p * 72 + ch] = (short)f2bf(v);
    }
    __syncthreads();
    {
      short8 a[2][2];
#pragma unroll
      for (int mt = 0; mt < 2; ++mt)
#pragma unroll
        for (int ks = 0; ks < 2; ++ks)
          a[mt][ks] = *(const short8*)&h1[((2 * wv + mt) * 16 + cB) * 72 + kB + ks * 32];
#pragma unroll
      for (int n0 = 0; n0 < 8; ++n0) {
        short8 bb[2];
#pragma unroll
        for (int ks = 0; ks < 2; ++ks)
          bb[ks] = *(const short8*)&w2t[(n0 * 16 + cB) * 64 + kB + ks * 32];
#pragma unroll
        for (int mt = 0; mt < 2; ++mt) {
          f32x4 acc = {0.f, 0.f, 0.f, 0.f};
          acc = mfma16(a[mt][0], bb[0], acc);
          acc = mfma16(a[mt][1], bb[1], acc);
          int rr = (2 * wv + mt) * 16 + r0;
#pragma unroll
          for (int r = 0; r < 4; ++r)
            h2[(rr + r) * 136 + n0 * 16 + cB] = (short)f2bf(fmaxf(acc[r], 0.f));
        }
      }
    }
    __syncthreads();
    {
      short8 a2[2][4];
#pragma unroll
      for (int mt = 0; mt < 2; ++mt)
#pragma unroll
        for (int ks = 0; ks < 4; ++ks)
          a2[mt][ks] = *(const short8*)&h2[((2 * wv + mt) * 16 + cB) * 136 + kB + ks * 32];
      for (int n0 = 0; n0 < 64; ++n0) {
        short8 b3[4];
#pragma unroll
        for (int ks = 0; ks < 4; ++ks)
          b3[ks] = *(const short8*)&w3t[(n0 * 16 + cB) * 128 + kB + ks * 32];
        f32x4 acc0 = {0.f, 0.f, 0.f, 0.f}, acc1 = {0.f, 0.f, 0.f, 0.f};
#pragma unroll
        for (int ks = 0; ks < 4; ++ks) acc0 = mfma16(a2[0][ks], b3[ks], acc0);
#pragma unroll
        for (int ks = 0; ks < 4; ++ks) acc1 = mfma16(a2[1][ks], b3[ks], acc1);
        float mv = fmaxf(fmaxf(fmaxf(acc0[0], acc0[1]), fmaxf(acc0[2], acc0[3])),
                         fmaxf(fmaxf(acc1[0], acc1[1]), fmaxf(acc1[2], acc1[3])));
        mv = fmaxf(mv, __shfl_xor(mv, 16));
        mv = fmaxf(mv, __shfl_xor(mv, 32));
        if (lane < 16) atomicMax(&gmax[n0 * 16 + lane], ordenc(mv));
      }
    }
  }
  __syncthreads();
  for (int i = tid; i < 1024; i += 256)
    gout[(g * 4 + split) * 1024 + i] = gmax[i];
}

// ---------------- combine split partials -> d_out ----------------------------
__global__ void __launch_bounds__(256) combine_kernel(const unsigned* __restrict__ gm,
                                                      float* __restrict__ out) {
  int c = blockIdx.x * 256 + threadIdx.x;
  int g = c >> 10, chn = c & 1023;
  unsigned m = 0u;
#pragma unroll
  for (int s = 0; s < 4; ++s) {
    unsigned v = gm[(g * 4 + s) * 1024 + chn];
    if (v > m) m = v;
  }
  out[c] = (m >> 31) ? __uint_as_float(m ^ 0x80000000u) : __uint_as_float(~m);
}

extern "C" void kernel_launch(void* const* d_in, const int* in_sizes, int n_in,
                              void* d_out, int out_size, void* d_ws, size_t ws_size,
                              hipStream_t stream) {
  (void)in_sizes; (void)n_in; (void)out_size; (void)ws_size;
  const float* pc = (const float*)d_in[0];
  const float* w1 = (const float*)d_in[1];
  const float* w2 = (const float*)d_in[2];
  const float* w3 = (const float*)d_in[3];
  float* out = (float*)d_out;
  char* ws = (char*)d_ws;

  unsigned* cnts = (unsigned*)(ws + 0);        // centroid counter at [4]
  ull* kslots = (ull*)(ws + 128);              // 32 ull = two 128B parity lines
  ull* cslots = (ull*)(ws + 1024);             // 48 ull centroid partials
  ull* mb = (ull*)(ws + 2048);                 // 128 groups x 128B mailbox lines
  unsigned short* w2t = (unsigned short*)(ws + 24576);           // 16 KiB
  unsigned short* w3t = (unsigned short*)(ws + 24576 + 16384);   // 256 KiB
  int* knn = (int*)(ws + 24576 + 16384 + 262144);                // 512 KiB
  unsigned* gout = (unsigned*)(ws + 24576 + 16384 + 262144 + 524288); // 2 MiB
  float* sampled = out + 131072;

  hipMemsetAsync(ws, 0, 20480, stream);
  fps_knn_kernel<<<FPS_B + NG, 1024, 0, stream>>>(pc, w2, w3, w2t, w3t, sampled,
                                                  knn, cnts, kslots, mb, cslots);
  mlp_kernel<<<NG * 4, 256, 0, stream>>>(pc, knn, w1, w2t, w3t, gout);
  combine_kernel<<<512, 256, 0, stream>>>(gout, out);
}